// Round 16
// baseline (566.693 us; speedup 1.0000x reference)
//
#include <hip/hip_runtime.h>
#include <hip/hip_bf16.h>

// FAVOR+ attention, MI355X. Round 16:
//  - outchunk: __launch_bounds__(512, 4) -> force 2 blocks/CU co-residency
//    (first inter-block stall coverage; code otherwise byte-identical R15).
//  - proj GEMMs merged into one dispatch (grid 1024x3, y selects {q,k,v}):
//    tail-filling between GEMMs. Per-block code identical to validated mm_k.
//  - kvstate / scan / convs / final mm_k: byte-identical to validated R15.
//
// Workspace (bytes), total 213,942,272 (~204 MB):
//   v      bf16 [64bh][4096][64]   @ 0            (32 MB)
//   q      bf16                    @ 33,554,432   (32 MB)
//   k      bf16                    @ 67,108,864   (32 MB)
//   xb     bf16 [16384][1024]      @ 100,663,296  (32 MB) -- ALIASED attn
//   stateb bf16 [64bh][32][16384]  @ 134,217,728  (64 MB)
//   ksum   f32  [64bh][32][256]    @ 201,326,592  (2 MB)
//   Wt     bf16 4x[1024][1024]     @ 203,423,744  (8 MB)
//   omb    bf16 [256][64]          @ 211,812,352  (32 KB)
//   nhq    f32  [64bh][4096]       @ 211,845,120  (1 MB)
//   nhk    f32  [64bh][4096]       @ 212,893,696  (1 MB)

#define B_ 4
#define H_ 16
#define L_ 4096
#define D_ 64
#define M_ 256
#define DM_ 1024
#define BH_ 64
#define NSC 32            // superchunks per bh (SC = 128 tokens)

typedef unsigned int u32;
typedef unsigned short u16;
typedef __attribute__((ext_vector_type(8))) short bf16x8;
typedef __attribute__((ext_vector_type(4))) float f32x4;

static __device__ __forceinline__ float bf2f(u16 u) {
  return __uint_as_float(((u32)u) << 16);
}
static __device__ __forceinline__ u16 f2bf(float f) {
  u32 x = __float_as_uint(f);
  return (u16)((x + 0x7fffu + ((x >> 16) & 1u)) >> 16);   // RNE
}
#define MFMA16(a, b, c) __builtin_amdgcn_mfma_f32_16x16x32_bf16((a), (b), (c), 0, 0, 0)

// ---------------- converters ----------------------------------------------
__global__ __launch_bounds__(256) void convx_k(const float* __restrict__ x,
                                               u16* __restrict__ xb) {
  const int i = blockIdx.x * 256 + threadIdx.x;
  float4 f = ((const float4*)x)[i];
  ushort4 u;
  u.x = f2bf(f.x); u.y = f2bf(f.y); u.z = f2bf(f.z); u.w = f2bf(f.w);
  ((ushort4*)xb)[i] = u;
}

__global__ __launch_bounds__(256) void convw_k(
    const float* __restrict__ W0, const float* __restrict__ W1,
    const float* __restrict__ W2, const float* __restrict__ W3,
    u16* __restrict__ out) {
  __shared__ u16 tt[64][66];
  const int z = blockIdx.z;
  const float* W = (z == 0) ? W0 : (z == 1) ? W1 : (z == 2) ? W2 : W3;
  u16* o = out + (size_t)z * 1048576ull;
  const int k0 = blockIdx.y * 64, n0 = blockIdx.x * 64;
  const int r = threadIdx.x >> 4, c4 = (threadIdx.x & 15) << 2;
  for (int rr = r; rr < 64; rr += 16) {
    float4 w4 = *(const float4*)(W + (size_t)(k0 + rr) * DM_ + n0 + c4);
    tt[c4 + 0][rr] = f2bf(w4.x);
    tt[c4 + 1][rr] = f2bf(w4.y);
    tt[c4 + 2][rr] = f2bf(w4.z);
    tt[c4 + 3][rr] = f2bf(w4.w);
  }
  __syncthreads();
  for (int rr = r; rr < 64; rr += 16) {
    ushort4 u4;
    u4.x = tt[rr][c4 + 0];
    u4.y = tt[rr][c4 + 1];
    u4.z = tt[rr][c4 + 2];
    u4.w = tt[rr][c4 + 3];
    *(ushort4*)(o + (size_t)(n0 + rr) * DM_ + k0 + c4) = u4;
  }
}

__global__ __launch_bounds__(256) void convom_k(const float* __restrict__ om,
                                                u16* __restrict__ omb) {
  const int i = blockIdx.x * 256 + threadIdx.x;
  omb[i] = f2bf(om[i] * 0.35355339059327373f);       // fold 64^-0.25
}

// ---------------- merged projection GEMMs (q,k,v), head bf16 out -----------
// grid (1024, 3): y selects {Wq->qb(+nhq), Wk->kb(+nhk), Wv->v}
__global__ __launch_bounds__(256) void mm3_k(
    const u16* __restrict__ A, const u16* __restrict__ Wt,
    const float* __restrict__ bq, const float* __restrict__ bk,
    const float* __restrict__ bv, u16* __restrict__ qb,
    u16* __restrict__ kb, u16* __restrict__ vb,
    float* __restrict__ nhq, float* __restrict__ nhk) {
  __shared__ u16 sA[128][64];   // 16 KB, XOR-swizzled 16B slots
  __shared__ u16 sB[128][64];   // 16 KB
  const int y = blockIdx.y;
  const u16* Bt = Wt + (size_t)y * 1048576ull;
  const float* bias = (y == 0) ? bq : (y == 1) ? bk : bv;
  u16* outp = (y == 0) ? qb : (y == 1) ? kb : vb;
  float* nhout = (y == 0) ? nhq : (y == 1) ? nhk : nullptr;
  const int tid = threadIdx.x, lane = tid & 63, w = tid >> 6;
  const int fr = lane & 15, fg = lane >> 4;
  const int wr = w >> 1, wc = w & 1;
  const int lb = ((blockIdx.x & 7) << 7) | (blockIdx.x >> 3);
  const int m0 = (lb >> 3) * 128, n0 = (lb & 7) * 128;
  const int srow = tid >> 3, sslot = tid & 7;   // +p*32 rows per pass
  f32x4 acc[4][4] = {};
  bf16x8 av[4], bv4[4];
#pragma unroll
  for (int p = 0; p < 4; ++p) {
    av[p]  = *(const bf16x8*)(A  + (size_t)(m0 + srow + p * 32) * DM_ + sslot * 8);
    bv4[p] = *(const bf16x8*)(Bt + (size_t)(n0 + srow + p * 32) * DM_ + sslot * 8);
  }
  for (int k0 = 0; k0 < DM_; k0 += 64) {
    __syncthreads();
#pragma unroll
    for (int p = 0; p < 4; ++p) {
      const int r = srow + p * 32;
      *(bf16x8*)&sA[r][(sslot ^ (r & 7)) * 8] = av[p];
      *(bf16x8*)&sB[r][(sslot ^ (r & 7)) * 8] = bv4[p];
    }
    if (k0 + 64 < DM_) {
#pragma unroll
      for (int p = 0; p < 4; ++p) {
        av[p]  = *(const bf16x8*)(A  + (size_t)(m0 + srow + p * 32) * DM_ + k0 + 64 + sslot * 8);
        bv4[p] = *(const bf16x8*)(Bt + (size_t)(n0 + srow + p * 32) * DM_ + k0 + 64 + sslot * 8);
      }
    }
    __syncthreads();
#pragma unroll
    for (int ks = 0; ks < 2; ++ks) {
      bf16x8 af[4], bf[4];
#pragma unroll
      for (int i = 0; i < 4; ++i) {
        const int r = wr * 64 + i * 16 + fr;
        af[i] = *(const bf16x8*)&sA[r][((ks * 4 + fg) ^ (r & 7)) * 8];
      }
#pragma unroll
      for (int j = 0; j < 4; ++j) {
        const int r = wc * 64 + j * 16 + fr;
        bf[j] = *(const bf16x8*)&sB[r][((ks * 4 + fg) ^ (r & 7)) * 8];
      }
#pragma unroll
      for (int i = 0; i < 4; ++i)
#pragma unroll
        for (int j = 0; j < 4; ++j)
          acc[i][j] = MFMA16(af[i], bf[j], acc[i][j]);
    }
  }
  const int m_blk = m0 + wr * 64, n_blk = n0 + wc * 64;
  float nhacc[4][4] = {};
#pragma unroll
  for (int j = 0; j < 4; ++j) {
    const int n = n_blk + j * 16 + fr;
    const float bi = bias[n];
    const int h = n >> 6, d = n & 63;
#pragma unroll
    for (int i = 0; i < 4; ++i) {
#pragma unroll
      for (int r = 0; r < 4; ++r) {
        const int m = m_blk + i * 16 + fg * 4 + r;
        const float val = acc[i][j][r] + bi;
        const int b = m >> 12, l = m & 4095;
        const u16 sv = f2bf(val);
        outp[((size_t)(b * H_ + h) * L_ + l) * D_ + d] = sv;
        const float rv = bf2f(sv);
        nhacc[i][r] += rv * rv;
      }
    }
  }
  if (nhout) {
    const int hh2 = n_blk >> 6;
#pragma unroll
    for (int i = 0; i < 4; ++i)
#pragma unroll
      for (int r = 0; r < 4; ++r) {
        float s = nhacc[i][r];
        s += __shfl_xor(s, 1, 64);
        s += __shfl_xor(s, 2, 64);
        s += __shfl_xor(s, 4, 64);
        s += __shfl_xor(s, 8, 64);
        if (fr == 0) {
          const int m = m_blk + i * 16 + fg * 4 + r;
          const int b = m >> 12, l = m & 4095;
          nhout[(size_t)(b * H_ + hh2) * L_ + l] = 0.0625f * s;
        }
      }
  }
}

// ---------------- final GEMM (attn bf16 -> f32 out), R15-validated ---------
__global__ __launch_bounds__(256) void mmo_k(
    const u16* __restrict__ A, const u16* __restrict__ Bt,
    const float* __restrict__ bias, float* __restrict__ outp) {
  __shared__ u16 sA[128][64];
  __shared__ u16 sB[128][64];
  const int tid = threadIdx.x, lane = tid & 63, w = tid >> 6;
  const int fr = lane & 15, fg = lane >> 4;
  const int wr = w >> 1, wc = w & 1;
  const int lb = ((blockIdx.x & 7) << 7) | (blockIdx.x >> 3);
  const int m0 = (lb >> 3) * 128, n0 = (lb & 7) * 128;
  const int srow = tid >> 3, sslot = tid & 7;
  f32x4 acc[4][4] = {};
  bf16x8 av[4], bv[4];
#pragma unroll
  for (int p = 0; p < 4; ++p) {
    av[p] = *(const bf16x8*)(A  + (size_t)(m0 + srow + p * 32) * DM_ + sslot * 8);
    bv[p] = *(const bf16x8*)(Bt + (size_t)(n0 + srow + p * 32) * DM_ + sslot * 8);
  }
  for (int k0 = 0; k0 < DM_; k0 += 64) {
    __syncthreads();
#pragma unroll
    for (int p = 0; p < 4; ++p) {
      const int r = srow + p * 32;
      *(bf16x8*)&sA[r][(sslot ^ (r & 7)) * 8] = av[p];
      *(bf16x8*)&sB[r][(sslot ^ (r & 7)) * 8] = bv[p];
    }
    if (k0 + 64 < DM_) {
#pragma unroll
      for (int p = 0; p < 4; ++p) {
        av[p] = *(const bf16x8*)(A  + (size_t)(m0 + srow + p * 32) * DM_ + k0 + 64 + sslot * 8);
        bv[p] = *(const bf16x8*)(Bt + (size_t)(n0 + srow + p * 32) * DM_ + k0 + 64 + sslot * 8);
      }
    }
    __syncthreads();
#pragma unroll
    for (int ks = 0; ks < 2; ++ks) {
      bf16x8 af[4], bf[4];
#pragma unroll
      for (int i = 0; i < 4; ++i) {
        const int r = wr * 64 + i * 16 + fr;
        af[i] = *(const bf16x8*)&sA[r][((ks * 4 + fg) ^ (r & 7)) * 8];
      }
#pragma unroll
      for (int j = 0; j < 4; ++j) {
        const int r = wc * 64 + j * 16 + fr;
        bf[j] = *(const bf16x8*)&sB[r][((ks * 4 + fg) ^ (r & 7)) * 8];
      }
#pragma unroll
      for (int i = 0; i < 4; ++i)
#pragma unroll
        for (int j = 0; j < 4; ++j)
          acc[i][j] = MFMA16(af[i], bf[j], acc[i][j]);
    }
  }
  const int m_blk = m0 + wr * 64, n_blk = n0 + wc * 64;
#pragma unroll
  for (int j = 0; j < 4; ++j) {
    const int n = n_blk + j * 16 + fr;
    const float bi = bias[n];
#pragma unroll
    for (int i = 0; i < 4; ++i)
#pragma unroll
      for (int r = 0; r < 4; ++r) {
        const int m = m_blk + i * 16 + fg * 4 + r;
        outp[(size_t)m * DM_ + n] = acc[i][j][r] + bi;
      }
  }
}

// ---------------- kvstate (MFMA, SC=128): bf16 state + f32 ksum ------------
__global__ __launch_bounds__(256) void kvstate_k(
    const u16* __restrict__ k, const u16* __restrict__ v,
    const u16* __restrict__ omb, const float* __restrict__ nhk,
    u16* __restrict__ stateb, float* __restrict__ ksum) {
  __shared__ u16 sPhi[256][72];
  __shared__ u16 sVt[64][72];
  const int tid = threadIdx.x, lane = tid & 63, w = tid >> 6;
  const int fr = lane & 15, fg = lane >> 4;
  const int sc = blockIdx.x, bh = blockIdx.y;
  const size_t base_l = (size_t)bh * L_ + (size_t)sc * 128;

  bf16x8 ones;
#pragma unroll
  for (int e = 0; e < 8; ++e) ones[e] = (short)0x3F80;

  f32x4 kvacc[4][4] = {};
  f32x4 ksacc[4] = {};

  for (int sub = 0; sub < 2; ++sub) {
    const size_t tl = base_l + sub * 64;
    const u16* kg = k + tl * 64;
    __syncthreads();
    {
      const u16* vp = v + (tl + lane) * 64 + w * 16;
      bf16x8 v0 = *(const bf16x8*)(vp);
      bf16x8 v1 = *(const bf16x8*)(vp + 8);
#pragma unroll
      for (int e = 0; e < 8; ++e) sVt[w * 16 + e][lane] = (u16)v0[e];
#pragma unroll
      for (int e = 0; e < 8; ++e) sVt[w * 16 + 8 + e][lane] = (u16)v1[e];
    }
    float nhr[4];
#pragma unroll
    for (int tt = 0; tt < 4; ++tt) nhr[tt] = nhk[tl + tt * 16 + fr];
#pragma unroll
    for (int mi = 0; mi < 4; ++mi) {
      const int m0 = (w << 6) + mi * 16;
      const bf16x8 a0 = *(const bf16x8*)(omb + (m0 + fr) * 64 + fg * 8);
      const bf16x8 a1 = *(const bf16x8*)(omb + (m0 + fr) * 64 + 32 + fg * 8);
#pragma unroll
      for (int tt = 0; tt < 4; ++tt) {
        const bf16x8 b0 = *(const bf16x8*)(kg + (tt * 16 + fr) * 64 + fg * 8);
        const bf16x8 b1 = *(const bf16x8*)(kg + (tt * 16 + fr) * 64 + 32 + fg * 8);
        f32x4 acc = {0.f, 0.f, 0.f, 0.f};
        acc = MFMA16(a0, b0, acc);
        acc = MFMA16(a1, b1, acc);
        const float nhv = nhr[tt];
#pragma unroll
        for (int r = 0; r < 4; ++r)
          sPhi[m0 + fg * 4 + r][tt * 16 + fr] = f2bf(__expf(acc[r] - nhv) * 0.0625f);
      }
    }
    __syncthreads();
#pragma unroll
    for (int mi = 0; mi < 4; ++mi) {
      const int m0 = (w << 6) + mi * 16;
      const bf16x8 pb0 = *(const bf16x8*)&sPhi[m0 + fr][fg * 8];
      const bf16x8 pb1 = *(const bf16x8*)&sPhi[m0 + fr][32 + fg * 8];
      ksacc[mi] = MFMA16(pb0, ones, ksacc[mi]);
      ksacc[mi] = MFMA16(pb1, ones, ksacc[mi]);
#pragma unroll
      for (int dj = 0; dj < 4; ++dj) {
        const bf16x8 va0 = *(const bf16x8*)&sVt[dj * 16 + fr][fg * 8];
        const bf16x8 va1 = *(const bf16x8*)&sVt[dj * 16 + fr][32 + fg * 8];
        kvacc[mi][dj] = MFMA16(va0, pb0, kvacc[mi][dj]);
        kvacc[mi][dj] = MFMA16(va1, pb1, kvacc[mi][dj]);
      }
    }
  }
  // state bf16 [d][m]; ksum f32
  u16* stb = stateb + (size_t)(bh * NSC + sc) * (M_ * D_);
  float* ksp = ksum + (size_t)(bh * NSC + sc) * M_;
#pragma unroll
  for (int mi = 0; mi < 4; ++mi) {
    const int m = (w << 6) + mi * 16 + fr;
#pragma unroll
    for (int dj = 0; dj < 4; ++dj)
#pragma unroll
      for (int r = 0; r < 4; ++r)
        stb[(size_t)(dj * 16 + fg * 4 + r) * M_ + m] = f2bf(kvacc[mi][dj][r]);
    if (fr == 0) {
#pragma unroll
      for (int r = 0; r < 4; ++r)
        ksp[(w << 6) + mi * 16 + fg * 4 + r] = ksacc[mi][r];
    }
  }
}

// ---------------- exclusive prefix over superchunks (bf16 state) -----------
__global__ __launch_bounds__(256) void scan_k(u16* __restrict__ stateb,
                                              float* __restrict__ ksum) {
  const int bh = blockIdx.y;
  u16* sb = stateb + (size_t)bh * NSC * (M_ * D_);
  const int base = blockIdx.x * 2048 + threadIdx.x * 8;
  float run[8] = {};
  for (int cc = 0; cc < NSC; ++cc) {
    u16* st = sb + (size_t)cc * (M_ * D_) + base;
    ushort4 t0 = *(ushort4*)st;
    ushort4 t1 = *(ushort4*)(st + 4);
    ushort4 w0, w1;
    w0.x = f2bf(run[0]); w0.y = f2bf(run[1]); w0.z = f2bf(run[2]); w0.w = f2bf(run[3]);
    w1.x = f2bf(run[4]); w1.y = f2bf(run[5]); w1.z = f2bf(run[6]); w1.w = f2bf(run[7]);
    *(ushort4*)st = w0;
    *(ushort4*)(st + 4) = w1;
    run[0] += bf2f(t0.x); run[1] += bf2f(t0.y); run[2] += bf2f(t0.z); run[3] += bf2f(t0.w);
    run[4] += bf2f(t1.x); run[5] += bf2f(t1.y); run[6] += bf2f(t1.z); run[7] += bf2f(t1.w);
  }
  if (blockIdx.x == 0) {           // ksum f32 in-place exclusive prefix
    float rk = 0.f;
    for (int cc = 0; cc < NSC; ++cc) {
      float* p = ksum + (size_t)(bh * NSC + cc) * M_ + threadIdx.x;
      const float t = *p;
      *p = rk;
      rk += t;
    }
  }
}

// ---------------- outchunk helpers -----------------------------------------
// phi quadrant: writes ONLY rows of band wb (wb*16..wb*16+15)
static __device__ __forceinline__ void phi_quad(
    const u16* __restrict__ xg, const u16* __restrict__ ombq,
    u16* __restrict__ dst, int dstride, const float* nhv,
    int wb, int lane) {
  const int fr = lane & 15, fg = lane >> 4;
  const int tband = wb * 16;
  const bf16x8 a0 = *(const bf16x8*)(xg + (tband + fr) * 64 + fg * 8);
  const bf16x8 a1 = *(const bf16x8*)(xg + (tband + fr) * 64 + 32 + fg * 8);
#pragma unroll
  for (int j = 0; j < 4; ++j) {
    const bf16x8 b0 = *(const bf16x8*)(ombq + (j * 16 + fr) * 64 + fg * 8);
    const bf16x8 b1 = *(const bf16x8*)(ombq + (j * 16 + fr) * 64 + 32 + fg * 8);
    f32x4 acc = {0.f, 0.f, 0.f, 0.f};
    acc = MFMA16(a0, b0, acc);
    acc = MFMA16(a1, b1, acc);
#pragma unroll
    for (int r = 0; r < 4; ++r) {
      const int t = tband + fg * 4 + r;
      dst[t * dstride + j * 16 + fr] = f2bf(__expf(acc[r] - nhv[r]) * 0.0625f);
    }
  }
}

// ---------------- outchunk: forced 2 blocks/CU -----------------------------
__global__ __launch_bounds__(512, 4) void outchunk_k(
    const u16* __restrict__ q, const u16* __restrict__ kk,
    const u16* __restrict__ v, const u16* __restrict__ omb,
    const u16* __restrict__ stateb, const float* __restrict__ ksum,
    const float* __restrict__ nhq, const float* __restrict__ nhk,
    u16* __restrict__ attn) {
  __shared__ u16 sK0[64][72];     // phi scratch ping / h0 S  9,216 B
  __shared__ u16 sK1[64][72];     // phi scratch pong / h1 S  9,216 B
  __shared__ u16 sB1[64][72];     // vT                       9,216 B
  __shared__ float ksum_l[256];   //  1,024 B    total 28,672 B
  const int tid = threadIdx.x, lane = tid & 63, w = tid >> 6;
  const int h = w >> 2, wl = w & 3;
  const int fr = lane & 15, fg = lane >> 4;
  const int bh = blockIdx.x >> 5, sc = blockIdx.x & 31;
  const size_t tokq = (size_t)bh * L_ + (size_t)sc * 128 + (size_t)h * 64;
  const u16* qg = q + tokq * 64;
  const u16* stgb = stateb + (size_t)(bh * NSC + sc) * (M_ * D_);   // [d][m]
  const float* ksg = ksum + (size_t)(bh * NSC + sc) * M_;

  if (tid < 256) ksum_l[tid] = ksg[tid];

  float nhq4[4];
#pragma unroll
  for (int r = 0; r < 4; ++r) nhq4[r] = nhq[tokq + wl * 16 + fg * 4 + r];

  // phi(q) -> registers via own-half scratch roundtrip (same-wave own-band
  // write->read). Cross term fused: state B-frags loaded before phi.
  u16* myscr = (h == 0) ? &sK0[0][0] : &sK1[0][0];
  bf16x8 qa0[2], qa1[2], qa2[2], qa3[2];
  f32x4 oacc[4] = {};
#define QPHASE(MQ, QA)                                                          \
  {                                                                             \
    bf16x8 b0r[4], b1r[4];                                                      \
    _Pragma("unroll")                                                           \
    for (int j = 0; j < 4; ++j) {                                               \
      b0r[j] = *(const bf16x8*)(stgb + (size_t)(j * 16 + fr) * M_ + MQ * 64 + fg * 8);        \
      b1r[j] = *(const bf16x8*)(stgb + (size_t)(j * 16 + fr) * M_ + MQ * 64 + 32 + fg * 8);   \
    }                                                                           \
    phi_quad(qg, omb + MQ * 4096, myscr, 72, nhq4, wl, lane);                   \
    QA[0] = *(const bf16x8*)(myscr + (wl * 16 + fr) * 72 + fg * 8);             \
    QA[1] = *(const bf16x8*)(myscr + (wl * 16 + fr) * 72 + 32 + fg * 8);        \
    __builtin_amdgcn_s_setprio(1);                                              \
    _Pragma("unroll")                                                           \
    for (int j = 0; j < 4; ++j) {                                               \
      oacc[j] = MFMA16(QA[0], b0r[j], oacc[j]);                                 \
      oacc[j] = MFMA16(QA[1], b1r[j], oacc[j]);                                 \
    }                                                                           \
    __builtin_amdgcn_s_setprio(0);                                              \
  }
  QPHASE(0, qa0)
  QPHASE(1, qa1)
  QPHASE(2, qa2)
  QPHASE(3, qa3)
#undef QPHASE
  __syncthreads();   // BAR P: ksum_l visibility; also fences q-scratch reuse

  // den-ksum from register frags
  float denk = 0.f;
#pragma unroll
  for (int e = 0; e < 8; ++e) {
    denk += bf2f((u16)qa0[0][e]) * ksum_l[0   + fg * 8 + e]
          + bf2f((u16)qa0[1][e]) * ksum_l[32  + fg * 8 + e]
          + bf2f((u16)qa1[0][e]) * ksum_l[64  + fg * 8 + e]
          + bf2f((u16)qa1[1][e]) * ksum_l[96  + fg * 8 + e]
          + bf2f((u16)qa2[0][e]) * ksum_l[128 + fg * 8 + e]
          + bf2f((u16)qa2[1][e]) * ksum_l[160 + fg * 8 + e]
          + bf2f((u16)qa3[0][e]) * ksum_l[192 + fg * 8 + e]
          + bf2f((u16)qa3[1][e]) * ksum_l[224 + fg * 8 + e];
  }
  denk += __shfl_xor(denk, 16, 64);
  denk += __shfl_xor(denk, 32, 64);

  // ---- source chunks s=0,1
  float dS[4] = {0.f, 0.f, 0.f, 0.f};
#pragma unroll 1
  for (int s = 0; s < 2; ++s) {
    const size_t ktok = (size_t)bh * L_ + (size_t)sc * 128 + (size_t)s * 64;
    const u16* kg = kk + ktok * 64;
    const bool part = (h == 1) || (s == 0);
    const bool diag = (s == h);
    float nhk4[4];
#pragma unroll
    for (int r = 0; r < 4; ++r) nhk4[r] = nhk[ktok + wl * 16 + fg * 4 + r];
    f32x4 sacc[4] = {};
    if (h == 0)   // quadrant 0 producer
      phi_quad(kg, omb, &sK0[0][0], 72, nhk4, wl, lane);
    __syncthreads();   // BAR A: quadrant 0 ready; fences prev-phase readers
#define SPHASE(MQ, QA)                                                          \
  {                                                                             \
    u16* nxt = ((MQ & 1) == 0) ? &sK1[0][0] : &sK0[0][0];                       \
    const u16(*cur)[72] = ((MQ & 1) == 0) ? sK0 : sK1;                          \
    if (MQ < 3 && h == ((MQ + 1) & 1))                                          \
      phi_quad(kg, omb + (MQ + 1) * 4096, nxt, 72, nhk4, wl, lane);             \
    if (part) {                                                                 \
      __builtin_amdgcn_s_setprio(1);                                            \
      _Pragma("unroll")                                                         \
      for (int j = 0; j < 4; ++j) {                                             \
        const bf16x8 b0 = *(const bf16x8*)&cur[j * 16 + fr][fg * 8];            \
        const bf16x8 b1 = *(const bf16x8*)&cur[j * 16 + fr][32 + fg * 8];       \
        sacc[j] = MFMA16(QA[0], b0, sacc[j]);                                   \
        sacc[j] = MFMA16(QA[1], b1, sacc[j]);                                   \
      }                                                                         \
      __builtin_amdgcn_s_setprio(0);                                            \
    }                                                                           \
    __syncthreads();   /* quadrant BAR: nxt ready / WAR fence on cur */         \
  }
    SPHASE(0, qa0)
    SPHASE(1, qa1)
    SPHASE(2, qa2)
    SPHASE(3, qa3)
#undef SPHASE
    // S write (half h into its own buffer; own-band rows), dS from rounded val
    u16 (*sS)[72] = (h == 0) ? sK0 : sK1;
    if (part) {
#pragma unroll
      for (int j = 0; j < 4; ++j)
#pragma unroll
        for (int r = 0; r < 4; ++r) {
          const int ss = j * 16 + fr, t = wl * 16 + fg * 4 + r;
          float val = sacc[j][r];
          if (diag && ss > t) val = 0.f;
          const u16 vb = f2bf(val);
          sS[t][ss] = vb;
          dS[r] += bf2f(vb);
        }
    }
    if (h == 0) {  // vT staging (bands wl*16; prior readers fenced by BAR A)
      const u16* vp = v + (ktok + lane) * 64 + wl * 16;
      bf16x8 v0 = *(const bf16x8*)(vp);
      bf16x8 v1 = *(const bf16x8*)(vp + 8);
#pragma unroll
      for (int e = 0; e < 8; ++e) sB1[wl * 16 + e][lane] = (u16)v0[e];
#pragma unroll
      for (int e = 0; e < 8; ++e) sB1[wl * 16 + 8 + e][lane] = (u16)v1[e];
    }
    __syncthreads();   // BAR F: S buffers + vT visible
    if (part) {        // S @ V (A: own buffer own band; B: sB1 cross-band)
      const bf16x8 a0 = *(const bf16x8*)&sS[wl * 16 + fr][fg * 8];
      const bf16x8 a1 = *(const bf16x8*)&sS[wl * 16 + fr][32 + fg * 8];
      __builtin_amdgcn_s_setprio(1);
#pragma unroll
      for (int j = 0; j < 4; ++j) {
        const bf16x8 b0 = *(const bf16x8*)&sB1[j * 16 + fr][fg * 8];
        const bf16x8 b1 = *(const bf16x8*)&sB1[j * 16 + fr][32 + fg * 8];
        oacc[j] = MFMA16(a0, b0, oacc[j]);
        oacc[j] = MFMA16(a1, b1, oacc[j]);
      }
      __builtin_amdgcn_s_setprio(0);
    }
    // no trailing barrier: next phase's BAR A fences sB1/sK1; sK0's next
    // writer (phi0 by half0) follows its own wave's reads (in-order LDS).
  }

  // den: reduce dS over fr lanes; combine with denk via shfl
#pragma unroll
  for (int m2 = 1; m2 <= 8; m2 <<= 1) {
#pragma unroll
    for (int r = 0; r < 4; ++r) dS[r] += __shfl_xor(dS[r], m2, 64);
  }
  const int b = bh >> 4, hh = bh & 15;
#pragma unroll
  for (int r = 0; r < 4; ++r) {
    const float dk = __shfl(denk, fg * 4 + r, 64);   // token wl*16+fg*4+r
    const float rinv = 1.0f / (dk + dS[r] + 1e-6f);
    const int t = wl * 16 + fg * 4 + r;
    const int l = sc * 128 + h * 64 + t;
#pragma unroll
    for (int j = 0; j < 4; ++j) {
      const int d = j * 16 + fr;
      attn[((size_t)b * L_ + l) * DM_ + hh * 64 + d] = f2bf(oacc[j][r] * rinv);
    }
  }
}

extern "C" void kernel_launch(void* const* d_in, const int* in_sizes, int n_in,
                              void* d_out, int out_size, void* d_ws, size_t ws_size,
                              hipStream_t stream) {
  const float* x     = (const float*)d_in[0];
  const float* Wq    = (const float*)d_in[1];
  const float* bq    = (const float*)d_in[2];
  const float* Wk    = (const float*)d_in[3];
  const float* bk    = (const float*)d_in[4];
  const float* Wv    = (const float*)d_in[5];
  const float* bv    = (const float*)d_in[6];
  const float* Wo    = (const float*)d_in[7];
  const float* bo    = (const float*)d_in[8];
  const float* omega = (const float*)d_in[9];
  float* out = (float*)d_out;

  char* ws = (char*)d_ws;
  u16*   v      = (u16*)(ws);                           // 32 MB
  u16*   qb     = (u16*)(ws + 33554432ull);             // 32 MB
  u16*   kb     = (u16*)(ws + 67108864ull);             // 32 MB
  u16*   xb     = (u16*)(ws + 100663296ull);            // 32 MB (alias attn)
  u16*   attn   = xb;
  u16*   stateb = (u16*)(ws + 134217728ull);            // 64 MB
  float* ksum   = (float*)(ws + 201326592ull);          // 2 MB
  u16*   Wt     = (u16*)(ws + 203423744ull);            // 8 MB
  u16*   omb    = (u16*)(ws + 211812352ull);            // 32 KB
  float* nhq    = (float*)(ws + 211845120ull);          // 1 MB
  float* nhk    = (float*)(ws + 212893696ull);          // 1 MB -> 204 MB

  convx_k<<<16384, 256, 0, stream>>>(x, xb);
  convw_k<<<dim3(16, 16, 4), 256, 0, stream>>>(Wq, Wk, Wv, Wo, Wt);
  convom_k<<<64, 256, 0, stream>>>(omega, omb);

  mm3_k<<<dim3(1024, 3), 256, 0, stream>>>(xb, Wt, bq, bk, bv,
                                           qb, kb, v, nhq, nhk);
  kvstate_k<<<dim3(NSC, BH_), 256, 0, stream>>>(kb, v, omb, nhk, stateb, ksum);
  scan_k<<<dim3(8, BH_), 256, 0, stream>>>(stateb, ksum);
  outchunk_k<<<BH_ * NSC, 512, 0, stream>>>(qb, kb, v, omb, stateb, ksum,
                                            nhq, nhk, attn);
  mmo_k<<<1024, 256, 0, stream>>>(attn, Wt + 3145728ull, bo, out);
}

// Round 17
// 550.028 us; speedup vs baseline: 1.0303x; 1.0303x over previous
//
#include <hip/hip_runtime.h>
#include <hip/hip_bf16.h>

// FAVOR+ attention, MI355X. Round 17:
//  - outchunk: revert launch bound to (512) [R16's (512,4) forced VGPR=64 ->
//    270 MB scratch spill]; add T14 early V-issue (chunk's v loads issued at
//    chunk start, ~500cy HBM latency hidden under BAR A + 4 S-phases).
//  - convs merged into one prep_k dispatch (grid 17472, block-uniform branch).
//  - mm3_k / mmo_k / kvstate / scan: byte-identical to validated R16/R15.
//
// Workspace (bytes), total 213,942,272 (~204 MB):
//   v      bf16 [64bh][4096][64]   @ 0            (32 MB)
//   q      bf16                    @ 33,554,432   (32 MB)
//   k      bf16                    @ 67,108,864   (32 MB)
//   xb     bf16 [16384][1024]      @ 100,663,296  (32 MB) -- ALIASED attn
//   stateb bf16 [64bh][32][16384]  @ 134,217,728  (64 MB)
//   ksum   f32  [64bh][32][256]    @ 201,326,592  (2 MB)
//   Wt     bf16 4x[1024][1024]     @ 203,423,744  (8 MB)
//   omb    bf16 [256][64]          @ 211,812,352  (32 KB)
//   nhq    f32  [64bh][4096]       @ 211,845,120  (1 MB)
//   nhk    f32  [64bh][4096]       @ 212,893,696  (1 MB)

#define B_ 4
#define H_ 16
#define L_ 4096
#define D_ 64
#define M_ 256
#define DM_ 1024
#define BH_ 64
#define NSC 32            // superchunks per bh (SC = 128 tokens)

typedef unsigned int u32;
typedef unsigned short u16;
typedef __attribute__((ext_vector_type(8))) short bf16x8;
typedef __attribute__((ext_vector_type(4))) float f32x4;

static __device__ __forceinline__ float bf2f(u16 u) {
  return __uint_as_float(((u32)u) << 16);
}
static __device__ __forceinline__ u16 f2bf(float f) {
  u32 x = __float_as_uint(f);
  return (u16)((x + 0x7fffu + ((x >> 16) & 1u)) >> 16);   // RNE
}
#define MFMA16(a, b, c) __builtin_amdgcn_mfma_f32_16x16x32_bf16((a), (b), (c), 0, 0, 0)

// ---------------- merged prep: convx | convw | convom ----------------------
// grid 17472: [0,16384) convx; [16384,17408) convw; [17408,17472) convom
__global__ __launch_bounds__(256) void prep_k(
    const float* __restrict__ x, u16* __restrict__ xb,
    const float* __restrict__ W0, const float* __restrict__ W1,
    const float* __restrict__ W2, const float* __restrict__ W3,
    u16* __restrict__ Wt, const float* __restrict__ om,
    u16* __restrict__ omb) {
  __shared__ u16 tt[64][66];
  const int bid = blockIdx.x, tid = threadIdx.x;
  if (bid < 16384) {
    const int i = bid * 256 + tid;
    float4 f = ((const float4*)x)[i];
    ushort4 u;
    u.x = f2bf(f.x); u.y = f2bf(f.y); u.z = f2bf(f.z); u.w = f2bf(f.w);
    ((ushort4*)xb)[i] = u;
  } else if (bid < 17408) {
    const int rem = bid - 16384;
    const int z = rem >> 8, r2 = rem & 255;
    const int k0 = (r2 >> 4) * 64, n0 = (r2 & 15) * 64;
    const float* W = (z == 0) ? W0 : (z == 1) ? W1 : (z == 2) ? W2 : W3;
    u16* o = Wt + (size_t)z * 1048576ull;
    const int r = tid >> 4, c4 = (tid & 15) << 2;
    for (int rr = r; rr < 64; rr += 16) {
      float4 w4 = *(const float4*)(W + (size_t)(k0 + rr) * DM_ + n0 + c4);
      tt[c4 + 0][rr] = f2bf(w4.x);
      tt[c4 + 1][rr] = f2bf(w4.y);
      tt[c4 + 2][rr] = f2bf(w4.z);
      tt[c4 + 3][rr] = f2bf(w4.w);
    }
    __syncthreads();
    for (int rr = r; rr < 64; rr += 16) {
      ushort4 u4;
      u4.x = tt[rr][c4 + 0];
      u4.y = tt[rr][c4 + 1];
      u4.z = tt[rr][c4 + 2];
      u4.w = tt[rr][c4 + 3];
      *(ushort4*)(o + (size_t)(n0 + rr) * DM_ + k0 + c4) = u4;
    }
  } else {
    const int i = (bid - 17408) * 256 + tid;
    omb[i] = f2bf(om[i] * 0.35355339059327373f);     // fold 64^-0.25
  }
}

// ---------------- merged projection GEMMs (q,k,v), head bf16 out -----------
// grid (1024, 3): y selects {Wq->qb(+nhq), Wk->kb(+nhk), Wv->v}
__global__ __launch_bounds__(256) void mm3_k(
    const u16* __restrict__ A, const u16* __restrict__ Wt,
    const float* __restrict__ bq, const float* __restrict__ bk,
    const float* __restrict__ bv, u16* __restrict__ qb,
    u16* __restrict__ kb, u16* __restrict__ vb,
    float* __restrict__ nhq, float* __restrict__ nhk) {
  __shared__ u16 sA[128][64];   // 16 KB, XOR-swizzled 16B slots
  __shared__ u16 sB[128][64];   // 16 KB
  const int y = blockIdx.y;
  const u16* Bt = Wt + (size_t)y * 1048576ull;
  const float* bias = (y == 0) ? bq : (y == 1) ? bk : bv;
  u16* outp = (y == 0) ? qb : (y == 1) ? kb : vb;
  float* nhout = (y == 0) ? nhq : (y == 1) ? nhk : nullptr;
  const int tid = threadIdx.x, lane = tid & 63, w = tid >> 6;
  const int fr = lane & 15, fg = lane >> 4;
  const int wr = w >> 1, wc = w & 1;
  const int lb = ((blockIdx.x & 7) << 7) | (blockIdx.x >> 3);
  const int m0 = (lb >> 3) * 128, n0 = (lb & 7) * 128;
  const int srow = tid >> 3, sslot = tid & 7;   // +p*32 rows per pass
  f32x4 acc[4][4] = {};
  bf16x8 av[4], bv4[4];
#pragma unroll
  for (int p = 0; p < 4; ++p) {
    av[p]  = *(const bf16x8*)(A  + (size_t)(m0 + srow + p * 32) * DM_ + sslot * 8);
    bv4[p] = *(const bf16x8*)(Bt + (size_t)(n0 + srow + p * 32) * DM_ + sslot * 8);
  }
  for (int k0 = 0; k0 < DM_; k0 += 64) {
    __syncthreads();
#pragma unroll
    for (int p = 0; p < 4; ++p) {
      const int r = srow + p * 32;
      *(bf16x8*)&sA[r][(sslot ^ (r & 7)) * 8] = av[p];
      *(bf16x8*)&sB[r][(sslot ^ (r & 7)) * 8] = bv4[p];
    }
    if (k0 + 64 < DM_) {
#pragma unroll
      for (int p = 0; p < 4; ++p) {
        av[p]  = *(const bf16x8*)(A  + (size_t)(m0 + srow + p * 32) * DM_ + k0 + 64 + sslot * 8);
        bv4[p] = *(const bf16x8*)(Bt + (size_t)(n0 + srow + p * 32) * DM_ + k0 + 64 + sslot * 8);
      }
    }
    __syncthreads();
#pragma unroll
    for (int ks = 0; ks < 2; ++ks) {
      bf16x8 af[4], bf[4];
#pragma unroll
      for (int i = 0; i < 4; ++i) {
        const int r = wr * 64 + i * 16 + fr;
        af[i] = *(const bf16x8*)&sA[r][((ks * 4 + fg) ^ (r & 7)) * 8];
      }
#pragma unroll
      for (int j = 0; j < 4; ++j) {
        const int r = wc * 64 + j * 16 + fr;
        bf[j] = *(const bf16x8*)&sB[r][((ks * 4 + fg) ^ (r & 7)) * 8];
      }
#pragma unroll
      for (int i = 0; i < 4; ++i)
#pragma unroll
        for (int j = 0; j < 4; ++j)
          acc[i][j] = MFMA16(af[i], bf[j], acc[i][j]);
    }
  }
  const int m_blk = m0 + wr * 64, n_blk = n0 + wc * 64;
  float nhacc[4][4] = {};
#pragma unroll
  for (int j = 0; j < 4; ++j) {
    const int n = n_blk + j * 16 + fr;
    const float bi = bias[n];
    const int h = n >> 6, d = n & 63;
#pragma unroll
    for (int i = 0; i < 4; ++i) {
#pragma unroll
      for (int r = 0; r < 4; ++r) {
        const int m = m_blk + i * 16 + fg * 4 + r;
        const float val = acc[i][j][r] + bi;
        const int b = m >> 12, l = m & 4095;
        const u16 sv = f2bf(val);
        outp[((size_t)(b * H_ + h) * L_ + l) * D_ + d] = sv;
        const float rv = bf2f(sv);
        nhacc[i][r] += rv * rv;
      }
    }
  }
  if (nhout) {
    const int hh2 = n_blk >> 6;
#pragma unroll
    for (int i = 0; i < 4; ++i)
#pragma unroll
      for (int r = 0; r < 4; ++r) {
        float s = nhacc[i][r];
        s += __shfl_xor(s, 1, 64);
        s += __shfl_xor(s, 2, 64);
        s += __shfl_xor(s, 4, 64);
        s += __shfl_xor(s, 8, 64);
        if (fr == 0) {
          const int m = m_blk + i * 16 + fg * 4 + r;
          const int b = m >> 12, l = m & 4095;
          nhout[(size_t)(b * H_ + hh2) * L_ + l] = 0.0625f * s;
        }
      }
  }
}

// ---------------- final GEMM (attn bf16 -> f32 out), validated -------------
__global__ __launch_bounds__(256) void mmo_k(
    const u16* __restrict__ A, const u16* __restrict__ Bt,
    const float* __restrict__ bias, float* __restrict__ outp) {
  __shared__ u16 sA[128][64];
  __shared__ u16 sB[128][64];
  const int tid = threadIdx.x, lane = tid & 63, w = tid >> 6;
  const int fr = lane & 15, fg = lane >> 4;
  const int wr = w >> 1, wc = w & 1;
  const int lb = ((blockIdx.x & 7) << 7) | (blockIdx.x >> 3);
  const int m0 = (lb >> 3) * 128, n0 = (lb & 7) * 128;
  const int srow = tid >> 3, sslot = tid & 7;
  f32x4 acc[4][4] = {};
  bf16x8 av[4], bv[4];
#pragma unroll
  for (int p = 0; p < 4; ++p) {
    av[p] = *(const bf16x8*)(A  + (size_t)(m0 + srow + p * 32) * DM_ + sslot * 8);
    bv[p] = *(const bf16x8*)(Bt + (size_t)(n0 + srow + p * 32) * DM_ + sslot * 8);
  }
  for (int k0 = 0; k0 < DM_; k0 += 64) {
    __syncthreads();
#pragma unroll
    for (int p = 0; p < 4; ++p) {
      const int r = srow + p * 32;
      *(bf16x8*)&sA[r][(sslot ^ (r & 7)) * 8] = av[p];
      *(bf16x8*)&sB[r][(sslot ^ (r & 7)) * 8] = bv[p];
    }
    if (k0 + 64 < DM_) {
#pragma unroll
      for (int p = 0; p < 4; ++p) {
        av[p] = *(const bf16x8*)(A  + (size_t)(m0 + srow + p * 32) * DM_ + k0 + 64 + sslot * 8);
        bv[p] = *(const bf16x8*)(Bt + (size_t)(n0 + srow + p * 32) * DM_ + k0 + 64 + sslot * 8);
      }
    }
    __syncthreads();
#pragma unroll
    for (int ks = 0; ks < 2; ++ks) {
      bf16x8 af[4], bf[4];
#pragma unroll
      for (int i = 0; i < 4; ++i) {
        const int r = wr * 64 + i * 16 + fr;
        af[i] = *(const bf16x8*)&sA[r][((ks * 4 + fg) ^ (r & 7)) * 8];
      }
#pragma unroll
      for (int j = 0; j < 4; ++j) {
        const int r = wc * 64 + j * 16 + fr;
        bf[j] = *(const bf16x8*)&sB[r][((ks * 4 + fg) ^ (r & 7)) * 8];
      }
#pragma unroll
      for (int i = 0; i < 4; ++i)
#pragma unroll
        for (int j = 0; j < 4; ++j)
          acc[i][j] = MFMA16(af[i], bf[j], acc[i][j]);
    }
  }
  const int m_blk = m0 + wr * 64, n_blk = n0 + wc * 64;
#pragma unroll
  for (int j = 0; j < 4; ++j) {
    const int n = n_blk + j * 16 + fr;
    const float bi = bias[n];
#pragma unroll
    for (int i = 0; i < 4; ++i)
#pragma unroll
      for (int r = 0; r < 4; ++r) {
        const int m = m_blk + i * 16 + fg * 4 + r;
        outp[(size_t)m * DM_ + n] = acc[i][j][r] + bi;
      }
  }
}

// ---------------- kvstate (MFMA, SC=128): bf16 state + f32 ksum ------------
__global__ __launch_bounds__(256) void kvstate_k(
    const u16* __restrict__ k, const u16* __restrict__ v,
    const u16* __restrict__ omb, const float* __restrict__ nhk,
    u16* __restrict__ stateb, float* __restrict__ ksum) {
  __shared__ u16 sPhi[256][72];
  __shared__ u16 sVt[64][72];
  const int tid = threadIdx.x, lane = tid & 63, w = tid >> 6;
  const int fr = lane & 15, fg = lane >> 4;
  const int sc = blockIdx.x, bh = blockIdx.y;
  const size_t base_l = (size_t)bh * L_ + (size_t)sc * 128;

  bf16x8 ones;
#pragma unroll
  for (int e = 0; e < 8; ++e) ones[e] = (short)0x3F80;

  f32x4 kvacc[4][4] = {};
  f32x4 ksacc[4] = {};

  for (int sub = 0; sub < 2; ++sub) {
    const size_t tl = base_l + sub * 64;
    const u16* kg = k + tl * 64;
    __syncthreads();
    {
      const u16* vp = v + (tl + lane) * 64 + w * 16;
      bf16x8 v0 = *(const bf16x8*)(vp);
      bf16x8 v1 = *(const bf16x8*)(vp + 8);
#pragma unroll
      for (int e = 0; e < 8; ++e) sVt[w * 16 + e][lane] = (u16)v0[e];
#pragma unroll
      for (int e = 0; e < 8; ++e) sVt[w * 16 + 8 + e][lane] = (u16)v1[e];
    }
    float nhr[4];
#pragma unroll
    for (int tt = 0; tt < 4; ++tt) nhr[tt] = nhk[tl + tt * 16 + fr];
#pragma unroll
    for (int mi = 0; mi < 4; ++mi) {
      const int m0 = (w << 6) + mi * 16;
      const bf16x8 a0 = *(const bf16x8*)(omb + (m0 + fr) * 64 + fg * 8);
      const bf16x8 a1 = *(const bf16x8*)(omb + (m0 + fr) * 64 + 32 + fg * 8);
#pragma unroll
      for (int tt = 0; tt < 4; ++tt) {
        const bf16x8 b0 = *(const bf16x8*)(kg + (tt * 16 + fr) * 64 + fg * 8);
        const bf16x8 b1 = *(const bf16x8*)(kg + (tt * 16 + fr) * 64 + 32 + fg * 8);
        f32x4 acc = {0.f, 0.f, 0.f, 0.f};
        acc = MFMA16(a0, b0, acc);
        acc = MFMA16(a1, b1, acc);
        const float nhv = nhr[tt];
#pragma unroll
        for (int r = 0; r < 4; ++r)
          sPhi[m0 + fg * 4 + r][tt * 16 + fr] = f2bf(__expf(acc[r] - nhv) * 0.0625f);
      }
    }
    __syncthreads();
#pragma unroll
    for (int mi = 0; mi < 4; ++mi) {
      const int m0 = (w << 6) + mi * 16;
      const bf16x8 pb0 = *(const bf16x8*)&sPhi[m0 + fr][fg * 8];
      const bf16x8 pb1 = *(const bf16x8*)&sPhi[m0 + fr][32 + fg * 8];
      ksacc[mi] = MFMA16(pb0, ones, ksacc[mi]);
      ksacc[mi] = MFMA16(pb1, ones, ksacc[mi]);
#pragma unroll
      for (int dj = 0; dj < 4; ++dj) {
        const bf16x8 va0 = *(const bf16x8*)&sVt[dj * 16 + fr][fg * 8];
        const bf16x8 va1 = *(const bf16x8*)&sVt[dj * 16 + fr][32 + fg * 8];
        kvacc[mi][dj] = MFMA16(va0, pb0, kvacc[mi][dj]);
        kvacc[mi][dj] = MFMA16(va1, pb1, kvacc[mi][dj]);
      }
    }
  }
  // state bf16 [d][m]; ksum f32
  u16* stb = stateb + (size_t)(bh * NSC + sc) * (M_ * D_);
  float* ksp = ksum + (size_t)(bh * NSC + sc) * M_;
#pragma unroll
  for (int mi = 0; mi < 4; ++mi) {
    const int m = (w << 6) + mi * 16 + fr;
#pragma unroll
    for (int dj = 0; dj < 4; ++dj)
#pragma unroll
      for (int r = 0; r < 4; ++r)
        stb[(size_t)(dj * 16 + fg * 4 + r) * M_ + m] = f2bf(kvacc[mi][dj][r]);
    if (fr == 0) {
#pragma unroll
      for (int r = 0; r < 4; ++r)
        ksp[(w << 6) + mi * 16 + fg * 4 + r] = ksacc[mi][r];
    }
  }
}

// ---------------- exclusive prefix over superchunks (bf16 state) -----------
__global__ __launch_bounds__(256) void scan_k(u16* __restrict__ stateb,
                                              float* __restrict__ ksum) {
  const int bh = blockIdx.y;
  u16* sb = stateb + (size_t)bh * NSC * (M_ * D_);
  const int base = blockIdx.x * 2048 + threadIdx.x * 8;
  float run[8] = {};
  for (int cc = 0; cc < NSC; ++cc) {
    u16* st = sb + (size_t)cc * (M_ * D_) + base;
    ushort4 t0 = *(ushort4*)st;
    ushort4 t1 = *(ushort4*)(st + 4);
    ushort4 w0, w1;
    w0.x = f2bf(run[0]); w0.y = f2bf(run[1]); w0.z = f2bf(run[2]); w0.w = f2bf(run[3]);
    w1.x = f2bf(run[4]); w1.y = f2bf(run[5]); w1.z = f2bf(run[6]); w1.w = f2bf(run[7]);
    *(ushort4*)st = w0;
    *(ushort4*)(st + 4) = w1;
    run[0] += bf2f(t0.x); run[1] += bf2f(t0.y); run[2] += bf2f(t0.z); run[3] += bf2f(t0.w);
    run[4] += bf2f(t1.x); run[5] += bf2f(t1.y); run[6] += bf2f(t1.z); run[7] += bf2f(t1.w);
  }
  if (blockIdx.x == 0) {           // ksum f32 in-place exclusive prefix
    float rk = 0.f;
    for (int cc = 0; cc < NSC; ++cc) {
      float* p = ksum + (size_t)(bh * NSC + cc) * M_ + threadIdx.x;
      const float t = *p;
      *p = rk;
      rk += t;
    }
  }
}

// ---------------- outchunk helpers -----------------------------------------
// phi quadrant: writes ONLY rows of band wb (wb*16..wb*16+15)
static __device__ __forceinline__ void phi_quad(
    const u16* __restrict__ xg, const u16* __restrict__ ombq,
    u16* __restrict__ dst, int dstride, const float* nhv,
    int wb, int lane) {
  const int fr = lane & 15, fg = lane >> 4;
  const int tband = wb * 16;
  const bf16x8 a0 = *(const bf16x8*)(xg + (tband + fr) * 64 + fg * 8);
  const bf16x8 a1 = *(const bf16x8*)(xg + (tband + fr) * 64 + 32 + fg * 8);
#pragma unroll
  for (int j = 0; j < 4; ++j) {
    const bf16x8 b0 = *(const bf16x8*)(ombq + (j * 16 + fr) * 64 + fg * 8);
    const bf16x8 b1 = *(const bf16x8*)(ombq + (j * 16 + fr) * 64 + 32 + fg * 8);
    f32x4 acc = {0.f, 0.f, 0.f, 0.f};
    acc = MFMA16(a0, b0, acc);
    acc = MFMA16(a1, b1, acc);
#pragma unroll
    for (int r = 0; r < 4; ++r) {
      const int t = tband + fg * 4 + r;
      dst[t * dstride + j * 16 + fr] = f2bf(__expf(acc[r] - nhv[r]) * 0.0625f);
    }
  }
}

// ---------------- outchunk: R15 structure + early V-issue ------------------
__global__ __launch_bounds__(512) void outchunk_k(
    const u16* __restrict__ q, const u16* __restrict__ kk,
    const u16* __restrict__ v, const u16* __restrict__ omb,
    const u16* __restrict__ stateb, const float* __restrict__ ksum,
    const float* __restrict__ nhq, const float* __restrict__ nhk,
    u16* __restrict__ attn) {
  __shared__ u16 sK0[64][72];     // phi scratch ping / h0 S  9,216 B
  __shared__ u16 sK1[64][72];     // phi scratch pong / h1 S  9,216 B
  __shared__ u16 sB1[64][72];     // vT                       9,216 B
  __shared__ float ksum_l[256];   //  1,024 B    total 28,672 B
  const int tid = threadIdx.x, lane = tid & 63, w = tid >> 6;
  const int h = w >> 2, wl = w & 3;
  const int fr = lane & 15, fg = lane >> 4;
  const int bh = blockIdx.x >> 5, sc = blockIdx.x & 31;
  const size_t tokq = (size_t)bh * L_ + (size_t)sc * 128 + (size_t)h * 64;
  const u16* qg = q + tokq * 64;
  const u16* stgb = stateb + (size_t)(bh * NSC + sc) * (M_ * D_);   // [d][m]
  const float* ksg = ksum + (size_t)(bh * NSC + sc) * M_;

  if (tid < 256) ksum_l[tid] = ksg[tid];

  float nhq4[4];
#pragma unroll
  for (int r = 0; r < 4; ++r) nhq4[r] = nhq[tokq + wl * 16 + fg * 4 + r];

  // phi(q) -> registers via own-half scratch roundtrip (same-wave own-band
  // write->read). Cross term fused: state B-frags loaded before phi.
  u16* myscr = (h == 0) ? &sK0[0][0] : &sK1[0][0];
  bf16x8 qa0[2], qa1[2], qa2[2], qa3[2];
  f32x4 oacc[4] = {};
#define QPHASE(MQ, QA)                                                          \
  {                                                                             \
    bf16x8 b0r[4], b1r[4];                                                      \
    _Pragma("unroll")                                                           \
    for (int j = 0; j < 4; ++j) {                                               \
      b0r[j] = *(const bf16x8*)(stgb + (size_t)(j * 16 + fr) * M_ + MQ * 64 + fg * 8);        \
      b1r[j] = *(const bf16x8*)(stgb + (size_t)(j * 16 + fr) * M_ + MQ * 64 + 32 + fg * 8);   \
    }                                                                           \
    phi_quad(qg, omb + MQ * 4096, myscr, 72, nhq4, wl, lane);                   \
    QA[0] = *(const bf16x8*)(myscr + (wl * 16 + fr) * 72 + fg * 8);             \
    QA[1] = *(const bf16x8*)(myscr + (wl * 16 + fr) * 72 + 32 + fg * 8);        \
    __builtin_amdgcn_s_setprio(1);                                              \
    _Pragma("unroll")                                                           \
    for (int j = 0; j < 4; ++j) {                                               \
      oacc[j] = MFMA16(QA[0], b0r[j], oacc[j]);                                 \
      oacc[j] = MFMA16(QA[1], b1r[j], oacc[j]);                                 \
    }                                                                           \
    __builtin_amdgcn_s_setprio(0);                                              \
  }
  QPHASE(0, qa0)
  QPHASE(1, qa1)
  QPHASE(2, qa2)
  QPHASE(3, qa3)
#undef QPHASE
  __syncthreads();   // BAR P: ksum_l visibility; also fences q-scratch reuse

  // den-ksum from register frags
  float denk = 0.f;
#pragma unroll
  for (int e = 0; e < 8; ++e) {
    denk += bf2f((u16)qa0[0][e]) * ksum_l[0   + fg * 8 + e]
          + bf2f((u16)qa0[1][e]) * ksum_l[32  + fg * 8 + e]
          + bf2f((u16)qa1[0][e]) * ksum_l[64  + fg * 8 + e]
          + bf2f((u16)qa1[1][e]) * ksum_l[96  + fg * 8 + e]
          + bf2f((u16)qa2[0][e]) * ksum_l[128 + fg * 8 + e]
          + bf2f((u16)qa2[1][e]) * ksum_l[160 + fg * 8 + e]
          + bf2f((u16)qa3[0][e]) * ksum_l[192 + fg * 8 + e]
          + bf2f((u16)qa3[1][e]) * ksum_l[224 + fg * 8 + e];
  }
  denk += __shfl_xor(denk, 16, 64);
  denk += __shfl_xor(denk, 32, 64);

  // ---- source chunks s=0,1
  float dS[4] = {0.f, 0.f, 0.f, 0.f};
#pragma unroll 1
  for (int s = 0; s < 2; ++s) {
    const size_t ktok = (size_t)bh * L_ + (size_t)sc * 128 + (size_t)s * 64;
    const u16* kg = kk + ktok * 64;
    const bool part = (h == 1) || (s == 0);
    const bool diag = (s == h);
    float nhk4[4];
#pragma unroll
    for (int r = 0; r < 4; ++r) nhk4[r] = nhk[ktok + wl * 16 + fg * 4 + r];
    // T14 early V-issue: loads in flight across BAR A + 4 S-phases
    bf16x8 v0 = {}, v1 = {};
    if (h == 0) {
      const u16* vp = v + (ktok + lane) * 64 + wl * 16;
      v0 = *(const bf16x8*)(vp);
      v1 = *(const bf16x8*)(vp + 8);
    }
    f32x4 sacc[4] = {};
    if (h == 0)   // quadrant 0 producer
      phi_quad(kg, omb, &sK0[0][0], 72, nhk4, wl, lane);
    __syncthreads();   // BAR A: quadrant 0 ready; fences prev-phase readers
#define SPHASE(MQ, QA)                                                          \
  {                                                                             \
    u16* nxt = ((MQ & 1) == 0) ? &sK1[0][0] : &sK0[0][0];                       \
    const u16(*cur)[72] = ((MQ & 1) == 0) ? sK0 : sK1;                          \
    if (MQ < 3 && h == ((MQ + 1) & 1))                                          \
      phi_quad(kg, omb + (MQ + 1) * 4096, nxt, 72, nhk4, wl, lane);             \
    if (part) {                                                                 \
      __builtin_amdgcn_s_setprio(1);                                            \
      _Pragma("unroll")                                                         \
      for (int j = 0; j < 4; ++j) {                                             \
        const bf16x8 b0 = *(const bf16x8*)&cur[j * 16 + fr][fg * 8];            \
        const bf16x8 b1 = *(const bf16x8*)&cur[j * 16 + fr][32 + fg * 8];       \
        sacc[j] = MFMA16(QA[0], b0, sacc[j]);                                   \
        sacc[j] = MFMA16(QA[1], b1, sacc[j]);                                   \
      }                                                                         \
      __builtin_amdgcn_s_setprio(0);                                            \
    }                                                                           \
    __syncthreads();   /* quadrant BAR: nxt ready / WAR fence on cur */         \
  }
    SPHASE(0, qa0)
    SPHASE(1, qa1)
    SPHASE(2, qa2)
    SPHASE(3, qa3)
#undef SPHASE
    // S write (half h into its own buffer; own-band rows), dS from rounded val
    u16 (*sS)[72] = (h == 0) ? sK0 : sK1;
    if (part) {
#pragma unroll
      for (int j = 0; j < 4; ++j)
#pragma unroll
        for (int r = 0; r < 4; ++r) {
          const int ss = j * 16 + fr, t = wl * 16 + fg * 4 + r;
          float val = sacc[j][r];
          if (diag && ss > t) val = 0.f;
          const u16 vb = f2bf(val);
          sS[t][ss] = vb;
          dS[r] += bf2f(vb);
        }
    }
    if (h == 0) {  // vT staging from early-issued regs
#pragma unroll
      for (int e = 0; e < 8; ++e) sB1[wl * 16 + e][lane] = (u16)v0[e];
#pragma unroll
      for (int e = 0; e < 8; ++e) sB1[wl * 16 + 8 + e][lane] = (u16)v1[e];
    }
    __syncthreads();   // BAR F: S buffers + vT visible
    if (part) {        // S @ V (A: own buffer own band; B: sB1 cross-band)
      const bf16x8 a0 = *(const bf16x8*)&sS[wl * 16 + fr][fg * 8];
      const bf16x8 a1 = *(const bf16x8*)&sS[wl * 16 + fr][32 + fg * 8];
      __builtin_amdgcn_s_setprio(1);
#pragma unroll
      for (int j = 0; j < 4; ++j) {
        const bf16x8 b0 = *(const bf16x8*)&sB1[j * 16 + fr][fg * 8];
        const bf16x8 b1 = *(const bf16x8*)&sB1[j * 16 + fr][32 + fg * 8];
        oacc[j] = MFMA16(a0, b0, oacc[j]);
        oacc[j] = MFMA16(a1, b1, oacc[j]);
      }
      __builtin_amdgcn_s_setprio(0);
    }
    // no trailing barrier: next phase's BAR A fences sB1/sK1; sK0's next
    // writer (phi0 by half0) follows its own wave's reads (in-order LDS).
  }

  // den: reduce dS over fr lanes; combine with denk via shfl
#pragma unroll
  for (int m2 = 1; m2 <= 8; m2 <<= 1) {
#pragma unroll
    for (int r = 0; r < 4; ++r) dS[r] += __shfl_xor(dS[r], m2, 64);
  }
  const int b = bh >> 4, hh = bh & 15;
#pragma unroll
  for (int r = 0; r < 4; ++r) {
    const float dk = __shfl(denk, fg * 4 + r, 64);   // token wl*16+fg*4+r
    const float rinv = 1.0f / (dk + dS[r] + 1e-6f);
    const int t = wl * 16 + fg * 4 + r;
    const int l = sc * 128 + h * 64 + t;
#pragma unroll
    for (int j = 0; j < 4; ++j) {
      const int d = j * 16 + fr;
      attn[((size_t)b * L_ + l) * DM_ + hh * 64 + d] = f2bf(oacc[j][r] * rinv);
    }
  }
}

extern "C" void kernel_launch(void* const* d_in, const int* in_sizes, int n_in,
                              void* d_out, int out_size, void* d_ws, size_t ws_size,
                              hipStream_t stream) {
  const float* x     = (const float*)d_in[0];
  const float* Wq    = (const float*)d_in[1];
  const float* bq    = (const float*)d_in[2];
  const float* Wk    = (const float*)d_in[3];
  const float* bk    = (const float*)d_in[4];
  const float* Wv    = (const float*)d_in[5];
  const float* bv    = (const float*)d_in[6];
  const float* Wo    = (const float*)d_in[7];
  const float* bo    = (const float*)d_in[8];
  const float* omega = (const float*)d_in[9];
  float* out = (float*)d_out;

  char* ws = (char*)d_ws;
  u16*   v      = (u16*)(ws);                           // 32 MB
  u16*   qb     = (u16*)(ws + 33554432ull);             // 32 MB
  u16*   kb     = (u16*)(ws + 67108864ull);             // 32 MB
  u16*   xb     = (u16*)(ws + 100663296ull);            // 32 MB (alias attn)
  u16*   attn   = xb;
  u16*   stateb = (u16*)(ws + 134217728ull);            // 64 MB
  float* ksum   = (float*)(ws + 201326592ull);          // 2 MB
  u16*   Wt     = (u16*)(ws + 203423744ull);            // 8 MB
  u16*   omb    = (u16*)(ws + 211812352ull);            // 32 KB
  float* nhq    = (float*)(ws + 211845120ull);          // 1 MB
  float* nhk    = (float*)(ws + 212893696ull);          // 1 MB -> 204 MB

  prep_k<<<17472, 256, 0, stream>>>(x, xb, Wq, Wk, Wv, Wo, Wt, omega, omb);
  mm3_k<<<dim3(1024, 3), 256, 0, stream>>>(xb, Wt, bq, bk, bv,
                                           qb, kb, v, nhq, nhk);
  kvstate_k<<<dim3(NSC, BH_), 256, 0, stream>>>(kb, v, omb, nhk, stateb, ksum);
  scan_k<<<dim3(8, BH_), 256, 0, stream>>>(stateb, ksum);
  outchunk_k<<<BH_ * NSC, 512, 0, stream>>>(qb, kb, v, omb, stateb, ksum,
                                            nhq, nhk, attn);
  mmo_k<<<1024, 256, 0, stream>>>(attn, Wt + 3145728ull, bo, out);
}

// Round 18
// 516.184 us; speedup vs baseline: 1.0978x; 1.0656x over previous
//
#include <hip/hip_runtime.h>
#include <hip/hip_bf16.h>

// FAVOR+ attention, MI355X. Round 18: outchunk 13 barriers -> 3.
//  - outchunk: full Kp of BOTH chunks in LDS (sKa/sKb[64][264]); half h
//    produces chunk h's phi(k) entirely (own rows -> no production barriers;
//    rows double as phi(q) scratch, wave-private across both uses).
//    Phases: QPHASE x4 | BAR P | den-k + phi(k) + early-v | BAR K |
//    S-chunk0 (32 MFMA, all) + masked->sS0/sS1 + vT0->sB1 + vT1->sB2 |
//    BAR F0 | S@V chunk0 (all); h1: S-chunk1 (sKb) -> masked sS1 (same-wave
//    overwrite after own A-reads) -> S@V chunk1 (sB2). Identical arithmetic.
//    LDS 28.7 -> 103 KB (still 1 block/CU, unchanged).
//  - prep_k / mm3_k / mmo_k / kvstate_k / scan_k: byte-identical to R17.
//
// Workspace (bytes), total 213,942,272 (~204 MB): layout as R17.

#define B_ 4
#define H_ 16
#define L_ 4096
#define D_ 64
#define M_ 256
#define DM_ 1024
#define BH_ 64
#define NSC 32            // superchunks per bh (SC = 128 tokens)

typedef unsigned int u32;
typedef unsigned short u16;
typedef __attribute__((ext_vector_type(8))) short bf16x8;
typedef __attribute__((ext_vector_type(4))) float f32x4;

static __device__ __forceinline__ float bf2f(u16 u) {
  return __uint_as_float(((u32)u) << 16);
}
static __device__ __forceinline__ u16 f2bf(float f) {
  u32 x = __float_as_uint(f);
  return (u16)((x + 0x7fffu + ((x >> 16) & 1u)) >> 16);   // RNE
}
#define MFMA16(a, b, c) __builtin_amdgcn_mfma_f32_16x16x32_bf16((a), (b), (c), 0, 0, 0)

// ---------------- merged prep: convx | convw | convom ----------------------
__global__ __launch_bounds__(256) void prep_k(
    const float* __restrict__ x, u16* __restrict__ xb,
    const float* __restrict__ W0, const float* __restrict__ W1,
    const float* __restrict__ W2, const float* __restrict__ W3,
    u16* __restrict__ Wt, const float* __restrict__ om,
    u16* __restrict__ omb) {
  __shared__ u16 tt[64][66];
  const int bid = blockIdx.x, tid = threadIdx.x;
  if (bid < 16384) {
    const int i = bid * 256 + tid;
    float4 f = ((const float4*)x)[i];
    ushort4 u;
    u.x = f2bf(f.x); u.y = f2bf(f.y); u.z = f2bf(f.z); u.w = f2bf(f.w);
    ((ushort4*)xb)[i] = u;
  } else if (bid < 17408) {
    const int rem = bid - 16384;
    const int z = rem >> 8, r2 = rem & 255;
    const int k0 = (r2 >> 4) * 64, n0 = (r2 & 15) * 64;
    const float* W = (z == 0) ? W0 : (z == 1) ? W1 : (z == 2) ? W2 : W3;
    u16* o = Wt + (size_t)z * 1048576ull;
    const int r = tid >> 4, c4 = (tid & 15) << 2;
    for (int rr = r; rr < 64; rr += 16) {
      float4 w4 = *(const float4*)(W + (size_t)(k0 + rr) * DM_ + n0 + c4);
      tt[c4 + 0][rr] = f2bf(w4.x);
      tt[c4 + 1][rr] = f2bf(w4.y);
      tt[c4 + 2][rr] = f2bf(w4.z);
      tt[c4 + 3][rr] = f2bf(w4.w);
    }
    __syncthreads();
    for (int rr = r; rr < 64; rr += 16) {
      ushort4 u4;
      u4.x = tt[rr][c4 + 0];
      u4.y = tt[rr][c4 + 1];
      u4.z = tt[rr][c4 + 2];
      u4.w = tt[rr][c4 + 3];
      *(ushort4*)(o + (size_t)(n0 + rr) * DM_ + k0 + c4) = u4;
    }
  } else {
    const int i = (bid - 17408) * 256 + tid;
    omb[i] = f2bf(om[i] * 0.35355339059327373f);     // fold 64^-0.25
  }
}

// ---------------- merged projection GEMMs (q,k,v), head bf16 out -----------
__global__ __launch_bounds__(256) void mm3_k(
    const u16* __restrict__ A, const u16* __restrict__ Wt,
    const float* __restrict__ bq, const float* __restrict__ bk,
    const float* __restrict__ bv, u16* __restrict__ qb,
    u16* __restrict__ kb, u16* __restrict__ vb,
    float* __restrict__ nhq, float* __restrict__ nhk) {
  __shared__ u16 sA[128][64];   // 16 KB, XOR-swizzled 16B slots
  __shared__ u16 sB[128][64];   // 16 KB
  const int y = blockIdx.y;
  const u16* Bt = Wt + (size_t)y * 1048576ull;
  const float* bias = (y == 0) ? bq : (y == 1) ? bk : bv;
  u16* outp = (y == 0) ? qb : (y == 1) ? kb : vb;
  float* nhout = (y == 0) ? nhq : (y == 1) ? nhk : nullptr;
  const int tid = threadIdx.x, lane = tid & 63, w = tid >> 6;
  const int fr = lane & 15, fg = lane >> 4;
  const int wr = w >> 1, wc = w & 1;
  const int lb = ((blockIdx.x & 7) << 7) | (blockIdx.x >> 3);
  const int m0 = (lb >> 3) * 128, n0 = (lb & 7) * 128;
  const int srow = tid >> 3, sslot = tid & 7;   // +p*32 rows per pass
  f32x4 acc[4][4] = {};
  bf16x8 av[4], bv4[4];
#pragma unroll
  for (int p = 0; p < 4; ++p) {
    av[p]  = *(const bf16x8*)(A  + (size_t)(m0 + srow + p * 32) * DM_ + sslot * 8);
    bv4[p] = *(const bf16x8*)(Bt + (size_t)(n0 + srow + p * 32) * DM_ + sslot * 8);
  }
  for (int k0 = 0; k0 < DM_; k0 += 64) {
    __syncthreads();
#pragma unroll
    for (int p = 0; p < 4; ++p) {
      const int r = srow + p * 32;
      *(bf16x8*)&sA[r][(sslot ^ (r & 7)) * 8] = av[p];
      *(bf16x8*)&sB[r][(sslot ^ (r & 7)) * 8] = bv4[p];
    }
    if (k0 + 64 < DM_) {
#pragma unroll
      for (int p = 0; p < 4; ++p) {
        av[p]  = *(const bf16x8*)(A  + (size_t)(m0 + srow + p * 32) * DM_ + k0 + 64 + sslot * 8);
        bv4[p] = *(const bf16x8*)(Bt + (size_t)(n0 + srow + p * 32) * DM_ + k0 + 64 + sslot * 8);
      }
    }
    __syncthreads();
#pragma unroll
    for (int ks = 0; ks < 2; ++ks) {
      bf16x8 af[4], bf[4];
#pragma unroll
      for (int i = 0; i < 4; ++i) {
        const int r = wr * 64 + i * 16 + fr;
        af[i] = *(const bf16x8*)&sA[r][((ks * 4 + fg) ^ (r & 7)) * 8];
      }
#pragma unroll
      for (int j = 0; j < 4; ++j) {
        const int r = wc * 64 + j * 16 + fr;
        bf[j] = *(const bf16x8*)&sB[r][((ks * 4 + fg) ^ (r & 7)) * 8];
      }
#pragma unroll
      for (int i = 0; i < 4; ++i)
#pragma unroll
        for (int j = 0; j < 4; ++j)
          acc[i][j] = MFMA16(af[i], bf[j], acc[i][j]);
    }
  }
  const int m_blk = m0 + wr * 64, n_blk = n0 + wc * 64;
  float nhacc[4][4] = {};
#pragma unroll
  for (int j = 0; j < 4; ++j) {
    const int n = n_blk + j * 16 + fr;
    const float bi = bias[n];
    const int h = n >> 6, d = n & 63;
#pragma unroll
    for (int i = 0; i < 4; ++i) {
#pragma unroll
      for (int r = 0; r < 4; ++r) {
        const int m = m_blk + i * 16 + fg * 4 + r;
        const float val = acc[i][j][r] + bi;
        const int b = m >> 12, l = m & 4095;
        const u16 sv = f2bf(val);
        outp[((size_t)(b * H_ + h) * L_ + l) * D_ + d] = sv;
        const float rv = bf2f(sv);
        nhacc[i][r] += rv * rv;
      }
    }
  }
  if (nhout) {
    const int hh2 = n_blk >> 6;
#pragma unroll
    for (int i = 0; i < 4; ++i)
#pragma unroll
      for (int r = 0; r < 4; ++r) {
        float s = nhacc[i][r];
        s += __shfl_xor(s, 1, 64);
        s += __shfl_xor(s, 2, 64);
        s += __shfl_xor(s, 4, 64);
        s += __shfl_xor(s, 8, 64);
        if (fr == 0) {
          const int m = m_blk + i * 16 + fg * 4 + r;
          const int b = m >> 12, l = m & 4095;
          nhout[(size_t)(b * H_ + hh2) * L_ + l] = 0.0625f * s;
        }
      }
  }
}

// ---------------- final GEMM (attn bf16 -> f32 out), validated -------------
__global__ __launch_bounds__(256) void mmo_k(
    const u16* __restrict__ A, const u16* __restrict__ Bt,
    const float* __restrict__ bias, float* __restrict__ outp) {
  __shared__ u16 sA[128][64];
  __shared__ u16 sB[128][64];
  const int tid = threadIdx.x, lane = tid & 63, w = tid >> 6;
  const int fr = lane & 15, fg = lane >> 4;
  const int wr = w >> 1, wc = w & 1;
  const int lb = ((blockIdx.x & 7) << 7) | (blockIdx.x >> 3);
  const int m0 = (lb >> 3) * 128, n0 = (lb & 7) * 128;
  const int srow = tid >> 3, sslot = tid & 7;
  f32x4 acc[4][4] = {};
  bf16x8 av[4], bv[4];
#pragma unroll
  for (int p = 0; p < 4; ++p) {
    av[p] = *(const bf16x8*)(A  + (size_t)(m0 + srow + p * 32) * DM_ + sslot * 8);
    bv[p] = *(const bf16x8*)(Bt + (size_t)(n0 + srow + p * 32) * DM_ + sslot * 8);
  }
  for (int k0 = 0; k0 < DM_; k0 += 64) {
    __syncthreads();
#pragma unroll
    for (int p = 0; p < 4; ++p) {
      const int r = srow + p * 32;
      *(bf16x8*)&sA[r][(sslot ^ (r & 7)) * 8] = av[p];
      *(bf16x8*)&sB[r][(sslot ^ (r & 7)) * 8] = bv[p];
    }
    if (k0 + 64 < DM_) {
#pragma unroll
      for (int p = 0; p < 4; ++p) {
        av[p] = *(const bf16x8*)(A  + (size_t)(m0 + srow + p * 32) * DM_ + k0 + 64 + sslot * 8);
        bv[p] = *(const bf16x8*)(Bt + (size_t)(n0 + srow + p * 32) * DM_ + k0 + 64 + sslot * 8);
      }
    }
    __syncthreads();
#pragma unroll
    for (int ks = 0; ks < 2; ++ks) {
      bf16x8 af[4], bf[4];
#pragma unroll
      for (int i = 0; i < 4; ++i) {
        const int r = wr * 64 + i * 16 + fr;
        af[i] = *(const bf16x8*)&sA[r][((ks * 4 + fg) ^ (r & 7)) * 8];
      }
#pragma unroll
      for (int j = 0; j < 4; ++j) {
        const int r = wc * 64 + j * 16 + fr;
        bf[j] = *(const bf16x8*)&sB[r][((ks * 4 + fg) ^ (r & 7)) * 8];
      }
#pragma unroll
      for (int i = 0; i < 4; ++i)
#pragma unroll
        for (int j = 0; j < 4; ++j)
          acc[i][j] = MFMA16(af[i], bf[j], acc[i][j]);
    }
  }
  const int m_blk = m0 + wr * 64, n_blk = n0 + wc * 64;
#pragma unroll
  for (int j = 0; j < 4; ++j) {
    const int n = n_blk + j * 16 + fr;
    const float bi = bias[n];
#pragma unroll
    for (int i = 0; i < 4; ++i)
#pragma unroll
      for (int r = 0; r < 4; ++r) {
        const int m = m_blk + i * 16 + fg * 4 + r;
        outp[(size_t)m * DM_ + n] = acc[i][j][r] + bi;
      }
  }
}

// ---------------- kvstate (MFMA, SC=128): bf16 state + f32 ksum ------------
__global__ __launch_bounds__(256) void kvstate_k(
    const u16* __restrict__ k, const u16* __restrict__ v,
    const u16* __restrict__ omb, const float* __restrict__ nhk,
    u16* __restrict__ stateb, float* __restrict__ ksum) {
  __shared__ u16 sPhi[256][72];
  __shared__ u16 sVt[64][72];
  const int tid = threadIdx.x, lane = tid & 63, w = tid >> 6;
  const int fr = lane & 15, fg = lane >> 4;
  const int sc = blockIdx.x, bh = blockIdx.y;
  const size_t base_l = (size_t)bh * L_ + (size_t)sc * 128;

  bf16x8 ones;
#pragma unroll
  for (int e = 0; e < 8; ++e) ones[e] = (short)0x3F80;

  f32x4 kvacc[4][4] = {};
  f32x4 ksacc[4] = {};

  for (int sub = 0; sub < 2; ++sub) {
    const size_t tl = base_l + sub * 64;
    const u16* kg = k + tl * 64;
    __syncthreads();
    {
      const u16* vp = v + (tl + lane) * 64 + w * 16;
      bf16x8 v0 = *(const bf16x8*)(vp);
      bf16x8 v1 = *(const bf16x8*)(vp + 8);
#pragma unroll
      for (int e = 0; e < 8; ++e) sVt[w * 16 + e][lane] = (u16)v0[e];
#pragma unroll
      for (int e = 0; e < 8; ++e) sVt[w * 16 + 8 + e][lane] = (u16)v1[e];
    }
    float nhr[4];
#pragma unroll
    for (int tt = 0; tt < 4; ++tt) nhr[tt] = nhk[tl + tt * 16 + fr];
#pragma unroll
    for (int mi = 0; mi < 4; ++mi) {
      const int m0 = (w << 6) + mi * 16;
      const bf16x8 a0 = *(const bf16x8*)(omb + (m0 + fr) * 64 + fg * 8);
      const bf16x8 a1 = *(const bf16x8*)(omb + (m0 + fr) * 64 + 32 + fg * 8);
#pragma unroll
      for (int tt = 0; tt < 4; ++tt) {
        const bf16x8 b0 = *(const bf16x8*)(kg + (tt * 16 + fr) * 64 + fg * 8);
        const bf16x8 b1 = *(const bf16x8*)(kg + (tt * 16 + fr) * 64 + 32 + fg * 8);
        f32x4 acc = {0.f, 0.f, 0.f, 0.f};
        acc = MFMA16(a0, b0, acc);
        acc = MFMA16(a1, b1, acc);
        const float nhv = nhr[tt];
#pragma unroll
        for (int r = 0; r < 4; ++r)
          sPhi[m0 + fg * 4 + r][tt * 16 + fr] = f2bf(__expf(acc[r] - nhv) * 0.0625f);
      }
    }
    __syncthreads();
#pragma unroll
    for (int mi = 0; mi < 4; ++mi) {
      const int m0 = (w << 6) + mi * 16;
      const bf16x8 pb0 = *(const bf16x8*)&sPhi[m0 + fr][fg * 8];
      const bf16x8 pb1 = *(const bf16x8*)&sPhi[m0 + fr][32 + fg * 8];
      ksacc[mi] = MFMA16(pb0, ones, ksacc[mi]);
      ksacc[mi] = MFMA16(pb1, ones, ksacc[mi]);
#pragma unroll
      for (int dj = 0; dj < 4; ++dj) {
        const bf16x8 va0 = *(const bf16x8*)&sVt[dj * 16 + fr][fg * 8];
        const bf16x8 va1 = *(const bf16x8*)&sVt[dj * 16 + fr][32 + fg * 8];
        kvacc[mi][dj] = MFMA16(va0, pb0, kvacc[mi][dj]);
        kvacc[mi][dj] = MFMA16(va1, pb1, kvacc[mi][dj]);
      }
    }
  }
  // state bf16 [d][m]; ksum f32
  u16* stb = stateb + (size_t)(bh * NSC + sc) * (M_ * D_);
  float* ksp = ksum + (size_t)(bh * NSC + sc) * M_;
#pragma unroll
  for (int mi = 0; mi < 4; ++mi) {
    const int m = (w << 6) + mi * 16 + fr;
#pragma unroll
    for (int dj = 0; dj < 4; ++dj)
#pragma unroll
      for (int r = 0; r < 4; ++r)
        stb[(size_t)(dj * 16 + fg * 4 + r) * M_ + m] = f2bf(kvacc[mi][dj][r]);
    if (fr == 0) {
#pragma unroll
      for (int r = 0; r < 4; ++r)
        ksp[(w << 6) + mi * 16 + fg * 4 + r] = ksacc[mi][r];
    }
  }
}

// ---------------- exclusive prefix over superchunks (bf16 state) -----------
__global__ __launch_bounds__(256) void scan_k(u16* __restrict__ stateb,
                                              float* __restrict__ ksum) {
  const int bh = blockIdx.y;
  u16* sb = stateb + (size_t)bh * NSC * (M_ * D_);
  const int base = blockIdx.x * 2048 + threadIdx.x * 8;
  float run[8] = {};
  for (int cc = 0; cc < NSC; ++cc) {
    u16* st = sb + (size_t)cc * (M_ * D_) + base;
    ushort4 t0 = *(ushort4*)st;
    ushort4 t1 = *(ushort4*)(st + 4);
    ushort4 w0, w1;
    w0.x = f2bf(run[0]); w0.y = f2bf(run[1]); w0.z = f2bf(run[2]); w0.w = f2bf(run[3]);
    w1.x = f2bf(run[4]); w1.y = f2bf(run[5]); w1.z = f2bf(run[6]); w1.w = f2bf(run[7]);
    *(ushort4*)st = w0;
    *(ushort4*)(st + 4) = w1;
    run[0] += bf2f(t0.x); run[1] += bf2f(t0.y); run[2] += bf2f(t0.z); run[3] += bf2f(t0.w);
    run[4] += bf2f(t1.x); run[5] += bf2f(t1.y); run[6] += bf2f(t1.z); run[7] += bf2f(t1.w);
  }
  if (blockIdx.x == 0) {           // ksum f32 in-place exclusive prefix
    float rk = 0.f;
    for (int cc = 0; cc < NSC; ++cc) {
      float* p = ksum + (size_t)(bh * NSC + cc) * M_ + threadIdx.x;
      const float t = *p;
      *p = rk;
      rk += t;
    }
  }
}

// ---------------- outchunk helpers -----------------------------------------
// phi quadrant: writes ONLY rows of band wb (wb*16..wb*16+15)
static __device__ __forceinline__ void phi_quad(
    const u16* __restrict__ xg, const u16* __restrict__ ombq,
    u16* __restrict__ dst, int dstride, const float* nhv,
    int wb, int lane) {
  const int fr = lane & 15, fg = lane >> 4;
  const int tband = wb * 16;
  const bf16x8 a0 = *(const bf16x8*)(xg + (tband + fr) * 64 + fg * 8);
  const bf16x8 a1 = *(const bf16x8*)(xg + (tband + fr) * 64 + 32 + fg * 8);
#pragma unroll
  for (int j = 0; j < 4; ++j) {
    const bf16x8 b0 = *(const bf16x8*)(ombq + (j * 16 + fr) * 64 + fg * 8);
    const bf16x8 b1 = *(const bf16x8*)(ombq + (j * 16 + fr) * 64 + 32 + fg * 8);
    f32x4 acc = {0.f, 0.f, 0.f, 0.f};
    acc = MFMA16(a0, b0, acc);
    acc = MFMA16(a1, b1, acc);
#pragma unroll
    for (int r = 0; r < 4; ++r) {
      const int t = tband + fg * 4 + r;
      dst[t * dstride + j * 16 + fr] = f2bf(__expf(acc[r] - nhv[r]) * 0.0625f);
    }
  }
}

// ---------------- outchunk: 3-barrier structure ----------------------------
__global__ __launch_bounds__(512) void outchunk_k(
    const u16* __restrict__ q, const u16* __restrict__ kk,
    const u16* __restrict__ v, const u16* __restrict__ omb,
    const u16* __restrict__ stateb, const float* __restrict__ ksum,
    const float* __restrict__ nhq, const float* __restrict__ nhk,
    u16* __restrict__ attn) {
  __shared__ u16 sKa[64][264];    // Kp chunk0 (h0-produced) / h0 q-scratch
  __shared__ u16 sKb[64][264];    // Kp chunk1 (h1-produced) / h1 q-scratch
  __shared__ u16 sS0[64][72];     // masked S, half 0
  __shared__ u16 sS1[64][72];     // masked S, half 1
  __shared__ u16 sB1[64][72];     // vT chunk0
  __shared__ u16 sB2[64][72];     // vT chunk1
  __shared__ float ksum_l[256];   // total 105,472 B -> 1 block/CU
  const int tid = threadIdx.x, lane = tid & 63, w = tid >> 6;
  const int h = w >> 2, wl = w & 3;
  const int fr = lane & 15, fg = lane >> 4;
  const int bh = blockIdx.x >> 5, sc = blockIdx.x & 31;
  const size_t base_l = (size_t)bh * L_ + (size_t)sc * 128;
  const size_t tokq = base_l + (size_t)h * 64;
  const u16* qg = q + tokq * 64;
  const u16* stgb = stateb + (size_t)(bh * NSC + sc) * (M_ * D_);   // [d][m]
  const float* ksg = ksum + (size_t)(bh * NSC + sc) * M_;

  if (tid < 256) ksum_l[tid] = ksg[tid];

  float nhq4[4];
#pragma unroll
  for (int r = 0; r < 4; ++r) nhq4[r] = nhq[tokq + wl * 16 + fg * 4 + r];

  // phi(q) -> regs via own-half Kp buffer as scratch (rows wave-private:
  // this wave's band is the only writer/reader until phi(k) refills it,
  // also by this same wave). Cross term fused (state B-frags pre-loaded).
  u16* myscr = (h == 0) ? &sKa[0][0] : &sKb[0][0];
  bf16x8 qa0[2], qa1[2], qa2[2], qa3[2];
  f32x4 oacc[4] = {};
#define QPHASE(MQ, QA)                                                          \
  {                                                                             \
    bf16x8 b0r[4], b1r[4];                                                      \
    _Pragma("unroll")                                                           \
    for (int j = 0; j < 4; ++j) {                                               \
      b0r[j] = *(const bf16x8*)(stgb + (size_t)(j * 16 + fr) * M_ + MQ * 64 + fg * 8);        \
      b1r[j] = *(const bf16x8*)(stgb + (size_t)(j * 16 + fr) * M_ + MQ * 64 + 32 + fg * 8);   \
    }                                                                           \
    phi_quad(qg, omb + MQ * 4096, myscr, 264, nhq4, wl, lane);                  \
    QA[0] = *(const bf16x8*)(myscr + (wl * 16 + fr) * 264 + fg * 8);            \
    QA[1] = *(const bf16x8*)(myscr + (wl * 16 + fr) * 264 + 32 + fg * 8);       \
    __builtin_amdgcn_s_setprio(1);                                              \
    _Pragma("unroll")                                                           \
    for (int j = 0; j < 4; ++j) {                                               \
      oacc[j] = MFMA16(QA[0], b0r[j], oacc[j]);                                 \
      oacc[j] = MFMA16(QA[1], b1r[j], oacc[j]);                                 \
    }                                                                           \
    __builtin_amdgcn_s_setprio(0);                                              \
  }
  QPHASE(0, qa0)
  QPHASE(1, qa1)
  QPHASE(2, qa2)
  QPHASE(3, qa3)
#undef QPHASE
  __syncthreads();   // BAR P: ksum_l visibility

  // den-ksum from register frags
  float denk = 0.f;
#pragma unroll
  for (int e = 0; e < 8; ++e) {
    denk += bf2f((u16)qa0[0][e]) * ksum_l[0   + fg * 8 + e]
          + bf2f((u16)qa0[1][e]) * ksum_l[32  + fg * 8 + e]
          + bf2f((u16)qa1[0][e]) * ksum_l[64  + fg * 8 + e]
          + bf2f((u16)qa1[1][e]) * ksum_l[96  + fg * 8 + e]
          + bf2f((u16)qa2[0][e]) * ksum_l[128 + fg * 8 + e]
          + bf2f((u16)qa2[1][e]) * ksum_l[160 + fg * 8 + e]
          + bf2f((u16)qa3[0][e]) * ksum_l[192 + fg * 8 + e]
          + bf2f((u16)qa3[1][e]) * ksum_l[224 + fg * 8 + e];
  }
  denk += __shfl_xor(denk, 16, 64);
  denk += __shfl_xor(denk, 32, 64);

  // phi(k): half h fills its chunk's Kp (all 4 quadrants, own rows only)
  {
    const size_t ktokh = base_l + (size_t)h * 64;
    const u16* kgh = kk + ktokh * 64;
    float nhkh[4];
#pragma unroll
    for (int r = 0; r < 4; ++r) nhkh[r] = nhk[ktokh + wl * 16 + fg * 4 + r];
#pragma unroll
    for (int mq = 0; mq < 4; ++mq)
      phi_quad(kgh, omb + mq * 4096, myscr + mq * 64, 264, nhkh, wl, lane);
  }
  // early v loads for BOTH chunks (h0 stages vT later)
  bf16x8 v0 = {}, v1 = {}, v2 = {}, v3 = {};
  if (h == 0) {
    const u16* vp0 = v + (base_l + lane) * 64 + wl * 16;
    const u16* vp1 = v + (base_l + 64 + lane) * 64 + wl * 16;
    v0 = *(const bf16x8*)(vp0);
    v1 = *(const bf16x8*)(vp0 + 8);
    v2 = *(const bf16x8*)(vp1);
    v3 = *(const bf16x8*)(vp1 + 8);
  }
  __syncthreads();   // BAR K: sKa/sKb (full Kp) visible to all

  // ---- S chunk0 (all waves): 32 MFMA, B-frags from sKa
  float dS[4] = {0.f, 0.f, 0.f, 0.f};
  {
    f32x4 sacc[4] = {};
    __builtin_amdgcn_s_setprio(1);
#define SPH0(MQ, QA)                                                            \
    _Pragma("unroll")                                                           \
    for (int j = 0; j < 4; ++j) {                                               \
      const bf16x8 b0 = *(const bf16x8*)&sKa[j * 16 + fr][MQ * 64 + fg * 8];    \
      const bf16x8 b1 = *(const bf16x8*)&sKa[j * 16 + fr][MQ * 64 + 32 + fg * 8]; \
      sacc[j] = MFMA16(QA[0], b0, sacc[j]);                                     \
      sacc[j] = MFMA16(QA[1], b1, sacc[j]);                                     \
    }
    SPH0(0, qa0)
    SPH0(1, qa1)
    SPH0(2, qa2)
    SPH0(3, qa3)
#undef SPH0
    __builtin_amdgcn_s_setprio(0);
    // masked write to own half's S buffer (own-band rows); diag iff h==0
    u16 (*sSo)[72] = (h == 0) ? sS0 : sS1;
#pragma unroll
    for (int j = 0; j < 4; ++j)
#pragma unroll
      for (int r = 0; r < 4; ++r) {
        const int ss = j * 16 + fr, t = wl * 16 + fg * 4 + r;
        float val = sacc[j][r];
        if (h == 0 && ss > t) val = 0.f;
        const u16 vb = f2bf(val);
        sSo[t][ss] = vb;
        dS[r] += bf2f(vb);
      }
  }
  if (h == 0) {   // vT staging: chunk0 -> sB1, chunk1 -> sB2 (fresh buffers)
#pragma unroll
    for (int e = 0; e < 8; ++e) sB1[wl * 16 + e][lane] = (u16)v0[e];
#pragma unroll
    for (int e = 0; e < 8; ++e) sB1[wl * 16 + 8 + e][lane] = (u16)v1[e];
#pragma unroll
    for (int e = 0; e < 8; ++e) sB2[wl * 16 + e][lane] = (u16)v2[e];
#pragma unroll
    for (int e = 0; e < 8; ++e) sB2[wl * 16 + 8 + e][lane] = (u16)v3[e];
  }
  __syncthreads();   // BAR F0: sS0/sS1 + sB1/sB2 visible

  // ---- S@V chunk0 (all waves): A = own masked S (own band), B = sB1
  {
    const u16 (*sSo)[72] = (h == 0) ? sS0 : sS1;
    const bf16x8 a0 = *(const bf16x8*)&sSo[wl * 16 + fr][fg * 8];
    const bf16x8 a1 = *(const bf16x8*)&sSo[wl * 16 + fr][32 + fg * 8];
    __builtin_amdgcn_s_setprio(1);
#pragma unroll
    for (int j = 0; j < 4; ++j) {
      const bf16x8 b0 = *(const bf16x8*)&sB1[j * 16 + fr][fg * 8];
      const bf16x8 b1 = *(const bf16x8*)&sB1[j * 16 + fr][32 + fg * 8];
      oacc[j] = MFMA16(a0, b0, oacc[j]);
      oacc[j] = MFMA16(a1, b1, oacc[j]);
    }
    __builtin_amdgcn_s_setprio(0);
  }

  // ---- h1 only: S chunk1 (sKb) -> masked sS1 (same-wave overwrite after
  //      its own A-reads above; in-order LDS) -> S@V chunk1 (B = sB2)
  if (h == 1) {
    f32x4 sacc[4] = {};
    __builtin_amdgcn_s_setprio(1);
#define SPH1(MQ, QA)                                                            \
    _Pragma("unroll")                                                           \
    for (int j = 0; j < 4; ++j) {                                               \
      const bf16x8 b0 = *(const bf16x8*)&sKb[j * 16 + fr][MQ * 64 + fg * 8];    \
      const bf16x8 b1 = *(const bf16x8*)&sKb[j * 16 + fr][MQ * 64 + 32 + fg * 8]; \
      sacc[j] = MFMA16(QA[0], b0, sacc[j]);                                     \
      sacc[j] = MFMA16(QA[1], b1, sacc[j]);                                     \
    }
    SPH1(0, qa0)
    SPH1(1, qa1)
    SPH1(2, qa2)
    SPH1(3, qa3)
#undef SPH1
    __builtin_amdgcn_s_setprio(0);
#pragma unroll
    for (int j = 0; j < 4; ++j)
#pragma unroll
      for (int r = 0; r < 4; ++r) {
        const int ss = j * 16 + fr, t = wl * 16 + fg * 4 + r;
        float val = sacc[j][r];
        if (ss > t) val = 0.f;           // diag (s == h == 1)
        const u16 vb = f2bf(val);
        sS1[t][ss] = vb;
        dS[r] += bf2f(vb);
      }
    {
      const bf16x8 a0 = *(const bf16x8*)&sS1[wl * 16 + fr][fg * 8];
      const bf16x8 a1 = *(const bf16x8*)&sS1[wl * 16 + fr][32 + fg * 8];
      __builtin_amdgcn_s_setprio(1);
#pragma unroll
      for (int j = 0; j < 4; ++j) {
        const bf16x8 b0 = *(const bf16x8*)&sB2[j * 16 + fr][fg * 8];
        const bf16x8 b1 = *(const bf16x8*)&sB2[j * 16 + fr][32 + fg * 8];
        oacc[j] = MFMA16(a0, b0, oacc[j]);
        oacc[j] = MFMA16(a1, b1, oacc[j]);
      }
      __builtin_amdgcn_s_setprio(0);
    }
  }

  // den: reduce dS over fr lanes; combine with denk via shfl
#pragma unroll
  for (int m2 = 1; m2 <= 8; m2 <<= 1) {
#pragma unroll
    for (int r = 0; r < 4; ++r) dS[r] += __shfl_xor(dS[r], m2, 64);
  }
  const int b = bh >> 4, hh = bh & 15;
#pragma unroll
  for (int r = 0; r < 4; ++r) {
    const float dk = __shfl(denk, fg * 4 + r, 64);   // token wl*16+fg*4+r
    const float rinv = 1.0f / (dk + dS[r] + 1e-6f);
    const int t = wl * 16 + fg * 4 + r;
    const int l = sc * 128 + h * 64 + t;
#pragma unroll
    for (int j = 0; j < 4; ++j) {
      const int d = j * 16 + fr;
      attn[((size_t)b * L_ + l) * DM_ + hh * 64 + d] = f2bf(oacc[j][r] * rinv);
    }
  }
}

extern "C" void kernel_launch(void* const* d_in, const int* in_sizes, int n_in,
                              void* d_out, int out_size, void* d_ws, size_t ws_size,
                              hipStream_t stream) {
  const float* x     = (const float*)d_in[0];
  const float* Wq    = (const float*)d_in[1];
  const float* bq    = (const float*)d_in[2];
  const float* Wk    = (const float*)d_in[3];
  const float* bk    = (const float*)d_in[4];
  const float* Wv    = (const float*)d_in[5];
  const float* bv    = (const float*)d_in[6];
  const float* Wo    = (const float*)d_in[7];
  const float* bo    = (const float*)d_in[8];
  const float* omega = (const float*)d_in[9];
  float* out = (float*)d_out;

  char* ws = (char*)d_ws;
  u16*   v      = (u16*)(ws);                           // 32 MB
  u16*   qb     = (u16*)(ws + 33554432ull);             // 32 MB
  u16*   kb     = (u16*)(ws + 67108864ull);             // 32 MB
  u16*   xb     = (u16*)(ws + 100663296ull);            // 32 MB (alias attn)
  u16*   attn   = xb;
  u16*   stateb = (u16*)(ws + 134217728ull);            // 64 MB
  float* ksum   = (float*)(ws + 201326592ull);          // 2 MB
  u16*   Wt     = (u16*)(ws + 203423744ull);            // 8 MB
  u16*   omb    = (u16*)(ws + 211812352ull);            // 32 KB
  float* nhq    = (float*)(ws + 211845120ull);          // 1 MB
  float* nhk    = (float*)(ws + 212893696ull);          // 1 MB -> 204 MB

  prep_k<<<17472, 256, 0, stream>>>(x, xb, Wq, Wk, Wv, Wo, Wt, omega, omb);
  mm3_k<<<dim3(1024, 3), 256, 0, stream>>>(xb, Wt, bq, bk, bv,
                                           qb, kb, v, nhq, nhk);
  kvstate_k<<<dim3(NSC, BH_), 256, 0, stream>>>(kb, v, omb, nhk, stateb, ksum);
  scan_k<<<dim3(8, BH_), 256, 0, stream>>>(stateb, ksum);
  outchunk_k<<<BH_ * NSC, 512, 0, stream>>>(qb, kb, v, omb, stateb, ksum,
                                            nhq, nhk, attn);
  mmo_k<<<1024, 256, 0, stream>>>(attn, Wt + 3145728ull, bo, out);
}

// Round 19
// 505.941 us; speedup vs baseline: 1.1201x; 1.0202x over previous
//
#include <hip/hip_runtime.h>
#include <hip/hip_bf16.h>

// FAVOR+ attention, MI355X. Round 19: outchunk 3 barriers -> 2.
//  - outchunk: phi(k) moved BEFORE QPHASE (independent; fills sKa/sKb own
//    rows) and BAR P merged into BAR K -> one straight-line pre-barrier
//    region where state-load latency hides under phi(k) compute. phi(q)
//    scratch = own half's S buffer (wave-private rows; masked-S overwrites
//    it after the same wave's register read-back: in-order LDS). Early-v
//    split across halves (h0->chunk0->sB1, h1->chunk1->sB2).
//    Identical arithmetic to R18; LDS unchanged (105,472 B).
//  - prep_k / mm3_k / mmo_k / kvstate_k / scan_k: byte-identical to R18.
//
// Workspace (bytes), total 213,942,272 (~204 MB): layout as R17/R18.

#define B_ 4
#define H_ 16
#define L_ 4096
#define D_ 64
#define M_ 256
#define DM_ 1024
#define BH_ 64
#define NSC 32            // superchunks per bh (SC = 128 tokens)

typedef unsigned int u32;
typedef unsigned short u16;
typedef __attribute__((ext_vector_type(8))) short bf16x8;
typedef __attribute__((ext_vector_type(4))) float f32x4;

static __device__ __forceinline__ float bf2f(u16 u) {
  return __uint_as_float(((u32)u) << 16);
}
static __device__ __forceinline__ u16 f2bf(float f) {
  u32 x = __float_as_uint(f);
  return (u16)((x + 0x7fffu + ((x >> 16) & 1u)) >> 16);   // RNE
}
#define MFMA16(a, b, c) __builtin_amdgcn_mfma_f32_16x16x32_bf16((a), (b), (c), 0, 0, 0)

// ---------------- merged prep: convx | convw | convom ----------------------
__global__ __launch_bounds__(256) void prep_k(
    const float* __restrict__ x, u16* __restrict__ xb,
    const float* __restrict__ W0, const float* __restrict__ W1,
    const float* __restrict__ W2, const float* __restrict__ W3,
    u16* __restrict__ Wt, const float* __restrict__ om,
    u16* __restrict__ omb) {
  __shared__ u16 tt[64][66];
  const int bid = blockIdx.x, tid = threadIdx.x;
  if (bid < 16384) {
    const int i = bid * 256 + tid;
    float4 f = ((const float4*)x)[i];
    ushort4 u;
    u.x = f2bf(f.x); u.y = f2bf(f.y); u.z = f2bf(f.z); u.w = f2bf(f.w);
    ((ushort4*)xb)[i] = u;
  } else if (bid < 17408) {
    const int rem = bid - 16384;
    const int z = rem >> 8, r2 = rem & 255;
    const int k0 = (r2 >> 4) * 64, n0 = (r2 & 15) * 64;
    const float* W = (z == 0) ? W0 : (z == 1) ? W1 : (z == 2) ? W2 : W3;
    u16* o = Wt + (size_t)z * 1048576ull;
    const int r = tid >> 4, c4 = (tid & 15) << 2;
    for (int rr = r; rr < 64; rr += 16) {
      float4 w4 = *(const float4*)(W + (size_t)(k0 + rr) * DM_ + n0 + c4);
      tt[c4 + 0][rr] = f2bf(w4.x);
      tt[c4 + 1][rr] = f2bf(w4.y);
      tt[c4 + 2][rr] = f2bf(w4.z);
      tt[c4 + 3][rr] = f2bf(w4.w);
    }
    __syncthreads();
    for (int rr = r; rr < 64; rr += 16) {
      ushort4 u4;
      u4.x = tt[rr][c4 + 0];
      u4.y = tt[rr][c4 + 1];
      u4.z = tt[rr][c4 + 2];
      u4.w = tt[rr][c4 + 3];
      *(ushort4*)(o + (size_t)(n0 + rr) * DM_ + k0 + c4) = u4;
    }
  } else {
    const int i = (bid - 17408) * 256 + tid;
    omb[i] = f2bf(om[i] * 0.35355339059327373f);     // fold 64^-0.25
  }
}

// ---------------- merged projection GEMMs (q,k,v), head bf16 out -----------
__global__ __launch_bounds__(256) void mm3_k(
    const u16* __restrict__ A, const u16* __restrict__ Wt,
    const float* __restrict__ bq, const float* __restrict__ bk,
    const float* __restrict__ bv, u16* __restrict__ qb,
    u16* __restrict__ kb, u16* __restrict__ vb,
    float* __restrict__ nhq, float* __restrict__ nhk) {
  __shared__ u16 sA[128][64];   // 16 KB, XOR-swizzled 16B slots
  __shared__ u16 sB[128][64];   // 16 KB
  const int y = blockIdx.y;
  const u16* Bt = Wt + (size_t)y * 1048576ull;
  const float* bias = (y == 0) ? bq : (y == 1) ? bk : bv;
  u16* outp = (y == 0) ? qb : (y == 1) ? kb : vb;
  float* nhout = (y == 0) ? nhq : (y == 1) ? nhk : nullptr;
  const int tid = threadIdx.x, lane = tid & 63, w = tid >> 6;
  const int fr = lane & 15, fg = lane >> 4;
  const int wr = w >> 1, wc = w & 1;
  const int lb = ((blockIdx.x & 7) << 7) | (blockIdx.x >> 3);
  const int m0 = (lb >> 3) * 128, n0 = (lb & 7) * 128;
  const int srow = tid >> 3, sslot = tid & 7;   // +p*32 rows per pass
  f32x4 acc[4][4] = {};
  bf16x8 av[4], bv4[4];
#pragma unroll
  for (int p = 0; p < 4; ++p) {
    av[p]  = *(const bf16x8*)(A  + (size_t)(m0 + srow + p * 32) * DM_ + sslot * 8);
    bv4[p] = *(const bf16x8*)(Bt + (size_t)(n0 + srow + p * 32) * DM_ + sslot * 8);
  }
  for (int k0 = 0; k0 < DM_; k0 += 64) {
    __syncthreads();
#pragma unroll
    for (int p = 0; p < 4; ++p) {
      const int r = srow + p * 32;
      *(bf16x8*)&sA[r][(sslot ^ (r & 7)) * 8] = av[p];
      *(bf16x8*)&sB[r][(sslot ^ (r & 7)) * 8] = bv4[p];
    }
    if (k0 + 64 < DM_) {
#pragma unroll
      for (int p = 0; p < 4; ++p) {
        av[p]  = *(const bf16x8*)(A  + (size_t)(m0 + srow + p * 32) * DM_ + k0 + 64 + sslot * 8);
        bv4[p] = *(const bf16x8*)(Bt + (size_t)(n0 + srow + p * 32) * DM_ + k0 + 64 + sslot * 8);
      }
    }
    __syncthreads();
#pragma unroll
    for (int ks = 0; ks < 2; ++ks) {
      bf16x8 af[4], bf[4];
#pragma unroll
      for (int i = 0; i < 4; ++i) {
        const int r = wr * 64 + i * 16 + fr;
        af[i] = *(const bf16x8*)&sA[r][((ks * 4 + fg) ^ (r & 7)) * 8];
      }
#pragma unroll
      for (int j = 0; j < 4; ++j) {
        const int r = wc * 64 + j * 16 + fr;
        bf[j] = *(const bf16x8*)&sB[r][((ks * 4 + fg) ^ (r & 7)) * 8];
      }
#pragma unroll
      for (int i = 0; i < 4; ++i)
#pragma unroll
        for (int j = 0; j < 4; ++j)
          acc[i][j] = MFMA16(af[i], bf[j], acc[i][j]);
    }
  }
  const int m_blk = m0 + wr * 64, n_blk = n0 + wc * 64;
  float nhacc[4][4] = {};
#pragma unroll
  for (int j = 0; j < 4; ++j) {
    const int n = n_blk + j * 16 + fr;
    const float bi = bias[n];
    const int h = n >> 6, d = n & 63;
#pragma unroll
    for (int i = 0; i < 4; ++i) {
#pragma unroll
      for (int r = 0; r < 4; ++r) {
        const int m = m_blk + i * 16 + fg * 4 + r;
        const float val = acc[i][j][r] + bi;
        const int b = m >> 12, l = m & 4095;
        const u16 sv = f2bf(val);
        outp[((size_t)(b * H_ + h) * L_ + l) * D_ + d] = sv;
        const float rv = bf2f(sv);
        nhacc[i][r] += rv * rv;
      }
    }
  }
  if (nhout) {
    const int hh2 = n_blk >> 6;
#pragma unroll
    for (int i = 0; i < 4; ++i)
#pragma unroll
      for (int r = 0; r < 4; ++r) {
        float s = nhacc[i][r];
        s += __shfl_xor(s, 1, 64);
        s += __shfl_xor(s, 2, 64);
        s += __shfl_xor(s, 4, 64);
        s += __shfl_xor(s, 8, 64);
        if (fr == 0) {
          const int m = m_blk + i * 16 + fg * 4 + r;
          const int b = m >> 12, l = m & 4095;
          nhout[(size_t)(b * H_ + hh2) * L_ + l] = 0.0625f * s;
        }
      }
  }
}

// ---------------- final GEMM (attn bf16 -> f32 out), validated -------------
__global__ __launch_bounds__(256) void mmo_k(
    const u16* __restrict__ A, const u16* __restrict__ Bt,
    const float* __restrict__ bias, float* __restrict__ outp) {
  __shared__ u16 sA[128][64];
  __shared__ u16 sB[128][64];
  const int tid = threadIdx.x, lane = tid & 63, w = tid >> 6;
  const int fr = lane & 15, fg = lane >> 4;
  const int wr = w >> 1, wc = w & 1;
  const int lb = ((blockIdx.x & 7) << 7) | (blockIdx.x >> 3);
  const int m0 = (lb >> 3) * 128, n0 = (lb & 7) * 128;
  const int srow = tid >> 3, sslot = tid & 7;
  f32x4 acc[4][4] = {};
  bf16x8 av[4], bv[4];
#pragma unroll
  for (int p = 0; p < 4; ++p) {
    av[p] = *(const bf16x8*)(A  + (size_t)(m0 + srow + p * 32) * DM_ + sslot * 8);
    bv[p] = *(const bf16x8*)(Bt + (size_t)(n0 + srow + p * 32) * DM_ + sslot * 8);
  }
  for (int k0 = 0; k0 < DM_; k0 += 64) {
    __syncthreads();
#pragma unroll
    for (int p = 0; p < 4; ++p) {
      const int r = srow + p * 32;
      *(bf16x8*)&sA[r][(sslot ^ (r & 7)) * 8] = av[p];
      *(bf16x8*)&sB[r][(sslot ^ (r & 7)) * 8] = bv[p];
    }
    if (k0 + 64 < DM_) {
#pragma unroll
      for (int p = 0; p < 4; ++p) {
        av[p] = *(const bf16x8*)(A  + (size_t)(m0 + srow + p * 32) * DM_ + k0 + 64 + sslot * 8);
        bv[p] = *(const bf16x8*)(Bt + (size_t)(n0 + srow + p * 32) * DM_ + k0 + 64 + sslot * 8);
      }
    }
    __syncthreads();
#pragma unroll
    for (int ks = 0; ks < 2; ++ks) {
      bf16x8 af[4], bf[4];
#pragma unroll
      for (int i = 0; i < 4; ++i) {
        const int r = wr * 64 + i * 16 + fr;
        af[i] = *(const bf16x8*)&sA[r][((ks * 4 + fg) ^ (r & 7)) * 8];
      }
#pragma unroll
      for (int j = 0; j < 4; ++j) {
        const int r = wc * 64 + j * 16 + fr;
        bf[j] = *(const bf16x8*)&sB[r][((ks * 4 + fg) ^ (r & 7)) * 8];
      }
#pragma unroll
      for (int i = 0; i < 4; ++i)
#pragma unroll
        for (int j = 0; j < 4; ++j)
          acc[i][j] = MFMA16(af[i], bf[j], acc[i][j]);
    }
  }
  const int m_blk = m0 + wr * 64, n_blk = n0 + wc * 64;
#pragma unroll
  for (int j = 0; j < 4; ++j) {
    const int n = n_blk + j * 16 + fr;
    const float bi = bias[n];
#pragma unroll
    for (int i = 0; i < 4; ++i)
#pragma unroll
      for (int r = 0; r < 4; ++r) {
        const int m = m_blk + i * 16 + fg * 4 + r;
        outp[(size_t)m * DM_ + n] = acc[i][j][r] + bi;
      }
  }
}

// ---------------- kvstate (MFMA, SC=128): bf16 state + f32 ksum ------------
__global__ __launch_bounds__(256) void kvstate_k(
    const u16* __restrict__ k, const u16* __restrict__ v,
    const u16* __restrict__ omb, const float* __restrict__ nhk,
    u16* __restrict__ stateb, float* __restrict__ ksum) {
  __shared__ u16 sPhi[256][72];
  __shared__ u16 sVt[64][72];
  const int tid = threadIdx.x, lane = tid & 63, w = tid >> 6;
  const int fr = lane & 15, fg = lane >> 4;
  const int sc = blockIdx.x, bh = blockIdx.y;
  const size_t base_l = (size_t)bh * L_ + (size_t)sc * 128;

  bf16x8 ones;
#pragma unroll
  for (int e = 0; e < 8; ++e) ones[e] = (short)0x3F80;

  f32x4 kvacc[4][4] = {};
  f32x4 ksacc[4] = {};

  for (int sub = 0; sub < 2; ++sub) {
    const size_t tl = base_l + sub * 64;
    const u16* kg = k + tl * 64;
    __syncthreads();
    {
      const u16* vp = v + (tl + lane) * 64 + w * 16;
      bf16x8 v0 = *(const bf16x8*)(vp);
      bf16x8 v1 = *(const bf16x8*)(vp + 8);
#pragma unroll
      for (int e = 0; e < 8; ++e) sVt[w * 16 + e][lane] = (u16)v0[e];
#pragma unroll
      for (int e = 0; e < 8; ++e) sVt[w * 16 + 8 + e][lane] = (u16)v1[e];
    }
    float nhr[4];
#pragma unroll
    for (int tt = 0; tt < 4; ++tt) nhr[tt] = nhk[tl + tt * 16 + fr];
#pragma unroll
    for (int mi = 0; mi < 4; ++mi) {
      const int m0 = (w << 6) + mi * 16;
      const bf16x8 a0 = *(const bf16x8*)(omb + (m0 + fr) * 64 + fg * 8);
      const bf16x8 a1 = *(const bf16x8*)(omb + (m0 + fr) * 64 + 32 + fg * 8);
#pragma unroll
      for (int tt = 0; tt < 4; ++tt) {
        const bf16x8 b0 = *(const bf16x8*)(kg + (tt * 16 + fr) * 64 + fg * 8);
        const bf16x8 b1 = *(const bf16x8*)(kg + (tt * 16 + fr) * 64 + 32 + fg * 8);
        f32x4 acc = {0.f, 0.f, 0.f, 0.f};
        acc = MFMA16(a0, b0, acc);
        acc = MFMA16(a1, b1, acc);
        const float nhv = nhr[tt];
#pragma unroll
        for (int r = 0; r < 4; ++r)
          sPhi[m0 + fg * 4 + r][tt * 16 + fr] = f2bf(__expf(acc[r] - nhv) * 0.0625f);
      }
    }
    __syncthreads();
#pragma unroll
    for (int mi = 0; mi < 4; ++mi) {
      const int m0 = (w << 6) + mi * 16;
      const bf16x8 pb0 = *(const bf16x8*)&sPhi[m0 + fr][fg * 8];
      const bf16x8 pb1 = *(const bf16x8*)&sPhi[m0 + fr][32 + fg * 8];
      ksacc[mi] = MFMA16(pb0, ones, ksacc[mi]);
      ksacc[mi] = MFMA16(pb1, ones, ksacc[mi]);
#pragma unroll
      for (int dj = 0; dj < 4; ++dj) {
        const bf16x8 va0 = *(const bf16x8*)&sVt[dj * 16 + fr][fg * 8];
        const bf16x8 va1 = *(const bf16x8*)&sVt[dj * 16 + fr][32 + fg * 8];
        kvacc[mi][dj] = MFMA16(va0, pb0, kvacc[mi][dj]);
        kvacc[mi][dj] = MFMA16(va1, pb1, kvacc[mi][dj]);
      }
    }
  }
  // state bf16 [d][m]; ksum f32
  u16* stb = stateb + (size_t)(bh * NSC + sc) * (M_ * D_);
  float* ksp = ksum + (size_t)(bh * NSC + sc) * M_;
#pragma unroll
  for (int mi = 0; mi < 4; ++mi) {
    const int m = (w << 6) + mi * 16 + fr;
#pragma unroll
    for (int dj = 0; dj < 4; ++dj)
#pragma unroll
      for (int r = 0; r < 4; ++r)
        stb[(size_t)(dj * 16 + fg * 4 + r) * M_ + m] = f2bf(kvacc[mi][dj][r]);
    if (fr == 0) {
#pragma unroll
      for (int r = 0; r < 4; ++r)
        ksp[(w << 6) + mi * 16 + fg * 4 + r] = ksacc[mi][r];
    }
  }
}

// ---------------- exclusive prefix over superchunks (bf16 state) -----------
__global__ __launch_bounds__(256) void scan_k(u16* __restrict__ stateb,
                                              float* __restrict__ ksum) {
  const int bh = blockIdx.y;
  u16* sb = stateb + (size_t)bh * NSC * (M_ * D_);
  const int base = blockIdx.x * 2048 + threadIdx.x * 8;
  float run[8] = {};
  for (int cc = 0; cc < NSC; ++cc) {
    u16* st = sb + (size_t)cc * (M_ * D_) + base;
    ushort4 t0 = *(ushort4*)st;
    ushort4 t1 = *(ushort4*)(st + 4);
    ushort4 w0, w1;
    w0.x = f2bf(run[0]); w0.y = f2bf(run[1]); w0.z = f2bf(run[2]); w0.w = f2bf(run[3]);
    w1.x = f2bf(run[4]); w1.y = f2bf(run[5]); w1.z = f2bf(run[6]); w1.w = f2bf(run[7]);
    *(ushort4*)st = w0;
    *(ushort4*)(st + 4) = w1;
    run[0] += bf2f(t0.x); run[1] += bf2f(t0.y); run[2] += bf2f(t0.z); run[3] += bf2f(t0.w);
    run[4] += bf2f(t1.x); run[5] += bf2f(t1.y); run[6] += bf2f(t1.z); run[7] += bf2f(t1.w);
  }
  if (blockIdx.x == 0) {           // ksum f32 in-place exclusive prefix
    float rk = 0.f;
    for (int cc = 0; cc < NSC; ++cc) {
      float* p = ksum + (size_t)(bh * NSC + cc) * M_ + threadIdx.x;
      const float t = *p;
      *p = rk;
      rk += t;
    }
  }
}

// ---------------- outchunk helpers -----------------------------------------
// phi quadrant: writes ONLY rows of band wb (wb*16..wb*16+15)
static __device__ __forceinline__ void phi_quad(
    const u16* __restrict__ xg, const u16* __restrict__ ombq,
    u16* __restrict__ dst, int dstride, const float* nhv,
    int wb, int lane) {
  const int fr = lane & 15, fg = lane >> 4;
  const int tband = wb * 16;
  const bf16x8 a0 = *(const bf16x8*)(xg + (tband + fr) * 64 + fg * 8);
  const bf16x8 a1 = *(const bf16x8*)(xg + (tband + fr) * 64 + 32 + fg * 8);
#pragma unroll
  for (int j = 0; j < 4; ++j) {
    const bf16x8 b0 = *(const bf16x8*)(ombq + (j * 16 + fr) * 64 + fg * 8);
    const bf16x8 b1 = *(const bf16x8*)(ombq + (j * 16 + fr) * 64 + 32 + fg * 8);
    f32x4 acc = {0.f, 0.f, 0.f, 0.f};
    acc = MFMA16(a0, b0, acc);
    acc = MFMA16(a1, b1, acc);
#pragma unroll
    for (int r = 0; r < 4; ++r) {
      const int t = tband + fg * 4 + r;
      dst[t * dstride + j * 16 + fr] = f2bf(__expf(acc[r] - nhv[r]) * 0.0625f);
    }
  }
}

// ---------------- outchunk: 2-barrier structure ----------------------------
__global__ __launch_bounds__(512) void outchunk_k(
    const u16* __restrict__ q, const u16* __restrict__ kk,
    const u16* __restrict__ v, const u16* __restrict__ omb,
    const u16* __restrict__ stateb, const float* __restrict__ ksum,
    const float* __restrict__ nhq, const float* __restrict__ nhk,
    u16* __restrict__ attn) {
  __shared__ u16 sKa[64][264];    // Kp chunk0 (h0-produced)
  __shared__ u16 sKb[64][264];    // Kp chunk1 (h1-produced)
  __shared__ u16 sS0[64][72];     // h0 q-scratch / h0 masked S
  __shared__ u16 sS1[64][72];     // h1 q-scratch / h1 masked S
  __shared__ u16 sB1[64][72];     // vT chunk0 (h0-staged)
  __shared__ u16 sB2[64][72];     // vT chunk1 (h1-staged)
  __shared__ float ksum_l[256];   // total 105,472 B -> 1 block/CU
  const int tid = threadIdx.x, lane = tid & 63, w = tid >> 6;
  const int h = w >> 2, wl = w & 3;
  const int fr = lane & 15, fg = lane >> 4;
  const int bh = blockIdx.x >> 5, sc = blockIdx.x & 31;
  const size_t base_l = (size_t)bh * L_ + (size_t)sc * 128;
  const size_t tokq = base_l + (size_t)h * 64;
  const u16* qg = q + tokq * 64;
  const u16* stgb = stateb + (size_t)(bh * NSC + sc) * (M_ * D_);   // [d][m]
  const float* ksg = ksum + (size_t)(bh * NSC + sc) * M_;

  if (tid < 256) ksum_l[tid] = ksg[tid];

  // early v loads: half h loads its own chunk's v (staged to sB1/sB2 later)
  bf16x8 ev0, ev1;
  {
    const u16* vp = v + (base_l + (size_t)h * 64 + lane) * 64 + wl * 16;
    ev0 = *(const bf16x8*)(vp);
    ev1 = *(const bf16x8*)(vp + 8);
  }

  // phi(k): half h fills its chunk's Kp entirely (own rows, no syncs)
  u16* kdst = (h == 0) ? &sKa[0][0] : &sKb[0][0];
  {
    const size_t ktokh = base_l + (size_t)h * 64;
    const u16* kgh = kk + ktokh * 64;
    float nhkh[4];
#pragma unroll
    for (int r = 0; r < 4; ++r) nhkh[r] = nhk[ktokh + wl * 16 + fg * 4 + r];
#pragma unroll
    for (int mq = 0; mq < 4; ++mq)
      phi_quad(kgh, omb + mq * 4096, kdst + mq * 64, 264, nhkh, wl, lane);
  }

  // phi(q) -> regs via own half's S buffer as scratch (stride 72; rows
  // wave-private: written+read only by this wave until masked-S overwrites
  // them, also by this wave). Cross term fused (state B-frags pre-loaded;
  // their latency hides under the phi(k) compute above).
  float nhq4[4];
#pragma unroll
  for (int r = 0; r < 4; ++r) nhq4[r] = nhq[tokq + wl * 16 + fg * 4 + r];
  u16* myscr = (h == 0) ? &sS0[0][0] : &sS1[0][0];
  bf16x8 qa0[2], qa1[2], qa2[2], qa3[2];
  f32x4 oacc[4] = {};
#define QPHASE(MQ, QA)                                                          \
  {                                                                             \
    bf16x8 b0r[4], b1r[4];                                                      \
    _Pragma("unroll")                                                           \
    for (int j = 0; j < 4; ++j) {                                               \
      b0r[j] = *(const bf16x8*)(stgb + (size_t)(j * 16 + fr) * M_ + MQ * 64 + fg * 8);        \
      b1r[j] = *(const bf16x8*)(stgb + (size_t)(j * 16 + fr) * M_ + MQ * 64 + 32 + fg * 8);   \
    }                                                                           \
    phi_quad(qg, omb + MQ * 4096, myscr, 72, nhq4, wl, lane);                   \
    QA[0] = *(const bf16x8*)(myscr + (wl * 16 + fr) * 72 + fg * 8);             \
    QA[1] = *(const bf16x8*)(myscr + (wl * 16 + fr) * 72 + 32 + fg * 8);        \
    __builtin_amdgcn_s_setprio(1);                                              \
    _Pragma("unroll")                                                           \
    for (int j = 0; j < 4; ++j) {                                               \
      oacc[j] = MFMA16(QA[0], b0r[j], oacc[j]);                                 \
      oacc[j] = MFMA16(QA[1], b1r[j], oacc[j]);                                 \
    }                                                                           \
    __builtin_amdgcn_s_setprio(0);                                              \
  }
  QPHASE(0, qa0)
  QPHASE(1, qa1)
  QPHASE(2, qa2)
  QPHASE(3, qa3)
#undef QPHASE
  __syncthreads();   // BAR K: ksum_l + full Kp (sKa/sKb) visible to all

  // den-ksum from register frags
  float denk = 0.f;
#pragma unroll
  for (int e = 0; e < 8; ++e) {
    denk += bf2f((u16)qa0[0][e]) * ksum_l[0   + fg * 8 + e]
          + bf2f((u16)qa0[1][e]) * ksum_l[32  + fg * 8 + e]
          + bf2f((u16)qa1[0][e]) * ksum_l[64  + fg * 8 + e]
          + bf2f((u16)qa1[1][e]) * ksum_l[96  + fg * 8 + e]
          + bf2f((u16)qa2[0][e]) * ksum_l[128 + fg * 8 + e]
          + bf2f((u16)qa2[1][e]) * ksum_l[160 + fg * 8 + e]
          + bf2f((u16)qa3[0][e]) * ksum_l[192 + fg * 8 + e]
          + bf2f((u16)qa3[1][e]) * ksum_l[224 + fg * 8 + e];
  }
  denk += __shfl_xor(denk, 16, 64);
  denk += __shfl_xor(denk, 32, 64);

  // ---- S chunk0 (all waves): 32 MFMA, B-frags from sKa
  float dS[4] = {0.f, 0.f, 0.f, 0.f};
  {
    f32x4 sacc[4] = {};
    __builtin_amdgcn_s_setprio(1);
#define SPH0(MQ, QA)                                                            \
    _Pragma("unroll")                                                           \
    for (int j = 0; j < 4; ++j) {                                               \
      const bf16x8 b0 = *(const bf16x8*)&sKa[j * 16 + fr][MQ * 64 + fg * 8];    \
      const bf16x8 b1 = *(const bf16x8*)&sKa[j * 16 + fr][MQ * 64 + 32 + fg * 8]; \
      sacc[j] = MFMA16(QA[0], b0, sacc[j]);                                     \
      sacc[j] = MFMA16(QA[1], b1, sacc[j]);                                     \
    }
    SPH0(0, qa0)
    SPH0(1, qa1)
    SPH0(2, qa2)
    SPH0(3, qa3)
#undef SPH0
    __builtin_amdgcn_s_setprio(0);
    // masked write to own half's S buffer (own-band rows; overwrites the
    // q-scratch AFTER this wave's register read-back — same-wave in-order).
    u16 (*sSo)[72] = (h == 0) ? sS0 : sS1;
#pragma unroll
    for (int j = 0; j < 4; ++j)
#pragma unroll
      for (int r = 0; r < 4; ++r) {
        const int ss = j * 16 + fr, t = wl * 16 + fg * 4 + r;
        float val = sacc[j][r];
        if (h == 0 && ss > t) val = 0.f;
        const u16 vb = f2bf(val);
        sSo[t][ss] = vb;
        dS[r] += bf2f(vb);
      }
  }
  // vT staging: h0 -> sB1 (chunk0), h1 -> sB2 (chunk1); fresh buffers
  {
    u16 (*sBo)[72] = (h == 0) ? sB1 : sB2;
#pragma unroll
    for (int e = 0; e < 8; ++e) sBo[wl * 16 + e][lane] = (u16)ev0[e];
#pragma unroll
    for (int e = 0; e < 8; ++e) sBo[wl * 16 + 8 + e][lane] = (u16)ev1[e];
  }
  __syncthreads();   // BAR F0: sS0/sS1 + sB1/sB2 visible

  // ---- S@V chunk0 (all waves): A = own masked S (own band), B = sB1
  {
    const u16 (*sSo)[72] = (h == 0) ? sS0 : sS1;
    const bf16x8 a0 = *(const bf16x8*)&sSo[wl * 16 + fr][fg * 8];
    const bf16x8 a1 = *(const bf16x8*)&sSo[wl * 16 + fr][32 + fg * 8];
    __builtin_amdgcn_s_setprio(1);
#pragma unroll
    for (int j = 0; j < 4; ++j) {
      const bf16x8 b0 = *(const bf16x8*)&sB1[j * 16 + fr][fg * 8];
      const bf16x8 b1 = *(const bf16x8*)&sB1[j * 16 + fr][32 + fg * 8];
      oacc[j] = MFMA16(a0, b0, oacc[j]);
      oacc[j] = MFMA16(a1, b1, oacc[j]);
    }
    __builtin_amdgcn_s_setprio(0);
  }

  // ---- h1 only: S chunk1 (sKb) -> masked sS1 (same-wave overwrite after
  //      its own A-reads above; in-order LDS) -> S@V chunk1 (B = sB2)
  if (h == 1) {
    f32x4 sacc[4] = {};
    __builtin_amdgcn_s_setprio(1);
#define SPH1(MQ, QA)                                                            \
    _Pragma("unroll")                                                           \
    for (int j = 0; j < 4; ++j) {                                               \
      const bf16x8 b0 = *(const bf16x8*)&sKb[j * 16 + fr][MQ * 64 + fg * 8];    \
      const bf16x8 b1 = *(const bf16x8*)&sKb[j * 16 + fr][MQ * 64 + 32 + fg * 8]; \
      sacc[j] = MFMA16(QA[0], b0, sacc[j]);                                     \
      sacc[j] = MFMA16(QA[1], b1, sacc[j]);                                     \
    }
    SPH1(0, qa0)
    SPH1(1, qa1)
    SPH1(2, qa2)
    SPH1(3, qa3)
#undef SPH1
    __builtin_amdgcn_s_setprio(0);
#pragma unroll
    for (int j = 0; j < 4; ++j)
#pragma unroll
      for (int r = 0; r < 4; ++r) {
        const int ss = j * 16 + fr, t = wl * 16 + fg * 4 + r;
        float val = sacc[j][r];
        if (ss > t) val = 0.f;           // diag (s == h == 1)
        const u16 vb = f2bf(val);
        sS1[t][ss] = vb;
        dS[r] += bf2f(vb);
      }
    {
      const bf16x8 a0 = *(const bf16x8*)&sS1[wl * 16 + fr][fg * 8];
      const bf16x8 a1 = *(const bf16x8*)&sS1[wl * 16 + fr][32 + fg * 8];
      __builtin_amdgcn_s_setprio(1);
#pragma unroll
      for (int j = 0; j < 4; ++j) {
        const bf16x8 b0 = *(const bf16x8*)&sB2[j * 16 + fr][fg * 8];
        const bf16x8 b1 = *(const bf16x8*)&sB2[j * 16 + fr][32 + fg * 8];
        oacc[j] = MFMA16(a0, b0, oacc[j]);
        oacc[j] = MFMA16(a1, b1, oacc[j]);
      }
      __builtin_amdgcn_s_setprio(0);
    }
  }

  // den: reduce dS over fr lanes; combine with denk via shfl
#pragma unroll
  for (int m2 = 1; m2 <= 8; m2 <<= 1) {
#pragma unroll
    for (int r = 0; r < 4; ++r) dS[r] += __shfl_xor(dS[r], m2, 64);
  }
  const int b = bh >> 4, hh = bh & 15;
#pragma unroll
  for (int r = 0; r < 4; ++r) {
    const float dk = __shfl(denk, fg * 4 + r, 64);   // token wl*16+fg*4+r
    const float rinv = 1.0f / (dk + dS[r] + 1e-6f);
    const int t = wl * 16 + fg * 4 + r;
    const int l = sc * 128 + h * 64 + t;
#pragma unroll
    for (int j = 0; j < 4; ++j) {
      const int d = j * 16 + fr;
      attn[((size_t)b * L_ + l) * DM_ + hh * 64 + d] = f2bf(oacc[j][r] * rinv);
    }
  }
}

extern "C" void kernel_launch(void* const* d_in, const int* in_sizes, int n_in,
                              void* d_out, int out_size, void* d_ws, size_t ws_size,
                              hipStream_t stream) {
  const float* x     = (const float*)d_in[0];
  const float* Wq    = (const float*)d_in[1];
  const float* bq    = (const float*)d_in[2];
  const float* Wk    = (const float*)d_in[3];
  const float* bk    = (const float*)d_in[4];
  const float* Wv    = (const float*)d_in[5];
  const float* bv    = (const float*)d_in[6];
  const float* Wo    = (const float*)d_in[7];
  const float* bo    = (const float*)d_in[8];
  const float* omega = (const float*)d_in[9];
  float* out = (float*)d_out;

  char* ws = (char*)d_ws;
  u16*   v      = (u16*)(ws);                           // 32 MB
  u16*   qb     = (u16*)(ws + 33554432ull);             // 32 MB
  u16*   kb     = (u16*)(ws + 67108864ull);             // 32 MB
  u16*   xb     = (u16*)(ws + 100663296ull);            // 32 MB (alias attn)
  u16*   attn   = xb;
  u16*   stateb = (u16*)(ws + 134217728ull);            // 64 MB
  float* ksum   = (float*)(ws + 201326592ull);          // 2 MB
  u16*   Wt     = (u16*)(ws + 203423744ull);            // 8 MB
  u16*   omb    = (u16*)(ws + 211812352ull);            // 32 KB
  float* nhq    = (float*)(ws + 211845120ull);          // 1 MB
  float* nhk    = (float*)(ws + 212893696ull);          // 1 MB -> 204 MB

  prep_k<<<17472, 256, 0, stream>>>(x, xb, Wq, Wk, Wv, Wo, Wt, omega, omb);
  mm3_k<<<dim3(1024, 3), 256, 0, stream>>>(xb, Wt, bq, bk, bv,
                                           qb, kb, v, nhq, nhk);
  kvstate_k<<<dim3(NSC, BH_), 256, 0, stream>>>(kb, v, omb, nhk, stateb, ksum);
  scan_k<<<dim3(8, BH_), 256, 0, stream>>>(stateb, ksum);
  outchunk_k<<<BH_ * NSC, 512, 0, stream>>>(qb, kb, v, omb, stateb, ksum,
                                            nhq, nhk, attn);
  mmo_k<<<1024, 256, 0, stream>>>(attn, Wt + 3145728ull, bo, out);
}

// Round 20
// 460.451 us; speedup vs baseline: 1.2307x; 1.0988x over previous
//
#include <hip/hip_runtime.h>
#include <hip/hip_bf16.h>

// FAVOR+ attention, MI355X. Round 20:
//  - outchunk: TWO superchunks per block (grid 1024, it=0,1 loop, trailing
//    full barrier per iteration) -> 4 of 8 per-CU round transitions become
//    one barrier instead of {drain+dispatch+cold prologue}.
//  - ln16 folded into nh (nh' = 0.0625*ss + ln16; phi = exp(acc - nh')):
//    drops the x0.0625 mul (128/wave in outchunk, 64 in kvstate). Applied
//    consistently in mm3 (producer), kvstate, outchunk.
//  - prep_k / mmo_k / scan_k: byte-identical to R19.
//
// Workspace (bytes), total 213,942,272 (~204 MB): layout as R17-R19.

#define B_ 4
#define H_ 16
#define L_ 4096
#define D_ 64
#define M_ 256
#define DM_ 1024
#define BH_ 64
#define NSC 32            // superchunks per bh (SC = 128 tokens)

typedef unsigned int u32;
typedef unsigned short u16;
typedef __attribute__((ext_vector_type(8))) short bf16x8;
typedef __attribute__((ext_vector_type(4))) float f32x4;

static __device__ __forceinline__ float bf2f(u16 u) {
  return __uint_as_float(((u32)u) << 16);
}
static __device__ __forceinline__ u16 f2bf(float f) {
  u32 x = __float_as_uint(f);
  return (u16)((x + 0x7fffu + ((x >> 16) & 1u)) >> 16);   // RNE
}
#define MFMA16(a, b, c) __builtin_amdgcn_mfma_f32_16x16x32_bf16((a), (b), (c), 0, 0, 0)
#define LN16 2.772588722239781f

// ---------------- merged prep: convx | convw | convom ----------------------
__global__ __launch_bounds__(256) void prep_k(
    const float* __restrict__ x, u16* __restrict__ xb,
    const float* __restrict__ W0, const float* __restrict__ W1,
    const float* __restrict__ W2, const float* __restrict__ W3,
    u16* __restrict__ Wt, const float* __restrict__ om,
    u16* __restrict__ omb) {
  __shared__ u16 tt[64][66];
  const int bid = blockIdx.x, tid = threadIdx.x;
  if (bid < 16384) {
    const int i = bid * 256 + tid;
    float4 f = ((const float4*)x)[i];
    ushort4 u;
    u.x = f2bf(f.x); u.y = f2bf(f.y); u.z = f2bf(f.z); u.w = f2bf(f.w);
    ((ushort4*)xb)[i] = u;
  } else if (bid < 17408) {
    const int rem = bid - 16384;
    const int z = rem >> 8, r2 = rem & 255;
    const int k0 = (r2 >> 4) * 64, n0 = (r2 & 15) * 64;
    const float* W = (z == 0) ? W0 : (z == 1) ? W1 : (z == 2) ? W2 : W3;
    u16* o = Wt + (size_t)z * 1048576ull;
    const int r = tid >> 4, c4 = (tid & 15) << 2;
    for (int rr = r; rr < 64; rr += 16) {
      float4 w4 = *(const float4*)(W + (size_t)(k0 + rr) * DM_ + n0 + c4);
      tt[c4 + 0][rr] = f2bf(w4.x);
      tt[c4 + 1][rr] = f2bf(w4.y);
      tt[c4 + 2][rr] = f2bf(w4.z);
      tt[c4 + 3][rr] = f2bf(w4.w);
    }
    __syncthreads();
    for (int rr = r; rr < 64; rr += 16) {
      ushort4 u4;
      u4.x = tt[rr][c4 + 0];
      u4.y = tt[rr][c4 + 1];
      u4.z = tt[rr][c4 + 2];
      u4.w = tt[rr][c4 + 3];
      *(ushort4*)(o + (size_t)(n0 + rr) * DM_ + k0 + c4) = u4;
    }
  } else {
    const int i = (bid - 17408) * 256 + tid;
    omb[i] = f2bf(om[i] * 0.35355339059327373f);     // fold 64^-0.25
  }
}

// ---------------- merged projection GEMMs (q,k,v), head bf16 out -----------
// nh' = 0.0625 * sum(bf2f(f2bf(v))^2) + ln16  (phi scale folded in)
__global__ __launch_bounds__(256) void mm3_k(
    const u16* __restrict__ A, const u16* __restrict__ Wt,
    const float* __restrict__ bq, const float* __restrict__ bk,
    const float* __restrict__ bv, u16* __restrict__ qb,
    u16* __restrict__ kb, u16* __restrict__ vb,
    float* __restrict__ nhq, float* __restrict__ nhk) {
  __shared__ u16 sA[128][64];   // 16 KB, XOR-swizzled 16B slots
  __shared__ u16 sB[128][64];   // 16 KB
  const int y = blockIdx.y;
  const u16* Bt = Wt + (size_t)y * 1048576ull;
  const float* bias = (y == 0) ? bq : (y == 1) ? bk : bv;
  u16* outp = (y == 0) ? qb : (y == 1) ? kb : vb;
  float* nhout = (y == 0) ? nhq : (y == 1) ? nhk : nullptr;
  const int tid = threadIdx.x, lane = tid & 63, w = tid >> 6;
  const int fr = lane & 15, fg = lane >> 4;
  const int wr = w >> 1, wc = w & 1;
  const int lb = ((blockIdx.x & 7) << 7) | (blockIdx.x >> 3);
  const int m0 = (lb >> 3) * 128, n0 = (lb & 7) * 128;
  const int srow = tid >> 3, sslot = tid & 7;   // +p*32 rows per pass
  f32x4 acc[4][4] = {};
  bf16x8 av[4], bv4[4];
#pragma unroll
  for (int p = 0; p < 4; ++p) {
    av[p]  = *(const bf16x8*)(A  + (size_t)(m0 + srow + p * 32) * DM_ + sslot * 8);
    bv4[p] = *(const bf16x8*)(Bt + (size_t)(n0 + srow + p * 32) * DM_ + sslot * 8);
  }
  for (int k0 = 0; k0 < DM_; k0 += 64) {
    __syncthreads();
#pragma unroll
    for (int p = 0; p < 4; ++p) {
      const int r = srow + p * 32;
      *(bf16x8*)&sA[r][(sslot ^ (r & 7)) * 8] = av[p];
      *(bf16x8*)&sB[r][(sslot ^ (r & 7)) * 8] = bv4[p];
    }
    if (k0 + 64 < DM_) {
#pragma unroll
      for (int p = 0; p < 4; ++p) {
        av[p]  = *(const bf16x8*)(A  + (size_t)(m0 + srow + p * 32) * DM_ + k0 + 64 + sslot * 8);
        bv4[p] = *(const bf16x8*)(Bt + (size_t)(n0 + srow + p * 32) * DM_ + k0 + 64 + sslot * 8);
      }
    }
    __syncthreads();
#pragma unroll
    for (int ks = 0; ks < 2; ++ks) {
      bf16x8 af[4], bf[4];
#pragma unroll
      for (int i = 0; i < 4; ++i) {
        const int r = wr * 64 + i * 16 + fr;
        af[i] = *(const bf16x8*)&sA[r][((ks * 4 + fg) ^ (r & 7)) * 8];
      }
#pragma unroll
      for (int j = 0; j < 4; ++j) {
        const int r = wc * 64 + j * 16 + fr;
        bf[j] = *(const bf16x8*)&sB[r][((ks * 4 + fg) ^ (r & 7)) * 8];
      }
#pragma unroll
      for (int i = 0; i < 4; ++i)
#pragma unroll
        for (int j = 0; j < 4; ++j)
          acc[i][j] = MFMA16(af[i], bf[j], acc[i][j]);
    }
  }
  const int m_blk = m0 + wr * 64, n_blk = n0 + wc * 64;
  float nhacc[4][4] = {};
#pragma unroll
  for (int j = 0; j < 4; ++j) {
    const int n = n_blk + j * 16 + fr;
    const float bi = bias[n];
    const int h = n >> 6, d = n & 63;
#pragma unroll
    for (int i = 0; i < 4; ++i) {
#pragma unroll
      for (int r = 0; r < 4; ++r) {
        const int m = m_blk + i * 16 + fg * 4 + r;
        const float val = acc[i][j][r] + bi;
        const int b = m >> 12, l = m & 4095;
        const u16 sv = f2bf(val);
        outp[((size_t)(b * H_ + h) * L_ + l) * D_ + d] = sv;
        const float rv = bf2f(sv);
        nhacc[i][r] += rv * rv;
      }
    }
  }
  if (nhout) {
    const int hh2 = n_blk >> 6;
#pragma unroll
    for (int i = 0; i < 4; ++i)
#pragma unroll
      for (int r = 0; r < 4; ++r) {
        float s = nhacc[i][r];
        s += __shfl_xor(s, 1, 64);
        s += __shfl_xor(s, 2, 64);
        s += __shfl_xor(s, 4, 64);
        s += __shfl_xor(s, 8, 64);
        if (fr == 0) {
          const int m = m_blk + i * 16 + fg * 4 + r;
          const int b = m >> 12, l = m & 4095;
          nhout[(size_t)(b * H_ + hh2) * L_ + l] = 0.0625f * s + LN16;
        }
      }
  }
}

// ---------------- final GEMM (attn bf16 -> f32 out), validated -------------
__global__ __launch_bounds__(256) void mmo_k(
    const u16* __restrict__ A, const u16* __restrict__ Bt,
    const float* __restrict__ bias, float* __restrict__ outp) {
  __shared__ u16 sA[128][64];
  __shared__ u16 sB[128][64];
  const int tid = threadIdx.x, lane = tid & 63, w = tid >> 6;
  const int fr = lane & 15, fg = lane >> 4;
  const int wr = w >> 1, wc = w & 1;
  const int lb = ((blockIdx.x & 7) << 7) | (blockIdx.x >> 3);
  const int m0 = (lb >> 3) * 128, n0 = (lb & 7) * 128;
  const int srow = tid >> 3, sslot = tid & 7;
  f32x4 acc[4][4] = {};
  bf16x8 av[4], bv[4];
#pragma unroll
  for (int p = 0; p < 4; ++p) {
    av[p] = *(const bf16x8*)(A  + (size_t)(m0 + srow + p * 32) * DM_ + sslot * 8);
    bv[p] = *(const bf16x8*)(Bt + (size_t)(n0 + srow + p * 32) * DM_ + sslot * 8);
  }
  for (int k0 = 0; k0 < DM_; k0 += 64) {
    __syncthreads();
#pragma unroll
    for (int p = 0; p < 4; ++p) {
      const int r = srow + p * 32;
      *(bf16x8*)&sA[r][(sslot ^ (r & 7)) * 8] = av[p];
      *(bf16x8*)&sB[r][(sslot ^ (r & 7)) * 8] = bv[p];
    }
    if (k0 + 64 < DM_) {
#pragma unroll
      for (int p = 0; p < 4; ++p) {
        av[p] = *(const bf16x8*)(A  + (size_t)(m0 + srow + p * 32) * DM_ + k0 + 64 + sslot * 8);
        bv[p] = *(const bf16x8*)(Bt + (size_t)(n0 + srow + p * 32) * DM_ + k0 + 64 + sslot * 8);
      }
    }
    __syncthreads();
#pragma unroll
    for (int ks = 0; ks < 2; ++ks) {
      bf16x8 af[4], bf[4];
#pragma unroll
      for (int i = 0; i < 4; ++i) {
        const int r = wr * 64 + i * 16 + fr;
        af[i] = *(const bf16x8*)&sA[r][((ks * 4 + fg) ^ (r & 7)) * 8];
      }
#pragma unroll
      for (int j = 0; j < 4; ++j) {
        const int r = wc * 64 + j * 16 + fr;
        bf[j] = *(const bf16x8*)&sB[r][((ks * 4 + fg) ^ (r & 7)) * 8];
      }
#pragma unroll
      for (int i = 0; i < 4; ++i)
#pragma unroll
        for (int j = 0; j < 4; ++j)
          acc[i][j] = MFMA16(af[i], bf[j], acc[i][j]);
    }
  }
  const int m_blk = m0 + wr * 64, n_blk = n0 + wc * 64;
#pragma unroll
  for (int j = 0; j < 4; ++j) {
    const int n = n_blk + j * 16 + fr;
    const float bi = bias[n];
#pragma unroll
    for (int i = 0; i < 4; ++i)
#pragma unroll
      for (int r = 0; r < 4; ++r) {
        const int m = m_blk + i * 16 + fg * 4 + r;
        outp[(size_t)m * DM_ + n] = acc[i][j][r] + bi;
      }
  }
}

// ---------------- kvstate (MFMA, SC=128): bf16 state + f32 ksum ------------
__global__ __launch_bounds__(256) void kvstate_k(
    const u16* __restrict__ k, const u16* __restrict__ v,
    const u16* __restrict__ omb, const float* __restrict__ nhk,
    u16* __restrict__ stateb, float* __restrict__ ksum) {
  __shared__ u16 sPhi[256][72];
  __shared__ u16 sVt[64][72];
  const int tid = threadIdx.x, lane = tid & 63, w = tid >> 6;
  const int fr = lane & 15, fg = lane >> 4;
  const int sc = blockIdx.x, bh = blockIdx.y;
  const size_t base_l = (size_t)bh * L_ + (size_t)sc * 128;

  bf16x8 ones;
#pragma unroll
  for (int e = 0; e < 8; ++e) ones[e] = (short)0x3F80;

  f32x4 kvacc[4][4] = {};
  f32x4 ksacc[4] = {};

  for (int sub = 0; sub < 2; ++sub) {
    const size_t tl = base_l + sub * 64;
    const u16* kg = k + tl * 64;
    __syncthreads();
    {
      const u16* vp = v + (tl + lane) * 64 + w * 16;
      bf16x8 v0 = *(const bf16x8*)(vp);
      bf16x8 v1 = *(const bf16x8*)(vp + 8);
#pragma unroll
      for (int e = 0; e < 8; ++e) sVt[w * 16 + e][lane] = (u16)v0[e];
#pragma unroll
      for (int e = 0; e < 8; ++e) sVt[w * 16 + 8 + e][lane] = (u16)v1[e];
    }
    float nhr[4];
#pragma unroll
    for (int tt = 0; tt < 4; ++tt) nhr[tt] = nhk[tl + tt * 16 + fr];
#pragma unroll
    for (int mi = 0; mi < 4; ++mi) {
      const int m0 = (w << 6) + mi * 16;
      const bf16x8 a0 = *(const bf16x8*)(omb + (m0 + fr) * 64 + fg * 8);
      const bf16x8 a1 = *(const bf16x8*)(omb + (m0 + fr) * 64 + 32 + fg * 8);
#pragma unroll
      for (int tt = 0; tt < 4; ++tt) {
        const bf16x8 b0 = *(const bf16x8*)(kg + (tt * 16 + fr) * 64 + fg * 8);
        const bf16x8 b1 = *(const bf16x8*)(kg + (tt * 16 + fr) * 64 + 32 + fg * 8);
        f32x4 acc = {0.f, 0.f, 0.f, 0.f};
        acc = MFMA16(a0, b0, acc);
        acc = MFMA16(a1, b1, acc);
        const float nhv = nhr[tt];
#pragma unroll
        for (int r = 0; r < 4; ++r)
          sPhi[m0 + fg * 4 + r][tt * 16 + fr] = f2bf(__expf(acc[r] - nhv));
      }
    }
    __syncthreads();
#pragma unroll
    for (int mi = 0; mi < 4; ++mi) {
      const int m0 = (w << 6) + mi * 16;
      const bf16x8 pb0 = *(const bf16x8*)&sPhi[m0 + fr][fg * 8];
      const bf16x8 pb1 = *(const bf16x8*)&sPhi[m0 + fr][32 + fg * 8];
      ksacc[mi] = MFMA16(pb0, ones, ksacc[mi]);
      ksacc[mi] = MFMA16(pb1, ones, ksacc[mi]);
#pragma unroll
      for (int dj = 0; dj < 4; ++dj) {
        const bf16x8 va0 = *(const bf16x8*)&sVt[dj * 16 + fr][fg * 8];
        const bf16x8 va1 = *(const bf16x8*)&sVt[dj * 16 + fr][32 + fg * 8];
        kvacc[mi][dj] = MFMA16(va0, pb0, kvacc[mi][dj]);
        kvacc[mi][dj] = MFMA16(va1, pb1, kvacc[mi][dj]);
      }
    }
  }
  // state bf16 [d][m]; ksum f32
  u16* stb = stateb + (size_t)(bh * NSC + sc) * (M_ * D_);
  float* ksp = ksum + (size_t)(bh * NSC + sc) * M_;
#pragma unroll
  for (int mi = 0; mi < 4; ++mi) {
    const int m = (w << 6) + mi * 16 + fr;
#pragma unroll
    for (int dj = 0; dj < 4; ++dj)
#pragma unroll
      for (int r = 0; r < 4; ++r)
        stb[(size_t)(dj * 16 + fg * 4 + r) * M_ + m] = f2bf(kvacc[mi][dj][r]);
    if (fr == 0) {
#pragma unroll
      for (int r = 0; r < 4; ++r)
        ksp[(w << 6) + mi * 16 + fg * 4 + r] = ksacc[mi][r];
    }
  }
}

// ---------------- exclusive prefix over superchunks (bf16 state) -----------
__global__ __launch_bounds__(256) void scan_k(u16* __restrict__ stateb,
                                              float* __restrict__ ksum) {
  const int bh = blockIdx.y;
  u16* sb = stateb + (size_t)bh * NSC * (M_ * D_);
  const int base = blockIdx.x * 2048 + threadIdx.x * 8;
  float run[8] = {};
  for (int cc = 0; cc < NSC; ++cc) {
    u16* st = sb + (size_t)cc * (M_ * D_) + base;
    ushort4 t0 = *(ushort4*)st;
    ushort4 t1 = *(ushort4*)(st + 4);
    ushort4 w0, w1;
    w0.x = f2bf(run[0]); w0.y = f2bf(run[1]); w0.z = f2bf(run[2]); w0.w = f2bf(run[3]);
    w1.x = f2bf(run[4]); w1.y = f2bf(run[5]); w1.z = f2bf(run[6]); w1.w = f2bf(run[7]);
    *(ushort4*)st = w0;
    *(ushort4*)(st + 4) = w1;
    run[0] += bf2f(t0.x); run[1] += bf2f(t0.y); run[2] += bf2f(t0.z); run[3] += bf2f(t0.w);
    run[4] += bf2f(t1.x); run[5] += bf2f(t1.y); run[6] += bf2f(t1.z); run[7] += bf2f(t1.w);
  }
  if (blockIdx.x == 0) {           // ksum f32 in-place exclusive prefix
    float rk = 0.f;
    for (int cc = 0; cc < NSC; ++cc) {
      float* p = ksum + (size_t)(bh * NSC + cc) * M_ + threadIdx.x;
      const float t = *p;
      *p = rk;
      rk += t;
    }
  }
}

// ---------------- outchunk helpers -----------------------------------------
// phi quadrant: writes ONLY rows of band wb (wb*16..wb*16+15); nh has ln16
static __device__ __forceinline__ void phi_quad(
    const u16* __restrict__ xg, const u16* __restrict__ ombq,
    u16* __restrict__ dst, int dstride, const float* nhv,
    int wb, int lane) {
  const int fr = lane & 15, fg = lane >> 4;
  const int tband = wb * 16;
  const bf16x8 a0 = *(const bf16x8*)(xg + (tband + fr) * 64 + fg * 8);
  const bf16x8 a1 = *(const bf16x8*)(xg + (tband + fr) * 64 + 32 + fg * 8);
#pragma unroll
  for (int j = 0; j < 4; ++j) {
    const bf16x8 b0 = *(const bf16x8*)(ombq + (j * 16 + fr) * 64 + fg * 8);
    const bf16x8 b1 = *(const bf16x8*)(ombq + (j * 16 + fr) * 64 + 32 + fg * 8);
    f32x4 acc = {0.f, 0.f, 0.f, 0.f};
    acc = MFMA16(a0, b0, acc);
    acc = MFMA16(a1, b1, acc);
#pragma unroll
    for (int r = 0; r < 4; ++r) {
      const int t = tband + fg * 4 + r;
      dst[t * dstride + j * 16 + fr] = f2bf(__expf(acc[r] - nhv[r]));
    }
  }
}

// ---------------- outchunk: 2 superchunks/block, 2+1 barriers --------------
__global__ __launch_bounds__(512) void outchunk_k(
    const u16* __restrict__ q, const u16* __restrict__ kk,
    const u16* __restrict__ v, const u16* __restrict__ omb,
    const u16* __restrict__ stateb, const float* __restrict__ ksum,
    const float* __restrict__ nhq, const float* __restrict__ nhk,
    u16* __restrict__ attn) {
  __shared__ u16 sKa[64][264];    // Kp chunk0 (h0-produced)
  __shared__ u16 sKb[64][264];    // Kp chunk1 (h1-produced)
  __shared__ u16 sS0[64][72];     // h0 q-scratch / h0 masked S
  __shared__ u16 sS1[64][72];     // h1 q-scratch / h1 masked S
  __shared__ u16 sB1[64][72];     // vT chunk0 (h0-staged)
  __shared__ u16 sB2[64][72];     // vT chunk1 (h1-staged)
  __shared__ float ksum_l[256];   // total 105,472 B -> 1 block/CU
  const int tid = threadIdx.x, lane = tid & 63, w = tid >> 6;
  const int h = w >> 2, wl = w & 3;
  const int fr = lane & 15, fg = lane >> 4;
  const int bh = blockIdx.x >> 4, scp = blockIdx.x & 15;

#pragma unroll 1
  for (int it = 0; it < 2; ++it) {
    const int sc = scp * 2 + it;
    const size_t base_l = (size_t)bh * L_ + (size_t)sc * 128;
    const size_t tokq = base_l + (size_t)h * 64;
    const u16* qg = q + tokq * 64;
    const u16* stgb = stateb + (size_t)(bh * NSC + sc) * (M_ * D_);  // [d][m]
    const float* ksg = ksum + (size_t)(bh * NSC + sc) * M_;

    if (tid < 256) ksum_l[tid] = ksg[tid];

    // early v loads: half h loads its own chunk's v
    bf16x8 ev0, ev1;
    {
      const u16* vp = v + (base_l + (size_t)h * 64 + lane) * 64 + wl * 16;
      ev0 = *(const bf16x8*)(vp);
      ev1 = *(const bf16x8*)(vp + 8);
    }

    // phi(k): half h fills its chunk's Kp entirely (own rows, no syncs)
    u16* kdst = (h == 0) ? &sKa[0][0] : &sKb[0][0];
    {
      const size_t ktokh = base_l + (size_t)h * 64;
      const u16* kgh = kk + ktokh * 64;
      float nhkh[4];
#pragma unroll
      for (int r = 0; r < 4; ++r) nhkh[r] = nhk[ktokh + wl * 16 + fg * 4 + r];
#pragma unroll
      for (int mq = 0; mq < 4; ++mq)
        phi_quad(kgh, omb + mq * 4096, kdst + mq * 64, 264, nhkh, wl, lane);
    }

    // phi(q) -> regs via own half's S buffer as scratch (wave-private rows);
    // cross term fused (state B-frag latency hides under phi(k) compute).
    float nhq4[4];
#pragma unroll
    for (int r = 0; r < 4; ++r) nhq4[r] = nhq[tokq + wl * 16 + fg * 4 + r];
    u16* myscr = (h == 0) ? &sS0[0][0] : &sS1[0][0];
    bf16x8 qa0[2], qa1[2], qa2[2], qa3[2];
    f32x4 oacc[4] = {};
#define QPHASE(MQ, QA)                                                          \
    {                                                                           \
      bf16x8 b0r[4], b1r[4];                                                    \
      _Pragma("unroll")                                                         \
      for (int j = 0; j < 4; ++j) {                                             \
        b0r[j] = *(const bf16x8*)(stgb + (size_t)(j * 16 + fr) * M_ + MQ * 64 + fg * 8);      \
        b1r[j] = *(const bf16x8*)(stgb + (size_t)(j * 16 + fr) * M_ + MQ * 64 + 32 + fg * 8); \
      }                                                                         \
      phi_quad(qg, omb + MQ * 4096, myscr, 72, nhq4, wl, lane);                 \
      QA[0] = *(const bf16x8*)(myscr + (wl * 16 + fr) * 72 + fg * 8);           \
      QA[1] = *(const bf16x8*)(myscr + (wl * 16 + fr) * 72 + 32 + fg * 8);      \
      __builtin_amdgcn_s_setprio(1);                                            \
      _Pragma("unroll")                                                         \
      for (int j = 0; j < 4; ++j) {                                             \
        oacc[j] = MFMA16(QA[0], b0r[j], oacc[j]);                               \
        oacc[j] = MFMA16(QA[1], b1r[j], oacc[j]);                               \
      }                                                                         \
      __builtin_amdgcn_s_setprio(0);                                            \
    }
    QPHASE(0, qa0)
    QPHASE(1, qa1)
    QPHASE(2, qa2)
    QPHASE(3, qa3)
#undef QPHASE
    __syncthreads();   // BAR K: ksum_l + full Kp (sKa/sKb) visible to all

    // den-ksum from register frags
    float denk = 0.f;
#pragma unroll
    for (int e = 0; e < 8; ++e) {
      denk += bf2f((u16)qa0[0][e]) * ksum_l[0   + fg * 8 + e]
            + bf2f((u16)qa0[1][e]) * ksum_l[32  + fg * 8 + e]
            + bf2f((u16)qa1[0][e]) * ksum_l[64  + fg * 8 + e]
            + bf2f((u16)qa1[1][e]) * ksum_l[96  + fg * 8 + e]
            + bf2f((u16)qa2[0][e]) * ksum_l[128 + fg * 8 + e]
            + bf2f((u16)qa2[1][e]) * ksum_l[160 + fg * 8 + e]
            + bf2f((u16)qa3[0][e]) * ksum_l[192 + fg * 8 + e]
            + bf2f((u16)qa3[1][e]) * ksum_l[224 + fg * 8 + e];
    }
    denk += __shfl_xor(denk, 16, 64);
    denk += __shfl_xor(denk, 32, 64);

    // ---- S chunk0 (all waves): 32 MFMA, B-frags from sKa
    float dS[4] = {0.f, 0.f, 0.f, 0.f};
    {
      f32x4 sacc[4] = {};
      __builtin_amdgcn_s_setprio(1);
#define SPH0(MQ, QA)                                                            \
      _Pragma("unroll")                                                         \
      for (int j = 0; j < 4; ++j) {                                             \
        const bf16x8 b0 = *(const bf16x8*)&sKa[j * 16 + fr][MQ * 64 + fg * 8];  \
        const bf16x8 b1 = *(const bf16x8*)&sKa[j * 16 + fr][MQ * 64 + 32 + fg * 8]; \
        sacc[j] = MFMA16(QA[0], b0, sacc[j]);                                   \
        sacc[j] = MFMA16(QA[1], b1, sacc[j]);                                   \
      }
      SPH0(0, qa0)
      SPH0(1, qa1)
      SPH0(2, qa2)
      SPH0(3, qa3)
#undef SPH0
      __builtin_amdgcn_s_setprio(0);
      u16 (*sSo)[72] = (h == 0) ? sS0 : sS1;
#pragma unroll
      for (int j = 0; j < 4; ++j)
#pragma unroll
        for (int r = 0; r < 4; ++r) {
          const int ss = j * 16 + fr, t = wl * 16 + fg * 4 + r;
          float val = sacc[j][r];
          if (h == 0 && ss > t) val = 0.f;
          const u16 vb = f2bf(val);
          sSo[t][ss] = vb;
          dS[r] += bf2f(vb);
        }
    }
    // vT staging: h0 -> sB1 (chunk0), h1 -> sB2 (chunk1)
    {
      u16 (*sBo)[72] = (h == 0) ? sB1 : sB2;
#pragma unroll
      for (int e = 0; e < 8; ++e) sBo[wl * 16 + e][lane] = (u16)ev0[e];
#pragma unroll
      for (int e = 0; e < 8; ++e) sBo[wl * 16 + 8 + e][lane] = (u16)ev1[e];
    }
    __syncthreads();   // BAR F0: sS0/sS1 + sB1/sB2 visible

    // ---- S@V chunk0 (all waves): A = own masked S (own band), B = sB1
    {
      const u16 (*sSo)[72] = (h == 0) ? sS0 : sS1;
      const bf16x8 a0 = *(const bf16x8*)&sSo[wl * 16 + fr][fg * 8];
      const bf16x8 a1 = *(const bf16x8*)&sSo[wl * 16 + fr][32 + fg * 8];
      __builtin_amdgcn_s_setprio(1);
#pragma unroll
      for (int j = 0; j < 4; ++j) {
        const bf16x8 b0 = *(const bf16x8*)&sB1[j * 16 + fr][fg * 8];
        const bf16x8 b1 = *(const bf16x8*)&sB1[j * 16 + fr][32 + fg * 8];
        oacc[j] = MFMA16(a0, b0, oacc[j]);
        oacc[j] = MFMA16(a1, b1, oacc[j]);
      }
      __builtin_amdgcn_s_setprio(0);
    }

    // ---- h1 only: S chunk1 (sKb) -> masked sS1 -> S@V chunk1 (sB2)
    if (h == 1) {
      f32x4 sacc[4] = {};
      __builtin_amdgcn_s_setprio(1);
#define SPH1(MQ, QA)                                                            \
      _Pragma("unroll")                                                         \
      for (int j = 0; j < 4; ++j) {                                             \
        const bf16x8 b0 = *(const bf16x8*)&sKb[j * 16 + fr][MQ * 64 + fg * 8];  \
        const bf16x8 b1 = *(const bf16x8*)&sKb[j * 16 + fr][MQ * 64 + 32 + fg * 8]; \
        sacc[j] = MFMA16(QA[0], b0, sacc[j]);                                   \
        sacc[j] = MFMA16(QA[1], b1, sacc[j]);                                   \
      }
      SPH1(0, qa0)
      SPH1(1, qa1)
      SPH1(2, qa2)
      SPH1(3, qa3)
#undef SPH1
      __builtin_amdgcn_s_setprio(0);
#pragma unroll
      for (int j = 0; j < 4; ++j)
#pragma unroll
        for (int r = 0; r < 4; ++r) {
          const int ss = j * 16 + fr, t = wl * 16 + fg * 4 + r;
          float val = sacc[j][r];
          if (ss > t) val = 0.f;         // diag (s == h == 1)
          const u16 vb = f2bf(val);
          sS1[t][ss] = vb;
          dS[r] += bf2f(vb);
        }
      {
        const bf16x8 a0 = *(const bf16x8*)&sS1[wl * 16 + fr][fg * 8];
        const bf16x8 a1 = *(const bf16x8*)&sS1[wl * 16 + fr][32 + fg * 8];
        __builtin_amdgcn_s_setprio(1);
#pragma unroll
        for (int j = 0; j < 4; ++j) {
          const bf16x8 b0 = *(const bf16x8*)&sB2[j * 16 + fr][fg * 8];
          const bf16x8 b1 = *(const bf16x8*)&sB2[j * 16 + fr][32 + fg * 8];
          oacc[j] = MFMA16(a0, b0, oacc[j]);
          oacc[j] = MFMA16(a1, b1, oacc[j]);
        }
        __builtin_amdgcn_s_setprio(0);
      }
    }

    // den: reduce dS over fr lanes; combine with denk via shfl
#pragma unroll
    for (int m2 = 1; m2 <= 8; m2 <<= 1) {
#pragma unroll
      for (int r = 0; r < 4; ++r) dS[r] += __shfl_xor(dS[r], m2, 64);
    }
    const int b = bh >> 4, hh = bh & 15;
#pragma unroll
    for (int r = 0; r < 4; ++r) {
      const float dk = __shfl(denk, fg * 4 + r, 64);   // token wl*16+fg*4+r
      const float rinv = 1.0f / (dk + dS[r] + 1e-6f);
      const int t = wl * 16 + fg * 4 + r;
      const int l = sc * 128 + h * 64 + t;
#pragma unroll
      for (int j = 0; j < 4; ++j) {
        const int d = j * 16 + fr;
        attn[((size_t)b * L_ + l) * DM_ + hh * 64 + d] = f2bf(oacc[j][r] * rinv);
      }
    }
    __syncthreads();   // BAR E: full fence before next superchunk's reuse
  }
}

extern "C" void kernel_launch(void* const* d_in, const int* in_sizes, int n_in,
                              void* d_out, int out_size, void* d_ws, size_t ws_size,
                              hipStream_t stream) {
  const float* x     = (const float*)d_in[0];
  const float* Wq    = (const float*)d_in[1];
  const float* bq    = (const float*)d_in[2];
  const float* Wk    = (const float*)d_in[3];
  const float* bk    = (const float*)d_in[4];
  const float* Wv    = (const float*)d_in[5];
  const float* bv    = (const float*)d_in[6];
  const float* Wo    = (const float*)d_in[7];
  const float* bo    = (const float*)d_in[8];
  const float* omega = (const float*)d_in[9];
  float* out = (float*)d_out;

  char* ws = (char*)d_ws;
  u16*   v      = (u16*)(ws);                           // 32 MB
  u16*   qb     = (u16*)(ws + 33554432ull);             // 32 MB
  u16*   kb     = (u16*)(ws + 67108864ull);             // 32 MB
  u16*   xb     = (u16*)(ws + 100663296ull);            // 32 MB (alias attn)
  u16*   attn   = xb;
  u16*   stateb = (u16*)(ws + 134217728ull);            // 64 MB
  float* ksum   = (float*)(ws + 201326592ull);          // 2 MB
  u16*   Wt     = (u16*)(ws + 203423744ull);            // 8 MB
  u16*   omb    = (u16*)(ws + 211812352ull);            // 32 KB
  float* nhq    = (float*)(ws + 211845120ull);          // 1 MB
  float* nhk    = (float*)(ws + 212893696ull);          // 1 MB -> 204 MB

  prep_k<<<17472, 256, 0, stream>>>(x, xb, Wq, Wk, Wv, Wo, Wt, omega, omb);
  mm3_k<<<dim3(1024, 3), 256, 0, stream>>>(xb, Wt, bq, bk, bv,
                                           qb, kb, v, nhq, nhk);
  kvstate_k<<<dim3(NSC, BH_), 256, 0, stream>>>(kb, v, omb, nhk, stateb, ksum);
  scan_k<<<dim3(8, BH_), 256, 0, stream>>>(stateb, ksum);
  outchunk_k<<<BH_ * (NSC / 2), 512, 0, stream>>>(qb, kb, v, omb, stateb, ksum,
                                                  nhq, nhk, attn);
  mmo_k<<<1024, 256, 0, stream>>>(attn, Wt + 3145728ull, bo, out);
}

// Round 21
// 443.199 us; speedup vs baseline: 1.2786x; 1.0389x over previous
//
#include <hip/hip_runtime.h>
#include <hip/hip_bf16.h>

// FAVOR+ attention, MI355X. Round 21:
//  - outchunk: FOUR superchunks per block (grid 512, it=0..3) -> 6 of 8
//    per-CU round transitions become barriers; __launch_bounds__(512,2)
//    raises the VGPR cap to 256 (kills R20's ~44 MB spill at VGPR=128).
//  - prep_k / mm3_k / mmo_k / kvstate_k / scan_k: byte-identical to R20.
//
// Workspace (bytes), total 213,942,272 (~204 MB): layout as R17-R20.

#define B_ 4
#define H_ 16
#define L_ 4096
#define D_ 64
#define M_ 256
#define DM_ 1024
#define BH_ 64
#define NSC 32            // superchunks per bh (SC = 128 tokens)

typedef unsigned int u32;
typedef unsigned short u16;
typedef __attribute__((ext_vector_type(8))) short bf16x8;
typedef __attribute__((ext_vector_type(4))) float f32x4;

static __device__ __forceinline__ float bf2f(u16 u) {
  return __uint_as_float(((u32)u) << 16);
}
static __device__ __forceinline__ u16 f2bf(float f) {
  u32 x = __float_as_uint(f);
  return (u16)((x + 0x7fffu + ((x >> 16) & 1u)) >> 16);   // RNE
}
#define MFMA16(a, b, c) __builtin_amdgcn_mfma_f32_16x16x32_bf16((a), (b), (c), 0, 0, 0)
#define LN16 2.772588722239781f

// ---------------- merged prep: convx | convw | convom ----------------------
__global__ __launch_bounds__(256) void prep_k(
    const float* __restrict__ x, u16* __restrict__ xb,
    const float* __restrict__ W0, const float* __restrict__ W1,
    const float* __restrict__ W2, const float* __restrict__ W3,
    u16* __restrict__ Wt, const float* __restrict__ om,
    u16* __restrict__ omb) {
  __shared__ u16 tt[64][66];
  const int bid = blockIdx.x, tid = threadIdx.x;
  if (bid < 16384) {
    const int i = bid * 256 + tid;
    float4 f = ((const float4*)x)[i];
    ushort4 u;
    u.x = f2bf(f.x); u.y = f2bf(f.y); u.z = f2bf(f.z); u.w = f2bf(f.w);
    ((ushort4*)xb)[i] = u;
  } else if (bid < 17408) {
    const int rem = bid - 16384;
    const int z = rem >> 8, r2 = rem & 255;
    const int k0 = (r2 >> 4) * 64, n0 = (r2 & 15) * 64;
    const float* W = (z == 0) ? W0 : (z == 1) ? W1 : (z == 2) ? W2 : W3;
    u16* o = Wt + (size_t)z * 1048576ull;
    const int r = tid >> 4, c4 = (tid & 15) << 2;
    for (int rr = r; rr < 64; rr += 16) {
      float4 w4 = *(const float4*)(W + (size_t)(k0 + rr) * DM_ + n0 + c4);
      tt[c4 + 0][rr] = f2bf(w4.x);
      tt[c4 + 1][rr] = f2bf(w4.y);
      tt[c4 + 2][rr] = f2bf(w4.z);
      tt[c4 + 3][rr] = f2bf(w4.w);
    }
    __syncthreads();
    for (int rr = r; rr < 64; rr += 16) {
      ushort4 u4;
      u4.x = tt[rr][c4 + 0];
      u4.y = tt[rr][c4 + 1];
      u4.z = tt[rr][c4 + 2];
      u4.w = tt[rr][c4 + 3];
      *(ushort4*)(o + (size_t)(n0 + rr) * DM_ + k0 + c4) = u4;
    }
  } else {
    const int i = (bid - 17408) * 256 + tid;
    omb[i] = f2bf(om[i] * 0.35355339059327373f);     // fold 64^-0.25
  }
}

// ---------------- merged projection GEMMs (q,k,v), head bf16 out -----------
// nh' = 0.0625 * sum(bf2f(f2bf(v))^2) + ln16  (phi scale folded in)
__global__ __launch_bounds__(256) void mm3_k(
    const u16* __restrict__ A, const u16* __restrict__ Wt,
    const float* __restrict__ bq, const float* __restrict__ bk,
    const float* __restrict__ bv, u16* __restrict__ qb,
    u16* __restrict__ kb, u16* __restrict__ vb,
    float* __restrict__ nhq, float* __restrict__ nhk) {
  __shared__ u16 sA[128][64];   // 16 KB, XOR-swizzled 16B slots
  __shared__ u16 sB[128][64];   // 16 KB
  const int y = blockIdx.y;
  const u16* Bt = Wt + (size_t)y * 1048576ull;
  const float* bias = (y == 0) ? bq : (y == 1) ? bk : bv;
  u16* outp = (y == 0) ? qb : (y == 1) ? kb : vb;
  float* nhout = (y == 0) ? nhq : (y == 1) ? nhk : nullptr;
  const int tid = threadIdx.x, lane = tid & 63, w = tid >> 6;
  const int fr = lane & 15, fg = lane >> 4;
  const int wr = w >> 1, wc = w & 1;
  const int lb = ((blockIdx.x & 7) << 7) | (blockIdx.x >> 3);
  const int m0 = (lb >> 3) * 128, n0 = (lb & 7) * 128;
  const int srow = tid >> 3, sslot = tid & 7;   // +p*32 rows per pass
  f32x4 acc[4][4] = {};
  bf16x8 av[4], bv4[4];
#pragma unroll
  for (int p = 0; p < 4; ++p) {
    av[p]  = *(const bf16x8*)(A  + (size_t)(m0 + srow + p * 32) * DM_ + sslot * 8);
    bv4[p] = *(const bf16x8*)(Bt + (size_t)(n0 + srow + p * 32) * DM_ + sslot * 8);
  }
  for (int k0 = 0; k0 < DM_; k0 += 64) {
    __syncthreads();
#pragma unroll
    for (int p = 0; p < 4; ++p) {
      const int r = srow + p * 32;
      *(bf16x8*)&sA[r][(sslot ^ (r & 7)) * 8] = av[p];
      *(bf16x8*)&sB[r][(sslot ^ (r & 7)) * 8] = bv4[p];
    }
    if (k0 + 64 < DM_) {
#pragma unroll
      for (int p = 0; p < 4; ++p) {
        av[p]  = *(const bf16x8*)(A  + (size_t)(m0 + srow + p * 32) * DM_ + k0 + 64 + sslot * 8);
        bv4[p] = *(const bf16x8*)(Bt + (size_t)(n0 + srow + p * 32) * DM_ + k0 + 64 + sslot * 8);
      }
    }
    __syncthreads();
#pragma unroll
    for (int ks = 0; ks < 2; ++ks) {
      bf16x8 af[4], bf[4];
#pragma unroll
      for (int i = 0; i < 4; ++i) {
        const int r = wr * 64 + i * 16 + fr;
        af[i] = *(const bf16x8*)&sA[r][((ks * 4 + fg) ^ (r & 7)) * 8];
      }
#pragma unroll
      for (int j = 0; j < 4; ++j) {
        const int r = wc * 64 + j * 16 + fr;
        bf[j] = *(const bf16x8*)&sB[r][((ks * 4 + fg) ^ (r & 7)) * 8];
      }
#pragma unroll
      for (int i = 0; i < 4; ++i)
#pragma unroll
        for (int j = 0; j < 4; ++j)
          acc[i][j] = MFMA16(af[i], bf[j], acc[i][j]);
    }
  }
  const int m_blk = m0 + wr * 64, n_blk = n0 + wc * 64;
  float nhacc[4][4] = {};
#pragma unroll
  for (int j = 0; j < 4; ++j) {
    const int n = n_blk + j * 16 + fr;
    const float bi = bias[n];
    const int h = n >> 6, d = n & 63;
#pragma unroll
    for (int i = 0; i < 4; ++i) {
#pragma unroll
      for (int r = 0; r < 4; ++r) {
        const int m = m_blk + i * 16 + fg * 4 + r;
        const float val = acc[i][j][r] + bi;
        const int b = m >> 12, l = m & 4095;
        const u16 sv = f2bf(val);
        outp[((size_t)(b * H_ + h) * L_ + l) * D_ + d] = sv;
        const float rv = bf2f(sv);
        nhacc[i][r] += rv * rv;
      }
    }
  }
  if (nhout) {
    const int hh2 = n_blk >> 6;
#pragma unroll
    for (int i = 0; i < 4; ++i)
#pragma unroll
      for (int r = 0; r < 4; ++r) {
        float s = nhacc[i][r];
        s += __shfl_xor(s, 1, 64);
        s += __shfl_xor(s, 2, 64);
        s += __shfl_xor(s, 4, 64);
        s += __shfl_xor(s, 8, 64);
        if (fr == 0) {
          const int m = m_blk + i * 16 + fg * 4 + r;
          const int b = m >> 12, l = m & 4095;
          nhout[(size_t)(b * H_ + hh2) * L_ + l] = 0.0625f * s + LN16;
        }
      }
  }
}

// ---------------- final GEMM (attn bf16 -> f32 out), validated -------------
__global__ __launch_bounds__(256) void mmo_k(
    const u16* __restrict__ A, const u16* __restrict__ Bt,
    const float* __restrict__ bias, float* __restrict__ outp) {
  __shared__ u16 sA[128][64];
  __shared__ u16 sB[128][64];
  const int tid = threadIdx.x, lane = tid & 63, w = tid >> 6;
  const int fr = lane & 15, fg = lane >> 4;
  const int wr = w >> 1, wc = w & 1;
  const int lb = ((blockIdx.x & 7) << 7) | (blockIdx.x >> 3);
  const int m0 = (lb >> 3) * 128, n0 = (lb & 7) * 128;
  const int srow = tid >> 3, sslot = tid & 7;
  f32x4 acc[4][4] = {};
  bf16x8 av[4], bv[4];
#pragma unroll
  for (int p = 0; p < 4; ++p) {
    av[p] = *(const bf16x8*)(A  + (size_t)(m0 + srow + p * 32) * DM_ + sslot * 8);
    bv[p] = *(const bf16x8*)(Bt + (size_t)(n0 + srow + p * 32) * DM_ + sslot * 8);
  }
  for (int k0 = 0; k0 < DM_; k0 += 64) {
    __syncthreads();
#pragma unroll
    for (int p = 0; p < 4; ++p) {
      const int r = srow + p * 32;
      *(bf16x8*)&sA[r][(sslot ^ (r & 7)) * 8] = av[p];
      *(bf16x8*)&sB[r][(sslot ^ (r & 7)) * 8] = bv[p];
    }
    if (k0 + 64 < DM_) {
#pragma unroll
      for (int p = 0; p < 4; ++p) {
        av[p] = *(const bf16x8*)(A  + (size_t)(m0 + srow + p * 32) * DM_ + k0 + 64 + sslot * 8);
        bv[p] = *(const bf16x8*)(Bt + (size_t)(n0 + srow + p * 32) * DM_ + k0 + 64 + sslot * 8);
      }
    }
    __syncthreads();
#pragma unroll
    for (int ks = 0; ks < 2; ++ks) {
      bf16x8 af[4], bf[4];
#pragma unroll
      for (int i = 0; i < 4; ++i) {
        const int r = wr * 64 + i * 16 + fr;
        af[i] = *(const bf16x8*)&sA[r][((ks * 4 + fg) ^ (r & 7)) * 8];
      }
#pragma unroll
      for (int j = 0; j < 4; ++j) {
        const int r = wc * 64 + j * 16 + fr;
        bf[j] = *(const bf16x8*)&sB[r][((ks * 4 + fg) ^ (r & 7)) * 8];
      }
#pragma unroll
      for (int i = 0; i < 4; ++i)
#pragma unroll
        for (int j = 0; j < 4; ++j)
          acc[i][j] = MFMA16(af[i], bf[j], acc[i][j]);
    }
  }
  const int m_blk = m0 + wr * 64, n_blk = n0 + wc * 64;
#pragma unroll
  for (int j = 0; j < 4; ++j) {
    const int n = n_blk + j * 16 + fr;
    const float bi = bias[n];
#pragma unroll
    for (int i = 0; i < 4; ++i)
#pragma unroll
      for (int r = 0; r < 4; ++r) {
        const int m = m_blk + i * 16 + fg * 4 + r;
        outp[(size_t)m * DM_ + n] = acc[i][j][r] + bi;
      }
  }
}

// ---------------- kvstate (MFMA, SC=128): bf16 state + f32 ksum ------------
__global__ __launch_bounds__(256) void kvstate_k(
    const u16* __restrict__ k, const u16* __restrict__ v,
    const u16* __restrict__ omb, const float* __restrict__ nhk,
    u16* __restrict__ stateb, float* __restrict__ ksum) {
  __shared__ u16 sPhi[256][72];
  __shared__ u16 sVt[64][72];
  const int tid = threadIdx.x, lane = tid & 63, w = tid >> 6;
  const int fr = lane & 15, fg = lane >> 4;
  const int sc = blockIdx.x, bh = blockIdx.y;
  const size_t base_l = (size_t)bh * L_ + (size_t)sc * 128;

  bf16x8 ones;
#pragma unroll
  for (int e = 0; e < 8; ++e) ones[e] = (short)0x3F80;

  f32x4 kvacc[4][4] = {};
  f32x4 ksacc[4] = {};

  for (int sub = 0; sub < 2; ++sub) {
    const size_t tl = base_l + sub * 64;
    const u16* kg = k + tl * 64;
    __syncthreads();
    {
      const u16* vp = v + (tl + lane) * 64 + w * 16;
      bf16x8 v0 = *(const bf16x8*)(vp);
      bf16x8 v1 = *(const bf16x8*)(vp + 8);
#pragma unroll
      for (int e = 0; e < 8; ++e) sVt[w * 16 + e][lane] = (u16)v0[e];
#pragma unroll
      for (int e = 0; e < 8; ++e) sVt[w * 16 + 8 + e][lane] = (u16)v1[e];
    }
    float nhr[4];
#pragma unroll
    for (int tt = 0; tt < 4; ++tt) nhr[tt] = nhk[tl + tt * 16 + fr];
#pragma unroll
    for (int mi = 0; mi < 4; ++mi) {
      const int m0 = (w << 6) + mi * 16;
      const bf16x8 a0 = *(const bf16x8*)(omb + (m0 + fr) * 64 + fg * 8);
      const bf16x8 a1 = *(const bf16x8*)(omb + (m0 + fr) * 64 + 32 + fg * 8);
#pragma unroll
      for (int tt = 0; tt < 4; ++tt) {
        const bf16x8 b0 = *(const bf16x8*)(kg + (tt * 16 + fr) * 64 + fg * 8);
        const bf16x8 b1 = *(const bf16x8*)(kg + (tt * 16 + fr) * 64 + 32 + fg * 8);
        f32x4 acc = {0.f, 0.f, 0.f, 0.f};
        acc = MFMA16(a0, b0, acc);
        acc = MFMA16(a1, b1, acc);
        const float nhv = nhr[tt];
#pragma unroll
        for (int r = 0; r < 4; ++r)
          sPhi[m0 + fg * 4 + r][tt * 16 + fr] = f2bf(__expf(acc[r] - nhv));
      }
    }
    __syncthreads();
#pragma unroll
    for (int mi = 0; mi < 4; ++mi) {
      const int m0 = (w << 6) + mi * 16;
      const bf16x8 pb0 = *(const bf16x8*)&sPhi[m0 + fr][fg * 8];
      const bf16x8 pb1 = *(const bf16x8*)&sPhi[m0 + fr][32 + fg * 8];
      ksacc[mi] = MFMA16(pb0, ones, ksacc[mi]);
      ksacc[mi] = MFMA16(pb1, ones, ksacc[mi]);
#pragma unroll
      for (int dj = 0; dj < 4; ++dj) {
        const bf16x8 va0 = *(const bf16x8*)&sVt[dj * 16 + fr][fg * 8];
        const bf16x8 va1 = *(const bf16x8*)&sVt[dj * 16 + fr][32 + fg * 8];
        kvacc[mi][dj] = MFMA16(va0, pb0, kvacc[mi][dj]);
        kvacc[mi][dj] = MFMA16(va1, pb1, kvacc[mi][dj]);
      }
    }
  }
  // state bf16 [d][m]; ksum f32
  u16* stb = stateb + (size_t)(bh * NSC + sc) * (M_ * D_);
  float* ksp = ksum + (size_t)(bh * NSC + sc) * M_;
#pragma unroll
  for (int mi = 0; mi < 4; ++mi) {
    const int m = (w << 6) + mi * 16 + fr;
#pragma unroll
    for (int dj = 0; dj < 4; ++dj)
#pragma unroll
      for (int r = 0; r < 4; ++r)
        stb[(size_t)(dj * 16 + fg * 4 + r) * M_ + m] = f2bf(kvacc[mi][dj][r]);
    if (fr == 0) {
#pragma unroll
      for (int r = 0; r < 4; ++r)
        ksp[(w << 6) + mi * 16 + fg * 4 + r] = ksacc[mi][r];
    }
  }
}

// ---------------- exclusive prefix over superchunks (bf16 state) -----------
__global__ __launch_bounds__(256) void scan_k(u16* __restrict__ stateb,
                                              float* __restrict__ ksum) {
  const int bh = blockIdx.y;
  u16* sb = stateb + (size_t)bh * NSC * (M_ * D_);
  const int base = blockIdx.x * 2048 + threadIdx.x * 8;
  float run[8] = {};
  for (int cc = 0; cc < NSC; ++cc) {
    u16* st = sb + (size_t)cc * (M_ * D_) + base;
    ushort4 t0 = *(ushort4*)st;
    ushort4 t1 = *(ushort4*)(st + 4);
    ushort4 w0, w1;
    w0.x = f2bf(run[0]); w0.y = f2bf(run[1]); w0.z = f2bf(run[2]); w0.w = f2bf(run[3]);
    w1.x = f2bf(run[4]); w1.y = f2bf(run[5]); w1.z = f2bf(run[6]); w1.w = f2bf(run[7]);
    *(ushort4*)st = w0;
    *(ushort4*)(st + 4) = w1;
    run[0] += bf2f(t0.x); run[1] += bf2f(t0.y); run[2] += bf2f(t0.z); run[3] += bf2f(t0.w);
    run[4] += bf2f(t1.x); run[5] += bf2f(t1.y); run[6] += bf2f(t1.z); run[7] += bf2f(t1.w);
  }
  if (blockIdx.x == 0) {           // ksum f32 in-place exclusive prefix
    float rk = 0.f;
    for (int cc = 0; cc < NSC; ++cc) {
      float* p = ksum + (size_t)(bh * NSC + cc) * M_ + threadIdx.x;
      const float t = *p;
      *p = rk;
      rk += t;
    }
  }
}

// ---------------- outchunk helpers -----------------------------------------
// phi quadrant: writes ONLY rows of band wb (wb*16..wb*16+15); nh has ln16
static __device__ __forceinline__ void phi_quad(
    const u16* __restrict__ xg, const u16* __restrict__ ombq,
    u16* __restrict__ dst, int dstride, const float* nhv,
    int wb, int lane) {
  const int fr = lane & 15, fg = lane >> 4;
  const int tband = wb * 16;
  const bf16x8 a0 = *(const bf16x8*)(xg + (tband + fr) * 64 + fg * 8);
  const bf16x8 a1 = *(const bf16x8*)(xg + (tband + fr) * 64 + 32 + fg * 8);
#pragma unroll
  for (int j = 0; j < 4; ++j) {
    const bf16x8 b0 = *(const bf16x8*)(ombq + (j * 16 + fr) * 64 + fg * 8);
    const bf16x8 b1 = *(const bf16x8*)(ombq + (j * 16 + fr) * 64 + 32 + fg * 8);
    f32x4 acc = {0.f, 0.f, 0.f, 0.f};
    acc = MFMA16(a0, b0, acc);
    acc = MFMA16(a1, b1, acc);
#pragma unroll
    for (int r = 0; r < 4; ++r) {
      const int t = tband + fg * 4 + r;
      dst[t * dstride + j * 16 + fr] = f2bf(__expf(acc[r] - nhv[r]));
    }
  }
}

// ---------------- outchunk: 4 superchunks/block ----------------------------
__global__ __launch_bounds__(512, 2) void outchunk_k(
    const u16* __restrict__ q, const u16* __restrict__ kk,
    const u16* __restrict__ v, const u16* __restrict__ omb,
    const u16* __restrict__ stateb, const float* __restrict__ ksum,
    const float* __restrict__ nhq, const float* __restrict__ nhk,
    u16* __restrict__ attn) {
  __shared__ u16 sKa[64][264];    // Kp chunk0 (h0-produced)
  __shared__ u16 sKb[64][264];    // Kp chunk1 (h1-produced)
  __shared__ u16 sS0[64][72];     // h0 q-scratch / h0 masked S
  __shared__ u16 sS1[64][72];     // h1 q-scratch / h1 masked S
  __shared__ u16 sB1[64][72];     // vT chunk0 (h0-staged)
  __shared__ u16 sB2[64][72];     // vT chunk1 (h1-staged)
  __shared__ float ksum_l[256];   // total 105,472 B -> 1 block/CU
  const int tid = threadIdx.x, lane = tid & 63, w = tid >> 6;
  const int h = w >> 2, wl = w & 3;
  const int fr = lane & 15, fg = lane >> 4;
  const int bh = blockIdx.x >> 3, scp = blockIdx.x & 7;

#pragma unroll 1
  for (int it = 0; it < 4; ++it) {
    const int sc = scp * 4 + it;
    const size_t base_l = (size_t)bh * L_ + (size_t)sc * 128;
    const size_t tokq = base_l + (size_t)h * 64;
    const u16* qg = q + tokq * 64;
    const u16* stgb = stateb + (size_t)(bh * NSC + sc) * (M_ * D_);  // [d][m]
    const float* ksg = ksum + (size_t)(bh * NSC + sc) * M_;

    if (tid < 256) ksum_l[tid] = ksg[tid];

    // early v loads: half h loads its own chunk's v
    bf16x8 ev0, ev1;
    {
      const u16* vp = v + (base_l + (size_t)h * 64 + lane) * 64 + wl * 16;
      ev0 = *(const bf16x8*)(vp);
      ev1 = *(const bf16x8*)(vp + 8);
    }

    // phi(k): half h fills its chunk's Kp entirely (own rows, no syncs)
    u16* kdst = (h == 0) ? &sKa[0][0] : &sKb[0][0];
    {
      const size_t ktokh = base_l + (size_t)h * 64;
      const u16* kgh = kk + ktokh * 64;
      float nhkh[4];
#pragma unroll
      for (int r = 0; r < 4; ++r) nhkh[r] = nhk[ktokh + wl * 16 + fg * 4 + r];
#pragma unroll
      for (int mq = 0; mq < 4; ++mq)
        phi_quad(kgh, omb + mq * 4096, kdst + mq * 64, 264, nhkh, wl, lane);
    }

    // phi(q) -> regs via own half's S buffer as scratch (wave-private rows);
    // cross term fused (state B-frag latency hides under phi(k) compute).
    float nhq4[4];
#pragma unroll
    for (int r = 0; r < 4; ++r) nhq4[r] = nhq[tokq + wl * 16 + fg * 4 + r];
    u16* myscr = (h == 0) ? &sS0[0][0] : &sS1[0][0];
    bf16x8 qa0[2], qa1[2], qa2[2], qa3[2];
    f32x4 oacc[4] = {};
#define QPHASE(MQ, QA)                                                          \
    {                                                                           \
      bf16x8 b0r[4], b1r[4];                                                    \
      _Pragma("unroll")                                                         \
      for (int j = 0; j < 4; ++j) {                                             \
        b0r[j] = *(const bf16x8*)(stgb + (size_t)(j * 16 + fr) * M_ + MQ * 64 + fg * 8);      \
        b1r[j] = *(const bf16x8*)(stgb + (size_t)(j * 16 + fr) * M_ + MQ * 64 + 32 + fg * 8); \
      }                                                                         \
      phi_quad(qg, omb + MQ * 4096, myscr, 72, nhq4, wl, lane);                 \
      QA[0] = *(const bf16x8*)(myscr + (wl * 16 + fr) * 72 + fg * 8);           \
      QA[1] = *(const bf16x8*)(myscr + (wl * 16 + fr) * 72 + 32 + fg * 8);      \
      __builtin_amdgcn_s_setprio(1);                                            \
      _Pragma("unroll")                                                         \
      for (int j = 0; j < 4; ++j) {                                             \
        oacc[j] = MFMA16(QA[0], b0r[j], oacc[j]);                               \
        oacc[j] = MFMA16(QA[1], b1r[j], oacc[j]);                               \
      }                                                                         \
      __builtin_amdgcn_s_setprio(0);                                            \
    }
    QPHASE(0, qa0)
    QPHASE(1, qa1)
    QPHASE(2, qa2)
    QPHASE(3, qa3)
#undef QPHASE
    __syncthreads();   // BAR K: ksum_l + full Kp (sKa/sKb) visible to all

    // den-ksum from register frags
    float denk = 0.f;
#pragma unroll
    for (int e = 0; e < 8; ++e) {
      denk += bf2f((u16)qa0[0][e]) * ksum_l[0   + fg * 8 + e]
            + bf2f((u16)qa0[1][e]) * ksum_l[32  + fg * 8 + e]
            + bf2f((u16)qa1[0][e]) * ksum_l[64  + fg * 8 + e]
            + bf2f((u16)qa1[1][e]) * ksum_l[96  + fg * 8 + e]
            + bf2f((u16)qa2[0][e]) * ksum_l[128 + fg * 8 + e]
            + bf2f((u16)qa2[1][e]) * ksum_l[160 + fg * 8 + e]
            + bf2f((u16)qa3[0][e]) * ksum_l[192 + fg * 8 + e]
            + bf2f((u16)qa3[1][e]) * ksum_l[224 + fg * 8 + e];
    }
    denk += __shfl_xor(denk, 16, 64);
    denk += __shfl_xor(denk, 32, 64);

    // ---- S chunk0 (all waves): 32 MFMA, B-frags from sKa
    float dS[4] = {0.f, 0.f, 0.f, 0.f};
    {
      f32x4 sacc[4] = {};
      __builtin_amdgcn_s_setprio(1);
#define SPH0(MQ, QA)                                                            \
      _Pragma("unroll")                                                         \
      for (int j = 0; j < 4; ++j) {                                             \
        const bf16x8 b0 = *(const bf16x8*)&sKa[j * 16 + fr][MQ * 64 + fg * 8];  \
        const bf16x8 b1 = *(const bf16x8*)&sKa[j * 16 + fr][MQ * 64 + 32 + fg * 8]; \
        sacc[j] = MFMA16(QA[0], b0, sacc[j]);                                   \
        sacc[j] = MFMA16(QA[1], b1, sacc[j]);                                   \
      }
      SPH0(0, qa0)
      SPH0(1, qa1)
      SPH0(2, qa2)
      SPH0(3, qa3)
#undef SPH0
      __builtin_amdgcn_s_setprio(0);
      u16 (*sSo)[72] = (h == 0) ? sS0 : sS1;
#pragma unroll
      for (int j = 0; j < 4; ++j)
#pragma unroll
        for (int r = 0; r < 4; ++r) {
          const int ss = j * 16 + fr, t = wl * 16 + fg * 4 + r;
          float val = sacc[j][r];
          if (h == 0 && ss > t) val = 0.f;
          const u16 vb = f2bf(val);
          sSo[t][ss] = vb;
          dS[r] += bf2f(vb);
        }
    }
    // vT staging: h0 -> sB1 (chunk0), h1 -> sB2 (chunk1)
    {
      u16 (*sBo)[72] = (h == 0) ? sB1 : sB2;
#pragma unroll
      for (int e = 0; e < 8; ++e) sBo[wl * 16 + e][lane] = (u16)ev0[e];
#pragma unroll
      for (int e = 0; e < 8; ++e) sBo[wl * 16 + 8 + e][lane] = (u16)ev1[e];
    }
    __syncthreads();   // BAR F0: sS0/sS1 + sB1/sB2 visible

    // ---- S@V chunk0 (all waves): A = own masked S (own band), B = sB1
    {
      const u16 (*sSo)[72] = (h == 0) ? sS0 : sS1;
      const bf16x8 a0 = *(const bf16x8*)&sSo[wl * 16 + fr][fg * 8];
      const bf16x8 a1 = *(const bf16x8*)&sSo[wl * 16 + fr][32 + fg * 8];
      __builtin_amdgcn_s_setprio(1);
#pragma unroll
      for (int j = 0; j < 4; ++j) {
        const bf16x8 b0 = *(const bf16x8*)&sB1[j * 16 + fr][fg * 8];
        const bf16x8 b1 = *(const bf16x8*)&sB1[j * 16 + fr][32 + fg * 8];
        oacc[j] = MFMA16(a0, b0, oacc[j]);
        oacc[j] = MFMA16(a1, b1, oacc[j]);
      }
      __builtin_amdgcn_s_setprio(0);
    }

    // ---- h1 only: S chunk1 (sKb) -> masked sS1 -> S@V chunk1 (sB2)
    if (h == 1) {
      f32x4 sacc[4] = {};
      __builtin_amdgcn_s_setprio(1);
#define SPH1(MQ, QA)                                                            \
      _Pragma("unroll")                                                         \
      for (int j = 0; j < 4; ++j) {                                             \
        const bf16x8 b0 = *(const bf16x8*)&sKb[j * 16 + fr][MQ * 64 + fg * 8];  \
        const bf16x8 b1 = *(const bf16x8*)&sKb[j * 16 + fr][MQ * 64 + 32 + fg * 8]; \
        sacc[j] = MFMA16(QA[0], b0, sacc[j]);                                   \
        sacc[j] = MFMA16(QA[1], b1, sacc[j]);                                   \
      }
      SPH1(0, qa0)
      SPH1(1, qa1)
      SPH1(2, qa2)
      SPH1(3, qa3)
#undef SPH1
      __builtin_amdgcn_s_setprio(0);
#pragma unroll
      for (int j = 0; j < 4; ++j)
#pragma unroll
        for (int r = 0; r < 4; ++r) {
          const int ss = j * 16 + fr, t = wl * 16 + fg * 4 + r;
          float val = sacc[j][r];
          if (ss > t) val = 0.f;         // diag (s == h == 1)
          const u16 vb = f2bf(val);
          sS1[t][ss] = vb;
          dS[r] += bf2f(vb);
        }
      {
        const bf16x8 a0 = *(const bf16x8*)&sS1[wl * 16 + fr][fg * 8];
        const bf16x8 a1 = *(const bf16x8*)&sS1[wl * 16 + fr][32 + fg * 8];
        __builtin_amdgcn_s_setprio(1);
#pragma unroll
        for (int j = 0; j < 4; ++j) {
          const bf16x8 b0 = *(const bf16x8*)&sB2[j * 16 + fr][fg * 8];
          const bf16x8 b1 = *(const bf16x8*)&sB2[j * 16 + fr][32 + fg * 8];
          oacc[j] = MFMA16(a0, b0, oacc[j]);
          oacc[j] = MFMA16(a1, b1, oacc[j]);
        }
        __builtin_amdgcn_s_setprio(0);
      }
    }

    // den: reduce dS over fr lanes; combine with denk via shfl
#pragma unroll
    for (int m2 = 1; m2 <= 8; m2 <<= 1) {
#pragma unroll
      for (int r = 0; r < 4; ++r) dS[r] += __shfl_xor(dS[r], m2, 64);
    }
    const int b = bh >> 4, hh = bh & 15;
#pragma unroll
    for (int r = 0; r < 4; ++r) {
      const float dk = __shfl(denk, fg * 4 + r, 64);   // token wl*16+fg*4+r
      const float rinv = 1.0f / (dk + dS[r] + 1e-6f);
      const int t = wl * 16 + fg * 4 + r;
      const int l = sc * 128 + h * 64 + t;
#pragma unroll
      for (int j = 0; j < 4; ++j) {
        const int d = j * 16 + fr;
        attn[((size_t)b * L_ + l) * DM_ + hh * 64 + d] = f2bf(oacc[j][r] * rinv);
      }
    }
    __syncthreads();   // BAR E: full fence before next superchunk's reuse
  }
}

extern "C" void kernel_launch(void* const* d_in, const int* in_sizes, int n_in,
                              void* d_out, int out_size, void* d_ws, size_t ws_size,
                              hipStream_t stream) {
  const float* x     = (const float*)d_in[0];
  const float* Wq    = (const float*)d_in[1];
  const float* bq    = (const float*)d_in[2];
  const float* Wk    = (const float*)d_in[3];
  const float* bk    = (const float*)d_in[4];
  const float* Wv    = (const float*)d_in[5];
  const float* bv    = (const float*)d_in[6];
  const float* Wo    = (const float*)d_in[7];
  const float* bo    = (const float*)d_in[8];
  const float* omega = (const float*)d_in[9];
  float* out = (float*)d_out;

  char* ws = (char*)d_ws;
  u16*   v      = (u16*)(ws);                           // 32 MB
  u16*   qb     = (u16*)(ws + 33554432ull);             // 32 MB
  u16*   kb     = (u16*)(ws + 67108864ull);             // 32 MB
  u16*   xb     = (u16*)(ws + 100663296ull);            // 32 MB (alias attn)
  u16*   attn   = xb;
  u16*   stateb = (u16*)(ws + 134217728ull);            // 64 MB
  float* ksum   = (float*)(ws + 201326592ull);          // 2 MB
  u16*   Wt     = (u16*)(ws + 203423744ull);            // 8 MB
  u16*   omb    = (u16*)(ws + 211812352ull);            // 32 KB
  float* nhq    = (float*)(ws + 211845120ull);          // 1 MB
  float* nhk    = (float*)(ws + 212893696ull);          // 1 MB -> 204 MB

  prep_k<<<17472, 256, 0, stream>>>(x, xb, Wq, Wk, Wv, Wo, Wt, omega, omb);
  mm3_k<<<dim3(1024, 3), 256, 0, stream>>>(xb, Wt, bq, bk, bv,
                                           qb, kb, v, nhq, nhk);
  kvstate_k<<<dim3(NSC, BH_), 256, 0, stream>>>(kb, v, omb, nhk, stateb, ksum);
  scan_k<<<dim3(8, BH_), 256, 0, stream>>>(stateb, ksum);
  outchunk_k<<<BH_ * (NSC / 4), 512, 0, stream>>>(qb, kb, v, omb, stateb, ksum,
                                                  nhq, nhk, attn);
  mmo_k<<<1024, 256, 0, stream>>>(attn, Wt + 3145728ull, bo, out);
}

// Round 22
// 437.031 us; speedup vs baseline: 1.2967x; 1.0141x over previous
//
#include <hip/hip_runtime.h>
#include <hip/hip_bf16.h>

// FAVOR+ attention, MI355X. Round 22:
//  - outchunk: EIGHT superchunks per block (grid 256 = exactly 1 block/CU,
//    single round; it=0..7). All per-CU round transitions internalized.
//  - prep_k / mm3_k / mmo_k / kvstate_k / scan_k: byte-identical to R21.
//
// Workspace (bytes), total 213,942,272 (~204 MB): layout as R17-R21.

#define B_ 4
#define H_ 16
#define L_ 4096
#define D_ 64
#define M_ 256
#define DM_ 1024
#define BH_ 64
#define NSC 32            // superchunks per bh (SC = 128 tokens)

typedef unsigned int u32;
typedef unsigned short u16;
typedef __attribute__((ext_vector_type(8))) short bf16x8;
typedef __attribute__((ext_vector_type(4))) float f32x4;

static __device__ __forceinline__ float bf2f(u16 u) {
  return __uint_as_float(((u32)u) << 16);
}
static __device__ __forceinline__ u16 f2bf(float f) {
  u32 x = __float_as_uint(f);
  return (u16)((x + 0x7fffu + ((x >> 16) & 1u)) >> 16);   // RNE
}
#define MFMA16(a, b, c) __builtin_amdgcn_mfma_f32_16x16x32_bf16((a), (b), (c), 0, 0, 0)
#define LN16 2.772588722239781f

// ---------------- merged prep: convx | convw | convom ----------------------
__global__ __launch_bounds__(256) void prep_k(
    const float* __restrict__ x, u16* __restrict__ xb,
    const float* __restrict__ W0, const float* __restrict__ W1,
    const float* __restrict__ W2, const float* __restrict__ W3,
    u16* __restrict__ Wt, const float* __restrict__ om,
    u16* __restrict__ omb) {
  __shared__ u16 tt[64][66];
  const int bid = blockIdx.x, tid = threadIdx.x;
  if (bid < 16384) {
    const int i = bid * 256 + tid;
    float4 f = ((const float4*)x)[i];
    ushort4 u;
    u.x = f2bf(f.x); u.y = f2bf(f.y); u.z = f2bf(f.z); u.w = f2bf(f.w);
    ((ushort4*)xb)[i] = u;
  } else if (bid < 17408) {
    const int rem = bid - 16384;
    const int z = rem >> 8, r2 = rem & 255;
    const int k0 = (r2 >> 4) * 64, n0 = (r2 & 15) * 64;
    const float* W = (z == 0) ? W0 : (z == 1) ? W1 : (z == 2) ? W2 : W3;
    u16* o = Wt + (size_t)z * 1048576ull;
    const int r = tid >> 4, c4 = (tid & 15) << 2;
    for (int rr = r; rr < 64; rr += 16) {
      float4 w4 = *(const float4*)(W + (size_t)(k0 + rr) * DM_ + n0 + c4);
      tt[c4 + 0][rr] = f2bf(w4.x);
      tt[c4 + 1][rr] = f2bf(w4.y);
      tt[c4 + 2][rr] = f2bf(w4.z);
      tt[c4 + 3][rr] = f2bf(w4.w);
    }
    __syncthreads();
    for (int rr = r; rr < 64; rr += 16) {
      ushort4 u4;
      u4.x = tt[rr][c4 + 0];
      u4.y = tt[rr][c4 + 1];
      u4.z = tt[rr][c4 + 2];
      u4.w = tt[rr][c4 + 3];
      *(ushort4*)(o + (size_t)(n0 + rr) * DM_ + k0 + c4) = u4;
    }
  } else {
    const int i = (bid - 17408) * 256 + tid;
    omb[i] = f2bf(om[i] * 0.35355339059327373f);     // fold 64^-0.25
  }
}

// ---------------- merged projection GEMMs (q,k,v), head bf16 out -----------
// nh' = 0.0625 * sum(bf2f(f2bf(v))^2) + ln16  (phi scale folded in)
__global__ __launch_bounds__(256) void mm3_k(
    const u16* __restrict__ A, const u16* __restrict__ Wt,
    const float* __restrict__ bq, const float* __restrict__ bk,
    const float* __restrict__ bv, u16* __restrict__ qb,
    u16* __restrict__ kb, u16* __restrict__ vb,
    float* __restrict__ nhq, float* __restrict__ nhk) {
  __shared__ u16 sA[128][64];   // 16 KB, XOR-swizzled 16B slots
  __shared__ u16 sB[128][64];   // 16 KB
  const int y = blockIdx.y;
  const u16* Bt = Wt + (size_t)y * 1048576ull;
  const float* bias = (y == 0) ? bq : (y == 1) ? bk : bv;
  u16* outp = (y == 0) ? qb : (y == 1) ? kb : vb;
  float* nhout = (y == 0) ? nhq : (y == 1) ? nhk : nullptr;
  const int tid = threadIdx.x, lane = tid & 63, w = tid >> 6;
  const int fr = lane & 15, fg = lane >> 4;
  const int wr = w >> 1, wc = w & 1;
  const int lb = ((blockIdx.x & 7) << 7) | (blockIdx.x >> 3);
  const int m0 = (lb >> 3) * 128, n0 = (lb & 7) * 128;
  const int srow = tid >> 3, sslot = tid & 7;   // +p*32 rows per pass
  f32x4 acc[4][4] = {};
  bf16x8 av[4], bv4[4];
#pragma unroll
  for (int p = 0; p < 4; ++p) {
    av[p]  = *(const bf16x8*)(A  + (size_t)(m0 + srow + p * 32) * DM_ + sslot * 8);
    bv4[p] = *(const bf16x8*)(Bt + (size_t)(n0 + srow + p * 32) * DM_ + sslot * 8);
  }
  for (int k0 = 0; k0 < DM_; k0 += 64) {
    __syncthreads();
#pragma unroll
    for (int p = 0; p < 4; ++p) {
      const int r = srow + p * 32;
      *(bf16x8*)&sA[r][(sslot ^ (r & 7)) * 8] = av[p];
      *(bf16x8*)&sB[r][(sslot ^ (r & 7)) * 8] = bv4[p];
    }
    if (k0 + 64 < DM_) {
#pragma unroll
      for (int p = 0; p < 4; ++p) {
        av[p]  = *(const bf16x8*)(A  + (size_t)(m0 + srow + p * 32) * DM_ + k0 + 64 + sslot * 8);
        bv4[p] = *(const bf16x8*)(Bt + (size_t)(n0 + srow + p * 32) * DM_ + k0 + 64 + sslot * 8);
      }
    }
    __syncthreads();
#pragma unroll
    for (int ks = 0; ks < 2; ++ks) {
      bf16x8 af[4], bf[4];
#pragma unroll
      for (int i = 0; i < 4; ++i) {
        const int r = wr * 64 + i * 16 + fr;
        af[i] = *(const bf16x8*)&sA[r][((ks * 4 + fg) ^ (r & 7)) * 8];
      }
#pragma unroll
      for (int j = 0; j < 4; ++j) {
        const int r = wc * 64 + j * 16 + fr;
        bf[j] = *(const bf16x8*)&sB[r][((ks * 4 + fg) ^ (r & 7)) * 8];
      }
#pragma unroll
      for (int i = 0; i < 4; ++i)
#pragma unroll
        for (int j = 0; j < 4; ++j)
          acc[i][j] = MFMA16(af[i], bf[j], acc[i][j]);
    }
  }
  const int m_blk = m0 + wr * 64, n_blk = n0 + wc * 64;
  float nhacc[4][4] = {};
#pragma unroll
  for (int j = 0; j < 4; ++j) {
    const int n = n_blk + j * 16 + fr;
    const float bi = bias[n];
    const int h = n >> 6, d = n & 63;
#pragma unroll
    for (int i = 0; i < 4; ++i) {
#pragma unroll
      for (int r = 0; r < 4; ++r) {
        const int m = m_blk + i * 16 + fg * 4 + r;
        const float val = acc[i][j][r] + bi;
        const int b = m >> 12, l = m & 4095;
        const u16 sv = f2bf(val);
        outp[((size_t)(b * H_ + h) * L_ + l) * D_ + d] = sv;
        const float rv = bf2f(sv);
        nhacc[i][r] += rv * rv;
      }
    }
  }
  if (nhout) {
    const int hh2 = n_blk >> 6;
#pragma unroll
    for (int i = 0; i < 4; ++i)
#pragma unroll
      for (int r = 0; r < 4; ++r) {
        float s = nhacc[i][r];
        s += __shfl_xor(s, 1, 64);
        s += __shfl_xor(s, 2, 64);
        s += __shfl_xor(s, 4, 64);
        s += __shfl_xor(s, 8, 64);
        if (fr == 0) {
          const int m = m_blk + i * 16 + fg * 4 + r;
          const int b = m >> 12, l = m & 4095;
          nhout[(size_t)(b * H_ + hh2) * L_ + l] = 0.0625f * s + LN16;
        }
      }
  }
}

// ---------------- final GEMM (attn bf16 -> f32 out), validated -------------
__global__ __launch_bounds__(256) void mmo_k(
    const u16* __restrict__ A, const u16* __restrict__ Bt,
    const float* __restrict__ bias, float* __restrict__ outp) {
  __shared__ u16 sA[128][64];
  __shared__ u16 sB[128][64];
  const int tid = threadIdx.x, lane = tid & 63, w = tid >> 6;
  const int fr = lane & 15, fg = lane >> 4;
  const int wr = w >> 1, wc = w & 1;
  const int lb = ((blockIdx.x & 7) << 7) | (blockIdx.x >> 3);
  const int m0 = (lb >> 3) * 128, n0 = (lb & 7) * 128;
  const int srow = tid >> 3, sslot = tid & 7;
  f32x4 acc[4][4] = {};
  bf16x8 av[4], bv[4];
#pragma unroll
  for (int p = 0; p < 4; ++p) {
    av[p] = *(const bf16x8*)(A  + (size_t)(m0 + srow + p * 32) * DM_ + sslot * 8);
    bv[p] = *(const bf16x8*)(Bt + (size_t)(n0 + srow + p * 32) * DM_ + sslot * 8);
  }
  for (int k0 = 0; k0 < DM_; k0 += 64) {
    __syncthreads();
#pragma unroll
    for (int p = 0; p < 4; ++p) {
      const int r = srow + p * 32;
      *(bf16x8*)&sA[r][(sslot ^ (r & 7)) * 8] = av[p];
      *(bf16x8*)&sB[r][(sslot ^ (r & 7)) * 8] = bv[p];
    }
    if (k0 + 64 < DM_) {
#pragma unroll
      for (int p = 0; p < 4; ++p) {
        av[p] = *(const bf16x8*)(A  + (size_t)(m0 + srow + p * 32) * DM_ + k0 + 64 + sslot * 8);
        bv[p] = *(const bf16x8*)(Bt + (size_t)(n0 + srow + p * 32) * DM_ + k0 + 64 + sslot * 8);
      }
    }
    __syncthreads();
#pragma unroll
    for (int ks = 0; ks < 2; ++ks) {
      bf16x8 af[4], bf[4];
#pragma unroll
      for (int i = 0; i < 4; ++i) {
        const int r = wr * 64 + i * 16 + fr;
        af[i] = *(const bf16x8*)&sA[r][((ks * 4 + fg) ^ (r & 7)) * 8];
      }
#pragma unroll
      for (int j = 0; j < 4; ++j) {
        const int r = wc * 64 + j * 16 + fr;
        bf[j] = *(const bf16x8*)&sB[r][((ks * 4 + fg) ^ (r & 7)) * 8];
      }
#pragma unroll
      for (int i = 0; i < 4; ++i)
#pragma unroll
        for (int j = 0; j < 4; ++j)
          acc[i][j] = MFMA16(af[i], bf[j], acc[i][j]);
    }
  }
  const int m_blk = m0 + wr * 64, n_blk = n0 + wc * 64;
#pragma unroll
  for (int j = 0; j < 4; ++j) {
    const int n = n_blk + j * 16 + fr;
    const float bi = bias[n];
#pragma unroll
    for (int i = 0; i < 4; ++i)
#pragma unroll
      for (int r = 0; r < 4; ++r) {
        const int m = m_blk + i * 16 + fg * 4 + r;
        outp[(size_t)m * DM_ + n] = acc[i][j][r] + bi;
      }
  }
}

// ---------------- kvstate (MFMA, SC=128): bf16 state + f32 ksum ------------
__global__ __launch_bounds__(256) void kvstate_k(
    const u16* __restrict__ k, const u16* __restrict__ v,
    const u16* __restrict__ omb, const float* __restrict__ nhk,
    u16* __restrict__ stateb, float* __restrict__ ksum) {
  __shared__ u16 sPhi[256][72];
  __shared__ u16 sVt[64][72];
  const int tid = threadIdx.x, lane = tid & 63, w = tid >> 6;
  const int fr = lane & 15, fg = lane >> 4;
  const int sc = blockIdx.x, bh = blockIdx.y;
  const size_t base_l = (size_t)bh * L_ + (size_t)sc * 128;

  bf16x8 ones;
#pragma unroll
  for (int e = 0; e < 8; ++e) ones[e] = (short)0x3F80;

  f32x4 kvacc[4][4] = {};
  f32x4 ksacc[4] = {};

  for (int sub = 0; sub < 2; ++sub) {
    const size_t tl = base_l + sub * 64;
    const u16* kg = k + tl * 64;
    __syncthreads();
    {
      const u16* vp = v + (tl + lane) * 64 + w * 16;
      bf16x8 v0 = *(const bf16x8*)(vp);
      bf16x8 v1 = *(const bf16x8*)(vp + 8);
#pragma unroll
      for (int e = 0; e < 8; ++e) sVt[w * 16 + e][lane] = (u16)v0[e];
#pragma unroll
      for (int e = 0; e < 8; ++e) sVt[w * 16 + 8 + e][lane] = (u16)v1[e];
    }
    float nhr[4];
#pragma unroll
    for (int tt = 0; tt < 4; ++tt) nhr[tt] = nhk[tl + tt * 16 + fr];
#pragma unroll
    for (int mi = 0; mi < 4; ++mi) {
      const int m0 = (w << 6) + mi * 16;
      const bf16x8 a0 = *(const bf16x8*)(omb + (m0 + fr) * 64 + fg * 8);
      const bf16x8 a1 = *(const bf16x8*)(omb + (m0 + fr) * 64 + 32 + fg * 8);
#pragma unroll
      for (int tt = 0; tt < 4; ++tt) {
        const bf16x8 b0 = *(const bf16x8*)(kg + (tt * 16 + fr) * 64 + fg * 8);
        const bf16x8 b1 = *(const bf16x8*)(kg + (tt * 16 + fr) * 64 + 32 + fg * 8);
        f32x4 acc = {0.f, 0.f, 0.f, 0.f};
        acc = MFMA16(a0, b0, acc);
        acc = MFMA16(a1, b1, acc);
        const float nhv = nhr[tt];
#pragma unroll
        for (int r = 0; r < 4; ++r)
          sPhi[m0 + fg * 4 + r][tt * 16 + fr] = f2bf(__expf(acc[r] - nhv));
      }
    }
    __syncthreads();
#pragma unroll
    for (int mi = 0; mi < 4; ++mi) {
      const int m0 = (w << 6) + mi * 16;
      const bf16x8 pb0 = *(const bf16x8*)&sPhi[m0 + fr][fg * 8];
      const bf16x8 pb1 = *(const bf16x8*)&sPhi[m0 + fr][32 + fg * 8];
      ksacc[mi] = MFMA16(pb0, ones, ksacc[mi]);
      ksacc[mi] = MFMA16(pb1, ones, ksacc[mi]);
#pragma unroll
      for (int dj = 0; dj < 4; ++dj) {
        const bf16x8 va0 = *(const bf16x8*)&sVt[dj * 16 + fr][fg * 8];
        const bf16x8 va1 = *(const bf16x8*)&sVt[dj * 16 + fr][32 + fg * 8];
        kvacc[mi][dj] = MFMA16(va0, pb0, kvacc[mi][dj]);
        kvacc[mi][dj] = MFMA16(va1, pb1, kvacc[mi][dj]);
      }
    }
  }
  // state bf16 [d][m]; ksum f32
  u16* stb = stateb + (size_t)(bh * NSC + sc) * (M_ * D_);
  float* ksp = ksum + (size_t)(bh * NSC + sc) * M_;
#pragma unroll
  for (int mi = 0; mi < 4; ++mi) {
    const int m = (w << 6) + mi * 16 + fr;
#pragma unroll
    for (int dj = 0; dj < 4; ++dj)
#pragma unroll
      for (int r = 0; r < 4; ++r)
        stb[(size_t)(dj * 16 + fg * 4 + r) * M_ + m] = f2bf(kvacc[mi][dj][r]);
    if (fr == 0) {
#pragma unroll
      for (int r = 0; r < 4; ++r)
        ksp[(w << 6) + mi * 16 + fg * 4 + r] = ksacc[mi][r];
    }
  }
}

// ---------------- exclusive prefix over superchunks (bf16 state) -----------
__global__ __launch_bounds__(256) void scan_k(u16* __restrict__ stateb,
                                              float* __restrict__ ksum) {
  const int bh = blockIdx.y;
  u16* sb = stateb + (size_t)bh * NSC * (M_ * D_);
  const int base = blockIdx.x * 2048 + threadIdx.x * 8;
  float run[8] = {};
  for (int cc = 0; cc < NSC; ++cc) {
    u16* st = sb + (size_t)cc * (M_ * D_) + base;
    ushort4 t0 = *(ushort4*)st;
    ushort4 t1 = *(ushort4*)(st + 4);
    ushort4 w0, w1;
    w0.x = f2bf(run[0]); w0.y = f2bf(run[1]); w0.z = f2bf(run[2]); w0.w = f2bf(run[3]);
    w1.x = f2bf(run[4]); w1.y = f2bf(run[5]); w1.z = f2bf(run[6]); w1.w = f2bf(run[7]);
    *(ushort4*)st = w0;
    *(ushort4*)(st + 4) = w1;
    run[0] += bf2f(t0.x); run[1] += bf2f(t0.y); run[2] += bf2f(t0.z); run[3] += bf2f(t0.w);
    run[4] += bf2f(t1.x); run[5] += bf2f(t1.y); run[6] += bf2f(t1.z); run[7] += bf2f(t1.w);
  }
  if (blockIdx.x == 0) {           // ksum f32 in-place exclusive prefix
    float rk = 0.f;
    for (int cc = 0; cc < NSC; ++cc) {
      float* p = ksum + (size_t)(bh * NSC + cc) * M_ + threadIdx.x;
      const float t = *p;
      *p = rk;
      rk += t;
    }
  }
}

// ---------------- outchunk helpers -----------------------------------------
// phi quadrant: writes ONLY rows of band wb (wb*16..wb*16+15); nh has ln16
static __device__ __forceinline__ void phi_quad(
    const u16* __restrict__ xg, const u16* __restrict__ ombq,
    u16* __restrict__ dst, int dstride, const float* nhv,
    int wb, int lane) {
  const int fr = lane & 15, fg = lane >> 4;
  const int tband = wb * 16;
  const bf16x8 a0 = *(const bf16x8*)(xg + (tband + fr) * 64 + fg * 8);
  const bf16x8 a1 = *(const bf16x8*)(xg + (tband + fr) * 64 + 32 + fg * 8);
#pragma unroll
  for (int j = 0; j < 4; ++j) {
    const bf16x8 b0 = *(const bf16x8*)(ombq + (j * 16 + fr) * 64 + fg * 8);
    const bf16x8 b1 = *(const bf16x8*)(ombq + (j * 16 + fr) * 64 + 32 + fg * 8);
    f32x4 acc = {0.f, 0.f, 0.f, 0.f};
    acc = MFMA16(a0, b0, acc);
    acc = MFMA16(a1, b1, acc);
#pragma unroll
    for (int r = 0; r < 4; ++r) {
      const int t = tband + fg * 4 + r;
      dst[t * dstride + j * 16 + fr] = f2bf(__expf(acc[r] - nhv[r]));
    }
  }
}

// ---------------- outchunk: 8 superchunks/block (1 round) ------------------
__global__ __launch_bounds__(512, 2) void outchunk_k(
    const u16* __restrict__ q, const u16* __restrict__ kk,
    const u16* __restrict__ v, const u16* __restrict__ omb,
    const u16* __restrict__ stateb, const float* __restrict__ ksum,
    const float* __restrict__ nhq, const float* __restrict__ nhk,
    u16* __restrict__ attn) {
  __shared__ u16 sKa[64][264];    // Kp chunk0 (h0-produced)
  __shared__ u16 sKb[64][264];    // Kp chunk1 (h1-produced)
  __shared__ u16 sS0[64][72];     // h0 q-scratch / h0 masked S
  __shared__ u16 sS1[64][72];     // h1 q-scratch / h1 masked S
  __shared__ u16 sB1[64][72];     // vT chunk0 (h0-staged)
  __shared__ u16 sB2[64][72];     // vT chunk1 (h1-staged)
  __shared__ float ksum_l[256];   // total 105,472 B -> 1 block/CU
  const int tid = threadIdx.x, lane = tid & 63, w = tid >> 6;
  const int h = w >> 2, wl = w & 3;
  const int fr = lane & 15, fg = lane >> 4;
  const int bh = blockIdx.x >> 2, scp = blockIdx.x & 3;

#pragma unroll 1
  for (int it = 0; it < 8; ++it) {
    const int sc = scp * 8 + it;
    const size_t base_l = (size_t)bh * L_ + (size_t)sc * 128;
    const size_t tokq = base_l + (size_t)h * 64;
    const u16* qg = q + tokq * 64;
    const u16* stgb = stateb + (size_t)(bh * NSC + sc) * (M_ * D_);  // [d][m]
    const float* ksg = ksum + (size_t)(bh * NSC + sc) * M_;

    if (tid < 256) ksum_l[tid] = ksg[tid];

    // early v loads: half h loads its own chunk's v
    bf16x8 ev0, ev1;
    {
      const u16* vp = v + (base_l + (size_t)h * 64 + lane) * 64 + wl * 16;
      ev0 = *(const bf16x8*)(vp);
      ev1 = *(const bf16x8*)(vp + 8);
    }

    // phi(k): half h fills its chunk's Kp entirely (own rows, no syncs)
    u16* kdst = (h == 0) ? &sKa[0][0] : &sKb[0][0];
    {
      const size_t ktokh = base_l + (size_t)h * 64;
      const u16* kgh = kk + ktokh * 64;
      float nhkh[4];
#pragma unroll
      for (int r = 0; r < 4; ++r) nhkh[r] = nhk[ktokh + wl * 16 + fg * 4 + r];
#pragma unroll
      for (int mq = 0; mq < 4; ++mq)
        phi_quad(kgh, omb + mq * 4096, kdst + mq * 64, 264, nhkh, wl, lane);
    }

    // phi(q) -> regs via own half's S buffer as scratch (wave-private rows);
    // cross term fused (state B-frag latency hides under phi(k) compute).
    float nhq4[4];
#pragma unroll
    for (int r = 0; r < 4; ++r) nhq4[r] = nhq[tokq + wl * 16 + fg * 4 + r];
    u16* myscr = (h == 0) ? &sS0[0][0] : &sS1[0][0];
    bf16x8 qa0[2], qa1[2], qa2[2], qa3[2];
    f32x4 oacc[4] = {};
#define QPHASE(MQ, QA)                                                          \
    {                                                                           \
      bf16x8 b0r[4], b1r[4];                                                    \
      _Pragma("unroll")                                                         \
      for (int j = 0; j < 4; ++j) {                                             \
        b0r[j] = *(const bf16x8*)(stgb + (size_t)(j * 16 + fr) * M_ + MQ * 64 + fg * 8);      \
        b1r[j] = *(const bf16x8*)(stgb + (size_t)(j * 16 + fr) * M_ + MQ * 64 + 32 + fg * 8); \
      }                                                                         \
      phi_quad(qg, omb + MQ * 4096, myscr, 72, nhq4, wl, lane);                 \
      QA[0] = *(const bf16x8*)(myscr + (wl * 16 + fr) * 72 + fg * 8);           \
      QA[1] = *(const bf16x8*)(myscr + (wl * 16 + fr) * 72 + 32 + fg * 8);      \
      __builtin_amdgcn_s_setprio(1);                                            \
      _Pragma("unroll")                                                         \
      for (int j = 0; j < 4; ++j) {                                             \
        oacc[j] = MFMA16(QA[0], b0r[j], oacc[j]);                               \
        oacc[j] = MFMA16(QA[1], b1r[j], oacc[j]);                               \
      }                                                                         \
      __builtin_amdgcn_s_setprio(0);                                            \
    }
    QPHASE(0, qa0)
    QPHASE(1, qa1)
    QPHASE(2, qa2)
    QPHASE(3, qa3)
#undef QPHASE
    __syncthreads();   // BAR K: ksum_l + full Kp (sKa/sKb) visible to all

    // den-ksum from register frags
    float denk = 0.f;
#pragma unroll
    for (int e = 0; e < 8; ++e) {
      denk += bf2f((u16)qa0[0][e]) * ksum_l[0   + fg * 8 + e]
            + bf2f((u16)qa0[1][e]) * ksum_l[32  + fg * 8 + e]
            + bf2f((u16)qa1[0][e]) * ksum_l[64  + fg * 8 + e]
            + bf2f((u16)qa1[1][e]) * ksum_l[96  + fg * 8 + e]
            + bf2f((u16)qa2[0][e]) * ksum_l[128 + fg * 8 + e]
            + bf2f((u16)qa2[1][e]) * ksum_l[160 + fg * 8 + e]
            + bf2f((u16)qa3[0][e]) * ksum_l[192 + fg * 8 + e]
            + bf2f((u16)qa3[1][e]) * ksum_l[224 + fg * 8 + e];
    }
    denk += __shfl_xor(denk, 16, 64);
    denk += __shfl_xor(denk, 32, 64);

    // ---- S chunk0 (all waves): 32 MFMA, B-frags from sKa
    float dS[4] = {0.f, 0.f, 0.f, 0.f};
    {
      f32x4 sacc[4] = {};
      __builtin_amdgcn_s_setprio(1);
#define SPH0(MQ, QA)                                                            \
      _Pragma("unroll")                                                         \
      for (int j = 0; j < 4; ++j) {                                             \
        const bf16x8 b0 = *(const bf16x8*)&sKa[j * 16 + fr][MQ * 64 + fg * 8];  \
        const bf16x8 b1 = *(const bf16x8*)&sKa[j * 16 + fr][MQ * 64 + 32 + fg * 8]; \
        sacc[j] = MFMA16(QA[0], b0, sacc[j]);                                   \
        sacc[j] = MFMA16(QA[1], b1, sacc[j]);                                   \
      }
      SPH0(0, qa0)
      SPH0(1, qa1)
      SPH0(2, qa2)
      SPH0(3, qa3)
#undef SPH0
      __builtin_amdgcn_s_setprio(0);
      u16 (*sSo)[72] = (h == 0) ? sS0 : sS1;
#pragma unroll
      for (int j = 0; j < 4; ++j)
#pragma unroll
        for (int r = 0; r < 4; ++r) {
          const int ss = j * 16 + fr, t = wl * 16 + fg * 4 + r;
          float val = sacc[j][r];
          if (h == 0 && ss > t) val = 0.f;
          const u16 vb = f2bf(val);
          sSo[t][ss] = vb;
          dS[r] += bf2f(vb);
        }
    }
    // vT staging: h0 -> sB1 (chunk0), h1 -> sB2 (chunk1)
    {
      u16 (*sBo)[72] = (h == 0) ? sB1 : sB2;
#pragma unroll
      for (int e = 0; e < 8; ++e) sBo[wl * 16 + e][lane] = (u16)ev0[e];
#pragma unroll
      for (int e = 0; e < 8; ++e) sBo[wl * 16 + 8 + e][lane] = (u16)ev1[e];
    }
    __syncthreads();   // BAR F0: sS0/sS1 + sB1/sB2 visible

    // ---- S@V chunk0 (all waves): A = own masked S (own band), B = sB1
    {
      const u16 (*sSo)[72] = (h == 0) ? sS0 : sS1;
      const bf16x8 a0 = *(const bf16x8*)&sSo[wl * 16 + fr][fg * 8];
      const bf16x8 a1 = *(const bf16x8*)&sSo[wl * 16 + fr][32 + fg * 8];
      __builtin_amdgcn_s_setprio(1);
#pragma unroll
      for (int j = 0; j < 4; ++j) {
        const bf16x8 b0 = *(const bf16x8*)&sB1[j * 16 + fr][fg * 8];
        const bf16x8 b1 = *(const bf16x8*)&sB1[j * 16 + fr][32 + fg * 8];
        oacc[j] = MFMA16(a0, b0, oacc[j]);
        oacc[j] = MFMA16(a1, b1, oacc[j]);
      }
      __builtin_amdgcn_s_setprio(0);
    }

    // ---- h1 only: S chunk1 (sKb) -> masked sS1 -> S@V chunk1 (sB2)
    if (h == 1) {
      f32x4 sacc[4] = {};
      __builtin_amdgcn_s_setprio(1);
#define SPH1(MQ, QA)                                                            \
      _Pragma("unroll")                                                         \
      for (int j = 0; j < 4; ++j) {                                             \
        const bf16x8 b0 = *(const bf16x8*)&sKb[j * 16 + fr][MQ * 64 + fg * 8];  \
        const bf16x8 b1 = *(const bf16x8*)&sKb[j * 16 + fr][MQ * 64 + 32 + fg * 8]; \
        sacc[j] = MFMA16(QA[0], b0, sacc[j]);                                   \
        sacc[j] = MFMA16(QA[1], b1, sacc[j]);                                   \
      }
      SPH1(0, qa0)
      SPH1(1, qa1)
      SPH1(2, qa2)
      SPH1(3, qa3)
#undef SPH1
      __builtin_amdgcn_s_setprio(0);
#pragma unroll
      for (int j = 0; j < 4; ++j)
#pragma unroll
        for (int r = 0; r < 4; ++r) {
          const int ss = j * 16 + fr, t = wl * 16 + fg * 4 + r;
          float val = sacc[j][r];
          if (ss > t) val = 0.f;         // diag (s == h == 1)
          const u16 vb = f2bf(val);
          sS1[t][ss] = vb;
          dS[r] += bf2f(vb);
        }
      {
        const bf16x8 a0 = *(const bf16x8*)&sS1[wl * 16 + fr][fg * 8];
        const bf16x8 a1 = *(const bf16x8*)&sS1[wl * 16 + fr][32 + fg * 8];
        __builtin_amdgcn_s_setprio(1);
#pragma unroll
        for (int j = 0; j < 4; ++j) {
          const bf16x8 b0 = *(const bf16x8*)&sB2[j * 16 + fr][fg * 8];
          const bf16x8 b1 = *(const bf16x8*)&sB2[j * 16 + fr][32 + fg * 8];
          oacc[j] = MFMA16(a0, b0, oacc[j]);
          oacc[j] = MFMA16(a1, b1, oacc[j]);
        }
        __builtin_amdgcn_s_setprio(0);
      }
    }

    // den: reduce dS over fr lanes; combine with denk via shfl
#pragma unroll
    for (int m2 = 1; m2 <= 8; m2 <<= 1) {
#pragma unroll
      for (int r = 0; r < 4; ++r) dS[r] += __shfl_xor(dS[r], m2, 64);
    }
    const int b = bh >> 4, hh = bh & 15;
#pragma unroll
    for (int r = 0; r < 4; ++r) {
      const float dk = __shfl(denk, fg * 4 + r, 64);   // token wl*16+fg*4+r
      const float rinv = 1.0f / (dk + dS[r] + 1e-6f);
      const int t = wl * 16 + fg * 4 + r;
      const int l = sc * 128 + h * 64 + t;
#pragma unroll
      for (int j = 0; j < 4; ++j) {
        const int d = j * 16 + fr;
        attn[((size_t)b * L_ + l) * DM_ + hh * 64 + d] = f2bf(oacc[j][r] * rinv);
      }
    }
    __syncthreads();   // BAR E: full fence before next superchunk's reuse
  }
}

extern "C" void kernel_launch(void* const* d_in, const int* in_sizes, int n_in,
                              void* d_out, int out_size, void* d_ws, size_t ws_size,
                              hipStream_t stream) {
  const float* x     = (const float*)d_in[0];
  const float* Wq    = (const float*)d_in[1];
  const float* bq    = (const float*)d_in[2];
  const float* Wk    = (const float*)d_in[3];
  const float* bk    = (const float*)d_in[4];
  const float* Wv    = (const float*)d_in[5];
  const float* bv    = (const float*)d_in[6];
  const float* Wo    = (const float*)d_in[7];
  const float* bo    = (const float*)d_in[8];
  const float* omega = (const float*)d_in[9];
  float* out = (float*)d_out;

  char* ws = (char*)d_ws;
  u16*   v      = (u16*)(ws);                           // 32 MB
  u16*   qb     = (u16*)(ws + 33554432ull);             // 32 MB
  u16*   kb     = (u16*)(ws + 67108864ull);             // 32 MB
  u16*   xb     = (u16*)(ws + 100663296ull);            // 32 MB (alias attn)
  u16*   attn   = xb;
  u16*   stateb = (u16*)(ws + 134217728ull);            // 64 MB
  float* ksum   = (float*)(ws + 201326592ull);          // 2 MB
  u16*   Wt     = (u16*)(ws + 203423744ull);            // 8 MB
  u16*   omb    = (u16*)(ws + 211812352ull);            // 32 KB
  float* nhq    = (float*)(ws + 211845120ull);          // 1 MB
  float* nhk    = (float*)(ws + 212893696ull);          // 1 MB -> 204 MB

  prep_k<<<17472, 256, 0, stream>>>(x, xb, Wq, Wk, Wv, Wo, Wt, omega, omb);
  mm3_k<<<dim3(1024, 3), 256, 0, stream>>>(xb, Wt, bq, bk, bv,
                                           qb, kb, v, nhq, nhk);
  kvstate_k<<<dim3(NSC, BH_), 256, 0, stream>>>(kb, v, omb, nhk, stateb, ksum);
  scan_k<<<dim3(8, BH_), 256, 0, stream>>>(stateb, ksum);
  outchunk_k<<<BH_ * (NSC / 8), 512, 0, stream>>>(qb, kb, v, omb, stateb, ksum,
                                                  nhq, nhk, attn);
  mmo_k<<<1024, 256, 0, stream>>>(attn, Wt + 3145728ull, bo, out);
}

// Round 24
// 435.688 us; speedup vs baseline: 1.3007x; 1.0031x over previous
//
#include <hip/hip_runtime.h>
#include <hip/hip_bf16.h>

// FAVOR+ attention, MI355X. Round 24: revert R23's shared-sQ (cross-half
// race: both halves wrote the same sQ rows). Keep the two safe pieces:
//  - phi_quad_r: x-row fragments loaded ONCE per tile (not per quadrant).
//  - kvstate: 4 superchunks per block (grid (8,64)).
//  - outchunk structure = validated R22 (QPHASE scratch = own half's S
//    buffer, stride 72; 8 superchunks/block; 3 barriers/iter).
//
// Workspace (bytes), total 213,942,272 (~204 MB): layout as R17-R22.

#define B_ 4
#define H_ 16
#define L_ 4096
#define D_ 64
#define M_ 256
#define DM_ 1024
#define BH_ 64
#define NSC 32            // superchunks per bh (SC = 128 tokens)

typedef unsigned int u32;
typedef unsigned short u16;
typedef __attribute__((ext_vector_type(8))) short bf16x8;
typedef __attribute__((ext_vector_type(4))) float f32x4;

static __device__ __forceinline__ float bf2f(u16 u) {
  return __uint_as_float(((u32)u) << 16);
}
static __device__ __forceinline__ u16 f2bf(float f) {
  u32 x = __float_as_uint(f);
  return (u16)((x + 0x7fffu + ((x >> 16) & 1u)) >> 16);   // RNE
}
#define MFMA16(a, b, c) __builtin_amdgcn_mfma_f32_16x16x32_bf16((a), (b), (c), 0, 0, 0)
#define LN16 2.772588722239781f

// ---------------- merged prep: convx | convw | convom ----------------------
__global__ __launch_bounds__(256) void prep_k(
    const float* __restrict__ x, u16* __restrict__ xb,
    const float* __restrict__ W0, const float* __restrict__ W1,
    const float* __restrict__ W2, const float* __restrict__ W3,
    u16* __restrict__ Wt, const float* __restrict__ om,
    u16* __restrict__ omb) {
  __shared__ u16 tt[64][66];
  const int bid = blockIdx.x, tid = threadIdx.x;
  if (bid < 16384) {
    const int i = bid * 256 + tid;
    float4 f = ((const float4*)x)[i];
    ushort4 u;
    u.x = f2bf(f.x); u.y = f2bf(f.y); u.z = f2bf(f.z); u.w = f2bf(f.w);
    ((ushort4*)xb)[i] = u;
  } else if (bid < 17408) {
    const int rem = bid - 16384;
    const int z = rem >> 8, r2 = rem & 255;
    const int k0 = (r2 >> 4) * 64, n0 = (r2 & 15) * 64;
    const float* W = (z == 0) ? W0 : (z == 1) ? W1 : (z == 2) ? W2 : W3;
    u16* o = Wt + (size_t)z * 1048576ull;
    const int r = tid >> 4, c4 = (tid & 15) << 2;
    for (int rr = r; rr < 64; rr += 16) {
      float4 w4 = *(const float4*)(W + (size_t)(k0 + rr) * DM_ + n0 + c4);
      tt[c4 + 0][rr] = f2bf(w4.x);
      tt[c4 + 1][rr] = f2bf(w4.y);
      tt[c4 + 2][rr] = f2bf(w4.z);
      tt[c4 + 3][rr] = f2bf(w4.w);
    }
    __syncthreads();
    for (int rr = r; rr < 64; rr += 16) {
      ushort4 u4;
      u4.x = tt[rr][c4 + 0];
      u4.y = tt[rr][c4 + 1];
      u4.z = tt[rr][c4 + 2];
      u4.w = tt[rr][c4 + 3];
      *(ushort4*)(o + (size_t)(n0 + rr) * DM_ + k0 + c4) = u4;
    }
  } else {
    const int i = (bid - 17408) * 256 + tid;
    omb[i] = f2bf(om[i] * 0.35355339059327373f);     // fold 64^-0.25
  }
}

// ---------------- merged projection GEMMs (q,k,v), head bf16 out -----------
// nh' = 0.0625 * sum(bf2f(f2bf(v))^2) + ln16  (phi scale folded in)
__global__ __launch_bounds__(256) void mm3_k(
    const u16* __restrict__ A, const u16* __restrict__ Wt,
    const float* __restrict__ bq, const float* __restrict__ bk,
    const float* __restrict__ bv, u16* __restrict__ qb,
    u16* __restrict__ kb, u16* __restrict__ vb,
    float* __restrict__ nhq, float* __restrict__ nhk) {
  __shared__ u16 sA[128][64];   // 16 KB, XOR-swizzled 16B slots
  __shared__ u16 sB[128][64];   // 16 KB
  const int y = blockIdx.y;
  const u16* Bt = Wt + (size_t)y * 1048576ull;
  const float* bias = (y == 0) ? bq : (y == 1) ? bk : bv;
  u16* outp = (y == 0) ? qb : (y == 1) ? kb : vb;
  float* nhout = (y == 0) ? nhq : (y == 1) ? nhk : nullptr;
  const int tid = threadIdx.x, lane = tid & 63, w = tid >> 6;
  const int fr = lane & 15, fg = lane >> 4;
  const int wr = w >> 1, wc = w & 1;
  const int lb = ((blockIdx.x & 7) << 7) | (blockIdx.x >> 3);
  const int m0 = (lb >> 3) * 128, n0 = (lb & 7) * 128;
  const int srow = tid >> 3, sslot = tid & 7;   // +p*32 rows per pass
  f32x4 acc[4][4] = {};
  bf16x8 av[4], bv4[4];
#pragma unroll
  for (int p = 0; p < 4; ++p) {
    av[p]  = *(const bf16x8*)(A  + (size_t)(m0 + srow + p * 32) * DM_ + sslot * 8);
    bv4[p] = *(const bf16x8*)(Bt + (size_t)(n0 + srow + p * 32) * DM_ + sslot * 8);
  }
  for (int k0 = 0; k0 < DM_; k0 += 64) {
    __syncthreads();
#pragma unroll
    for (int p = 0; p < 4; ++p) {
      const int r = srow + p * 32;
      *(bf16x8*)&sA[r][(sslot ^ (r & 7)) * 8] = av[p];
      *(bf16x8*)&sB[r][(sslot ^ (r & 7)) * 8] = bv4[p];
    }
    if (k0 + 64 < DM_) {
#pragma unroll
      for (int p = 0; p < 4; ++p) {
        av[p]  = *(const bf16x8*)(A  + (size_t)(m0 + srow + p * 32) * DM_ + k0 + 64 + sslot * 8);
        bv4[p] = *(const bf16x8*)(Bt + (size_t)(n0 + srow + p * 32) * DM_ + k0 + 64 + sslot * 8);
      }
    }
    __syncthreads();
#pragma unroll
    for (int ks = 0; ks < 2; ++ks) {
      bf16x8 af[4], bf[4];
#pragma unroll
      for (int i = 0; i < 4; ++i) {
        const int r = wr * 64 + i * 16 + fr;
        af[i] = *(const bf16x8*)&sA[r][((ks * 4 + fg) ^ (r & 7)) * 8];
      }
#pragma unroll
      for (int j = 0; j < 4; ++j) {
        const int r = wc * 64 + j * 16 + fr;
        bf[j] = *(const bf16x8*)&sB[r][((ks * 4 + fg) ^ (r & 7)) * 8];
      }
#pragma unroll
      for (int i = 0; i < 4; ++i)
#pragma unroll
        for (int j = 0; j < 4; ++j)
          acc[i][j] = MFMA16(af[i], bf[j], acc[i][j]);
    }
  }
  const int m_blk = m0 + wr * 64, n_blk = n0 + wc * 64;
  float nhacc[4][4] = {};
#pragma unroll
  for (int j = 0; j < 4; ++j) {
    const int n = n_blk + j * 16 + fr;
    const float bi = bias[n];
    const int h = n >> 6, d = n & 63;
#pragma unroll
    for (int i = 0; i < 4; ++i) {
#pragma unroll
      for (int r = 0; r < 4; ++r) {
        const int m = m_blk + i * 16 + fg * 4 + r;
        const float val = acc[i][j][r] + bi;
        const int b = m >> 12, l = m & 4095;
        const u16 sv = f2bf(val);
        outp[((size_t)(b * H_ + h) * L_ + l) * D_ + d] = sv;
        const float rv = bf2f(sv);
        nhacc[i][r] += rv * rv;
      }
    }
  }
  if (nhout) {
    const int hh2 = n_blk >> 6;
#pragma unroll
    for (int i = 0; i < 4; ++i)
#pragma unroll
      for (int r = 0; r < 4; ++r) {
        float s = nhacc[i][r];
        s += __shfl_xor(s, 1, 64);
        s += __shfl_xor(s, 2, 64);
        s += __shfl_xor(s, 4, 64);
        s += __shfl_xor(s, 8, 64);
        if (fr == 0) {
          const int m = m_blk + i * 16 + fg * 4 + r;
          const int b = m >> 12, l = m & 4095;
          nhout[(size_t)(b * H_ + hh2) * L_ + l] = 0.0625f * s + LN16;
        }
      }
  }
}

// ---------------- final GEMM (attn bf16 -> f32 out), validated -------------
__global__ __launch_bounds__(256) void mmo_k(
    const u16* __restrict__ A, const u16* __restrict__ Bt,
    const float* __restrict__ bias, float* __restrict__ outp) {
  __shared__ u16 sA[128][64];
  __shared__ u16 sB[128][64];
  const int tid = threadIdx.x, lane = tid & 63, w = tid >> 6;
  const int fr = lane & 15, fg = lane >> 4;
  const int wr = w >> 1, wc = w & 1;
  const int lb = ((blockIdx.x & 7) << 7) | (blockIdx.x >> 3);
  const int m0 = (lb >> 3) * 128, n0 = (lb & 7) * 128;
  const int srow = tid >> 3, sslot = tid & 7;
  f32x4 acc[4][4] = {};
  bf16x8 av[4], bv[4];
#pragma unroll
  for (int p = 0; p < 4; ++p) {
    av[p] = *(const bf16x8*)(A  + (size_t)(m0 + srow + p * 32) * DM_ + sslot * 8);
    bv[p] = *(const bf16x8*)(Bt + (size_t)(n0 + srow + p * 32) * DM_ + sslot * 8);
  }
  for (int k0 = 0; k0 < DM_; k0 += 64) {
    __syncthreads();
#pragma unroll
    for (int p = 0; p < 4; ++p) {
      const int r = srow + p * 32;
      *(bf16x8*)&sA[r][(sslot ^ (r & 7)) * 8] = av[p];
      *(bf16x8*)&sB[r][(sslot ^ (r & 7)) * 8] = bv[p];
    }
    if (k0 + 64 < DM_) {
#pragma unroll
      for (int p = 0; p < 4; ++p) {
        av[p] = *(const bf16x8*)(A  + (size_t)(m0 + srow + p * 32) * DM_ + k0 + 64 + sslot * 8);
        bv[p] = *(const bf16x8*)(Bt + (size_t)(n0 + srow + p * 32) * DM_ + k0 + 64 + sslot * 8);
      }
    }
    __syncthreads();
#pragma unroll
    for (int ks = 0; ks < 2; ++ks) {
      bf16x8 af[4], bf[4];
#pragma unroll
      for (int i = 0; i < 4; ++i) {
        const int r = wr * 64 + i * 16 + fr;
        af[i] = *(const bf16x8*)&sA[r][((ks * 4 + fg) ^ (r & 7)) * 8];
      }
#pragma unroll
      for (int j = 0; j < 4; ++j) {
        const int r = wc * 64 + j * 16 + fr;
        bf[j] = *(const bf16x8*)&sB[r][((ks * 4 + fg) ^ (r & 7)) * 8];
      }
#pragma unroll
      for (int i = 0; i < 4; ++i)
#pragma unroll
        for (int j = 0; j < 4; ++j)
          acc[i][j] = MFMA16(af[i], bf[j], acc[i][j]);
    }
  }
  const int m_blk = m0 + wr * 64, n_blk = n0 + wc * 64;
#pragma unroll
  for (int j = 0; j < 4; ++j) {
    const int n = n_blk + j * 16 + fr;
    const float bi = bias[n];
#pragma unroll
    for (int i = 0; i < 4; ++i)
#pragma unroll
      for (int r = 0; r < 4; ++r) {
        const int m = m_blk + i * 16 + fg * 4 + r;
        outp[(size_t)m * DM_ + n] = acc[i][j][r] + bi;
      }
  }
}

// ---------------- kvstate (MFMA, SC=128, 4 superchunks/block) --------------
__global__ __launch_bounds__(256) void kvstate_k(
    const u16* __restrict__ k, const u16* __restrict__ v,
    const u16* __restrict__ omb, const float* __restrict__ nhk,
    u16* __restrict__ stateb, float* __restrict__ ksum) {
  __shared__ u16 sPhi[256][72];
  __shared__ u16 sVt[64][72];
  const int tid = threadIdx.x, lane = tid & 63, w = tid >> 6;
  const int fr = lane & 15, fg = lane >> 4;
  const int bh = blockIdx.y;

  bf16x8 ones;
#pragma unroll
  for (int e = 0; e < 8; ++e) ones[e] = (short)0x3F80;

#pragma unroll 1
  for (int isc = 0; isc < 4; ++isc) {
    const int sc = blockIdx.x * 4 + isc;
    const size_t base_l = (size_t)bh * L_ + (size_t)sc * 128;

    f32x4 kvacc[4][4] = {};
    f32x4 ksacc[4] = {};

    for (int sub = 0; sub < 2; ++sub) {
      const size_t tl = base_l + sub * 64;
      const u16* kg = k + tl * 64;
      __syncthreads();   // fences prior sPhi/sVt readers (incl. prev isc)
      {
        const u16* vp = v + (tl + lane) * 64 + w * 16;
        bf16x8 v0 = *(const bf16x8*)(vp);
        bf16x8 v1 = *(const bf16x8*)(vp + 8);
#pragma unroll
        for (int e = 0; e < 8; ++e) sVt[w * 16 + e][lane] = (u16)v0[e];
#pragma unroll
        for (int e = 0; e < 8; ++e) sVt[w * 16 + 8 + e][lane] = (u16)v1[e];
      }
      float nhr[4];
#pragma unroll
      for (int tt = 0; tt < 4; ++tt) nhr[tt] = nhk[tl + tt * 16 + fr];
#pragma unroll
      for (int mi = 0; mi < 4; ++mi) {
        const int m0 = (w << 6) + mi * 16;
        const bf16x8 a0 = *(const bf16x8*)(omb + (m0 + fr) * 64 + fg * 8);
        const bf16x8 a1 = *(const bf16x8*)(omb + (m0 + fr) * 64 + 32 + fg * 8);
#pragma unroll
        for (int tt = 0; tt < 4; ++tt) {
          const bf16x8 b0 = *(const bf16x8*)(kg + (tt * 16 + fr) * 64 + fg * 8);
          const bf16x8 b1 = *(const bf16x8*)(kg + (tt * 16 + fr) * 64 + 32 + fg * 8);
          f32x4 acc = {0.f, 0.f, 0.f, 0.f};
          acc = MFMA16(a0, b0, acc);
          acc = MFMA16(a1, b1, acc);
          const float nhv = nhr[tt];
#pragma unroll
          for (int r = 0; r < 4; ++r)
            sPhi[m0 + fg * 4 + r][tt * 16 + fr] = f2bf(__expf(acc[r] - nhv));
        }
      }
      __syncthreads();
#pragma unroll
      for (int mi = 0; mi < 4; ++mi) {
        const int m0 = (w << 6) + mi * 16;
        const bf16x8 pb0 = *(const bf16x8*)&sPhi[m0 + fr][fg * 8];
        const bf16x8 pb1 = *(const bf16x8*)&sPhi[m0 + fr][32 + fg * 8];
        ksacc[mi] = MFMA16(pb0, ones, ksacc[mi]);
        ksacc[mi] = MFMA16(pb1, ones, ksacc[mi]);
#pragma unroll
        for (int dj = 0; dj < 4; ++dj) {
          const bf16x8 va0 = *(const bf16x8*)&sVt[dj * 16 + fr][fg * 8];
          const bf16x8 va1 = *(const bf16x8*)&sVt[dj * 16 + fr][32 + fg * 8];
          kvacc[mi][dj] = MFMA16(va0, pb0, kvacc[mi][dj]);
          kvacc[mi][dj] = MFMA16(va1, pb1, kvacc[mi][dj]);
        }
      }
    }
    // state bf16 [d][m]; ksum f32
    u16* stb = stateb + (size_t)(bh * NSC + sc) * (M_ * D_);
    float* ksp = ksum + (size_t)(bh * NSC + sc) * M_;
#pragma unroll
    for (int mi = 0; mi < 4; ++mi) {
      const int m = (w << 6) + mi * 16 + fr;
#pragma unroll
      for (int dj = 0; dj < 4; ++dj)
#pragma unroll
        for (int r = 0; r < 4; ++r)
          stb[(size_t)(dj * 16 + fg * 4 + r) * M_ + m] = f2bf(kvacc[mi][dj][r]);
      if (fr == 0) {
#pragma unroll
        for (int r = 0; r < 4; ++r)
          ksp[(w << 6) + mi * 16 + fg * 4 + r] = ksacc[mi][r];
      }
    }
  }
}

// ---------------- exclusive prefix over superchunks (bf16 state) -----------
__global__ __launch_bounds__(256) void scan_k(u16* __restrict__ stateb,
                                              float* __restrict__ ksum) {
  const int bh = blockIdx.y;
  u16* sb = stateb + (size_t)bh * NSC * (M_ * D_);
  const int base = blockIdx.x * 2048 + threadIdx.x * 8;
  float run[8] = {};
  for (int cc = 0; cc < NSC; ++cc) {
    u16* st = sb + (size_t)cc * (M_ * D_) + base;
    ushort4 t0 = *(ushort4*)st;
    ushort4 t1 = *(ushort4*)(st + 4);
    ushort4 w0, w1;
    w0.x = f2bf(run[0]); w0.y = f2bf(run[1]); w0.z = f2bf(run[2]); w0.w = f2bf(run[3]);
    w1.x = f2bf(run[4]); w1.y = f2bf(run[5]); w1.z = f2bf(run[6]); w1.w = f2bf(run[7]);
    *(ushort4*)st = w0;
    *(ushort4*)(st + 4) = w1;
    run[0] += bf2f(t0.x); run[1] += bf2f(t0.y); run[2] += bf2f(t0.z); run[3] += bf2f(t0.w);
    run[4] += bf2f(t1.x); run[5] += bf2f(t1.y); run[6] += bf2f(t1.z); run[7] += bf2f(t1.w);
  }
  if (blockIdx.x == 0) {           // ksum f32 in-place exclusive prefix
    float rk = 0.f;
    for (int cc = 0; cc < NSC; ++cc) {
      float* p = ksum + (size_t)(bh * NSC + cc) * M_ + threadIdx.x;
      const float t = *p;
      *p = rk;
      rk += t;
    }
  }
}

// ---------------- outchunk helpers -----------------------------------------
// phi quadrant from PRELOADED x-frags: writes ONLY rows of band wb
static __device__ __forceinline__ void phi_quad_r(
    bf16x8 a0, bf16x8 a1, const u16* __restrict__ ombq,
    u16* __restrict__ dst, int dstride, const float* nhv,
    int wb, int lane) {
  const int fr = lane & 15, fg = lane >> 4;
  const int tband = wb * 16;
#pragma unroll
  for (int j = 0; j < 4; ++j) {
    const bf16x8 b0 = *(const bf16x8*)(ombq + (j * 16 + fr) * 64 + fg * 8);
    const bf16x8 b1 = *(const bf16x8*)(ombq + (j * 16 + fr) * 64 + 32 + fg * 8);
    f32x4 acc = {0.f, 0.f, 0.f, 0.f};
    acc = MFMA16(a0, b0, acc);
    acc = MFMA16(a1, b1, acc);
#pragma unroll
    for (int r = 0; r < 4; ++r) {
      const int t = tband + fg * 4 + r;
      dst[t * dstride + j * 16 + fr] = f2bf(__expf(acc[r] - nhv[r]));
    }
  }
}

// ---------------- outchunk: 8 superchunks/block (R22 structure) ------------
__global__ __launch_bounds__(512, 2) void outchunk_k(
    const u16* __restrict__ q, const u16* __restrict__ kk,
    const u16* __restrict__ v, const u16* __restrict__ omb,
    const u16* __restrict__ stateb, const float* __restrict__ ksum,
    const float* __restrict__ nhq, const float* __restrict__ nhk,
    u16* __restrict__ attn) {
  __shared__ u16 sKa[64][264];    // Kp chunk0 (h0-produced)
  __shared__ u16 sKb[64][264];    // Kp chunk1 (h1-produced)
  __shared__ u16 sS0[64][72];     // h0 q-scratch / h0 masked S
  __shared__ u16 sS1[64][72];     // h1 q-scratch / h1 masked S
  __shared__ u16 sB1[64][72];     // vT chunk0 (h0-staged)
  __shared__ u16 sB2[64][72];     // vT chunk1 (h1-staged)
  __shared__ float ksum_l[256];   // total 105,472 B -> 1 block/CU
  const int tid = threadIdx.x, lane = tid & 63, w = tid >> 6;
  const int h = w >> 2, wl = w & 3;
  const int fr = lane & 15, fg = lane >> 4;
  const int bh = blockIdx.x >> 2, scp = blockIdx.x & 3;

#pragma unroll 1
  for (int it = 0; it < 8; ++it) {
    const int sc = scp * 8 + it;
    const size_t base_l = (size_t)bh * L_ + (size_t)sc * 128;
    const size_t tokq = base_l + (size_t)h * 64;
    const u16* qg = q + tokq * 64;
    const u16* stgb = stateb + (size_t)(bh * NSC + sc) * (M_ * D_);  // [d][m]
    const float* ksg = ksum + (size_t)(bh * NSC + sc) * M_;

    if (tid < 256) ksum_l[tid] = ksg[tid];

    // early v loads: half h loads its own chunk's v
    bf16x8 ev0, ev1;
    {
      const u16* vp = v + (base_l + (size_t)h * 64 + lane) * 64 + wl * 16;
      ev0 = *(const bf16x8*)(vp);
      ev1 = *(const bf16x8*)(vp + 8);
    }

    // phi(k): half h fills its chunk's Kp entirely (own rows, no syncs);
    // x-row loaded once (phi_quad_r).
    u16* kdst = (h == 0) ? &sKa[0][0] : &sKb[0][0];
    {
      const size_t ktokh = base_l + (size_t)h * 64;
      const u16* kgh = kk + ktokh * 64;
      float nhkh[4];
#pragma unroll
      for (int r = 0; r < 4; ++r) nhkh[r] = nhk[ktokh + wl * 16 + fg * 4 + r];
      const bf16x8 xk0 = *(const bf16x8*)(kgh + (wl * 16 + fr) * 64 + fg * 8);
      const bf16x8 xk1 = *(const bf16x8*)(kgh + (wl * 16 + fr) * 64 + 32 + fg * 8);
#pragma unroll
      for (int mq = 0; mq < 4; ++mq)
        phi_quad_r(xk0, xk1, omb + mq * 4096, kdst + mq * 64, 264, nhkh, wl, lane);
    }

    // phi(q) -> regs via own half's S buffer as scratch (wave-private rows);
    // cross term fused; x-row loaded once.
    float nhq4[4];
#pragma unroll
    for (int r = 0; r < 4; ++r) nhq4[r] = nhq[tokq + wl * 16 + fg * 4 + r];
    u16* myscr = (h == 0) ? &sS0[0][0] : &sS1[0][0];
    const bf16x8 xq0 = *(const bf16x8*)(qg + (wl * 16 + fr) * 64 + fg * 8);
    const bf16x8 xq1 = *(const bf16x8*)(qg + (wl * 16 + fr) * 64 + 32 + fg * 8);
    bf16x8 qa0[2], qa1[2], qa2[2], qa3[2];
    f32x4 oacc[4] = {};
#define QPHASE(MQ, QA)                                                          \
    {                                                                           \
      bf16x8 b0r[4], b1r[4];                                                    \
      _Pragma("unroll")                                                         \
      for (int j = 0; j < 4; ++j) {                                             \
        b0r[j] = *(const bf16x8*)(stgb + (size_t)(j * 16 + fr) * M_ + MQ * 64 + fg * 8);      \
        b1r[j] = *(const bf16x8*)(stgb + (size_t)(j * 16 + fr) * M_ + MQ * 64 + 32 + fg * 8); \
      }                                                                         \
      phi_quad_r(xq0, xq1, omb + MQ * 4096, myscr, 72, nhq4, wl, lane);         \
      QA[0] = *(const bf16x8*)(myscr + (wl * 16 + fr) * 72 + fg * 8);           \
      QA[1] = *(const bf16x8*)(myscr + (wl * 16 + fr) * 72 + 32 + fg * 8);      \
      __builtin_amdgcn_s_setprio(1);                                            \
      _Pragma("unroll")                                                         \
      for (int j = 0; j < 4; ++j) {                                             \
        oacc[j] = MFMA16(QA[0], b0r[j], oacc[j]);                               \
        oacc[j] = MFMA16(QA[1], b1r[j], oacc[j]);                               \
      }                                                                         \
      __builtin_amdgcn_s_setprio(0);                                            \
    }
    QPHASE(0, qa0)
    QPHASE(1, qa1)
    QPHASE(2, qa2)
    QPHASE(3, qa3)
#undef QPHASE
    __syncthreads();   // BAR K: ksum_l + full Kp (sKa/sKb) visible to all

    // den-ksum from register frags
    float denk = 0.f;
#pragma unroll
    for (int e = 0; e < 8; ++e) {
      denk += bf2f((u16)qa0[0][e]) * ksum_l[0   + fg * 8 + e]
            + bf2f((u16)qa0[1][e]) * ksum_l[32  + fg * 8 + e]
            + bf2f((u16)qa1[0][e]) * ksum_l[64  + fg * 8 + e]
            + bf2f((u16)qa1[1][e]) * ksum_l[96  + fg * 8 + e]
            + bf2f((u16)qa2[0][e]) * ksum_l[128 + fg * 8 + e]
            + bf2f((u16)qa2[1][e]) * ksum_l[160 + fg * 8 + e]
            + bf2f((u16)qa3[0][e]) * ksum_l[192 + fg * 8 + e]
            + bf2f((u16)qa3[1][e]) * ksum_l[224 + fg * 8 + e];
    }
    denk += __shfl_xor(denk, 16, 64);
    denk += __shfl_xor(denk, 32, 64);

    // ---- S chunk0 (all waves): 32 MFMA, B-frags from sKa
    float dS[4] = {0.f, 0.f, 0.f, 0.f};
    {
      f32x4 sacc[4] = {};
      __builtin_amdgcn_s_setprio(1);
#define SPH0(MQ, QA)                                                            \
      _Pragma("unroll")                                                         \
      for (int j = 0; j < 4; ++j) {                                             \
        const bf16x8 b0 = *(const bf16x8*)&sKa[j * 16 + fr][MQ * 64 + fg * 8];  \
        const bf16x8 b1 = *(const bf16x8*)&sKa[j * 16 + fr][MQ * 64 + 32 + fg * 8]; \
        sacc[j] = MFMA16(QA[0], b0, sacc[j]);                                   \
        sacc[j] = MFMA16(QA[1], b1, sacc[j]);                                   \
      }
      SPH0(0, qa0)
      SPH0(1, qa1)
      SPH0(2, qa2)
      SPH0(3, qa3)
#undef SPH0
      __builtin_amdgcn_s_setprio(0);
      u16 (*sSo)[72] = (h == 0) ? sS0 : sS1;
#pragma unroll
      for (int j = 0; j < 4; ++j)
#pragma unroll
        for (int r = 0; r < 4; ++r) {
          const int ss = j * 16 + fr, t = wl * 16 + fg * 4 + r;
          float val = sacc[j][r];
          if (h == 0 && ss > t) val = 0.f;
          const u16 vb = f2bf(val);
          sSo[t][ss] = vb;
          dS[r] += bf2f(vb);
        }
    }
    // vT staging: h0 -> sB1 (chunk0), h1 -> sB2 (chunk1)
    {
      u16 (*sBo)[72] = (h == 0) ? sB1 : sB2;
#pragma unroll
      for (int e = 0; e < 8; ++e) sBo[wl * 16 + e][lane] = (u16)ev0[e];
#pragma unroll
      for (int e = 0; e < 8; ++e) sBo[wl * 16 + 8 + e][lane] = (u16)ev1[e];
    }
    __syncthreads();   // BAR F0: sS0/sS1 + sB1/sB2 visible

    // ---- S@V chunk0 (all waves): A = own masked S (own band), B = sB1
    {
      const u16 (*sSo)[72] = (h == 0) ? sS0 : sS1;
      const bf16x8 a0 = *(const bf16x8*)&sSo[wl * 16 + fr][fg * 8];
      const bf16x8 a1 = *(const bf16x8*)&sSo[wl * 16 + fr][32 + fg * 8];
      __builtin_amdgcn_s_setprio(1);
#pragma unroll
      for (int j = 0; j < 4; ++j) {
        const bf16x8 b0 = *(const bf16x8*)&sB1[j * 16 + fr][fg * 8];
        const bf16x8 b1 = *(const bf16x8*)&sB1[j * 16 + fr][32 + fg * 8];
        oacc[j] = MFMA16(a0, b0, oacc[j]);
        oacc[j] = MFMA16(a1, b1, oacc[j]);
      }
      __builtin_amdgcn_s_setprio(0);
    }

    // ---- h1 only: S chunk1 (sKb) -> masked sS1 -> S@V chunk1 (sB2)
    if (h == 1) {
      f32x4 sacc[4] = {};
      __builtin_amdgcn_s_setprio(1);
#define SPH1(MQ, QA)                                                            \
      _Pragma("unroll")                                                         \
      for (int j = 0; j < 4; ++j) {                                             \
        const bf16x8 b0 = *(const bf16x8*)&sKb[j * 16 + fr][MQ * 64 + fg * 8];  \
        const bf16x8 b1 = *(const bf16x8*)&sKb[j * 16 + fr][MQ * 64 + 32 + fg * 8]; \
        sacc[j] = MFMA16(QA[0], b0, sacc[j]);                                   \
        sacc[j] = MFMA16(QA[1], b1, sacc[j]);                                   \
      }
      SPH1(0, qa0)
      SPH1(1, qa1)
      SPH1(2, qa2)
      SPH1(3, qa3)
#undef SPH1
      __builtin_amdgcn_s_setprio(0);
#pragma unroll
      for (int j = 0; j < 4; ++j)
#pragma unroll
        for (int r = 0; r < 4; ++r) {
          const int ss = j * 16 + fr, t = wl * 16 + fg * 4 + r;
          float val = sacc[j][r];
          if (ss > t) val = 0.f;         // diag (s == h == 1)
          const u16 vb = f2bf(val);
          sS1[t][ss] = vb;
          dS[r] += bf2f(vb);
        }
      {
        const bf16x8 a0 = *(const bf16x8*)&sS1[wl * 16 + fr][fg * 8];
        const bf16x8 a1 = *(const bf16x8*)&sS1[wl * 16 + fr][32 + fg * 8];
        __builtin_amdgcn_s_setprio(1);
#pragma unroll
        for (int j = 0; j < 4; ++j) {
          const bf16x8 b0 = *(const bf16x8*)&sB2[j * 16 + fr][fg * 8];
          const bf16x8 b1 = *(const bf16x8*)&sB2[j * 16 + fr][32 + fg * 8];
          oacc[j] = MFMA16(a0, b0, oacc[j]);
          oacc[j] = MFMA16(a1, b1, oacc[j]);
        }
        __builtin_amdgcn_s_setprio(0);
      }
    }

    // den: reduce dS over fr lanes; combine with denk via shfl
#pragma unroll
    for (int m2 = 1; m2 <= 8; m2 <<= 1) {
#pragma unroll
      for (int r = 0; r < 4; ++r) dS[r] += __shfl_xor(dS[r], m2, 64);
    }
    const int b = bh >> 4, hh = bh & 15;
#pragma unroll
    for (int r = 0; r < 4; ++r) {
      const float dk = __shfl(denk, fg * 4 + r, 64);   // token wl*16+fg*4+r
      const float rinv = 1.0f / (dk + dS[r] + 1e-6f);
      const int t = wl * 16 + fg * 4 + r;
      const int l = sc * 128 + h * 64 + t;
#pragma unroll
      for (int j = 0; j < 4; ++j) {
        const int d = j * 16 + fr;
        attn[((size_t)b * L_ + l) * DM_ + hh * 64 + d] = f2bf(oacc[j][r] * rinv);
      }
    }
    __syncthreads();   // BAR E: full fence before next superchunk's reuse
  }
}

extern "C" void kernel_launch(void* const* d_in, const int* in_sizes, int n_in,
                              void* d_out, int out_size, void* d_ws, size_t ws_size,
                              hipStream_t stream) {
  const float* x     = (const float*)d_in[0];
  const float* Wq    = (const float*)d_in[1];
  const float* bq    = (const float*)d_in[2];
  const float* Wk    = (const float*)d_in[3];
  const float* bk    = (const float*)d_in[4];
  const float* Wv    = (const float*)d_in[5];
  const float* bv    = (const float*)d_in[6];
  const float* Wo    = (const float*)d_in[7];
  const float* bo    = (const float*)d_in[8];
  const float* omega = (const float*)d_in[9];
  float* out = (float*)d_out;

  char* ws = (char*)d_ws;
  u16*   v      = (u16*)(ws);                           // 32 MB
  u16*   qb     = (u16*)(ws + 33554432ull);             // 32 MB
  u16*   kb     = (u16*)(ws + 67108864ull);             // 32 MB
  u16*   xb     = (u16*)(ws + 100663296ull);            // 32 MB (alias attn)
  u16*   attn   = xb;
  u16*   stateb = (u16*)(ws + 134217728ull);            // 64 MB
  float* ksum   = (float*)(ws + 201326592ull);          // 2 MB
  u16*   Wt     = (u16*)(ws + 203423744ull);            // 8 MB
  u16*   omb    = (u16*)(ws + 211812352ull);            // 32 KB
  float* nhq    = (float*)(ws + 211845120ull);          // 1 MB
  float* nhk    = (float*)(ws + 212893696ull);          // 1 MB -> 204 MB

  prep_k<<<17472, 256, 0, stream>>>(x, xb, Wq, Wk, Wv, Wo, Wt, omega, omb);
  mm3_k<<<dim3(1024, 3), 256, 0, stream>>>(xb, Wt, bq, bk, bv,
                                           qb, kb, v, nhq, nhk);
  kvstate_k<<<dim3(NSC / 4, BH_), 256, 0, stream>>>(kb, v, omb, nhk, stateb, ksum);
  scan_k<<<dim3(8, BH_), 256, 0, stream>>>(stateb, ksum);
  outchunk_k<<<BH_ * (NSC / 8), 512, 0, stream>>>(qb, kb, v, omb, stateb, ksum,
                                                  nhq, nhk, attn);
  mmo_k<<<1024, 256, 0, stream>>>(attn, Wt + 3145728ull, bo, out);
}